// Round 1
// baseline (2244.106 us; speedup 1.0000x reference)
//
#include <hip/hip_runtime.h>
#include <cstdint>
#include <cstddef>

static constexpr int NUM_PEAK = 28000;
static constexpr int NUM_GENE = 12000;
static constexpr int N_NODES  = NUM_PEAK + NUM_GENE;   // 40000
static constexpr int N_EDGES  = 640000;
static constexpr int E_TOTAL  = N_EDGES + N_NODES;     // 680000 (incl self loops)
static constexpr int NT       = 100;                   // topics
static constexpr int TH       = 512;                   // encoder hidden
static constexpr int EMB      = 64;
static constexpr int HID      = 128;
static constexpr int BATCH    = 256;
#define BN_EPS 1e-5f

// ---------------------------------------------------------------------------
// Generic tiled GEMM: C(M,N) = A(M,K) @ B(N,K)^T  (+ bias on N, non-split only)
// grid = (ceil(N/64), ceil(M/64), ksplit). If ksplit>1, C must be pre-zeroed
// and results are atomicAdd'ed (bias must be handled later by caller).
// ---------------------------------------------------------------------------
__global__ __launch_bounds__(256) void gemm_nt(
    const float* __restrict__ A, const float* __restrict__ B,
    float* __restrict__ C, const float* __restrict__ bias,
    int M, int N, int K) {
  __shared__ float As[16][68];
  __shared__ float Bs[16][68];
  const int ksplit = gridDim.z;
  const int chunk  = (K + ksplit - 1) / ksplit;
  const int k0 = blockIdx.z * chunk;
  const int k1 = min(K, k0 + chunk);
  const int tid = threadIdx.x;
  const int tm = (tid >> 4) << 2;   // 0..60
  const int tn = (tid & 15) << 2;   // 0..60
  const int bm = blockIdx.y * 64, bn = blockIdx.x * 64;
  float acc[4][4] = {};
  for (int k = k0; k < k1; k += 16) {
    for (int i = tid; i < 1024; i += 256) {
      int m = i >> 4, kk = i & 15;
      int gk = k + kk;
      int gm = bm + m;
      As[kk][m] = (gm < M && gk < k1) ? A[(size_t)gm * K + gk] : 0.f;
      int gn = bn + m;
      Bs[kk][m] = (gn < N && gk < k1) ? B[(size_t)gn * K + gk] : 0.f;
    }
    __syncthreads();
#pragma unroll
    for (int kk = 0; kk < 16; ++kk) {
      float a[4], b[4];
#pragma unroll
      for (int i = 0; i < 4; ++i) a[i] = As[kk][tm + i];
#pragma unroll
      for (int j = 0; j < 4; ++j) b[j] = Bs[kk][tn + j];
#pragma unroll
      for (int i = 0; i < 4; ++i)
#pragma unroll
        for (int j = 0; j < 4; ++j) acc[i][j] += a[i] * b[j];
    }
    __syncthreads();
  }
  const bool split = (gridDim.z > 1);
#pragma unroll
  for (int i = 0; i < 4; ++i) {
    int gm = bm + tm + i;
    if (gm >= M) continue;
#pragma unroll
    for (int j = 0; j < 4; ++j) {
      int gn = bn + tn + j;
      if (gn >= N) continue;
      if (split) atomicAdd(&C[(size_t)gm * N + gn], acc[i][j]);
      else C[(size_t)gm * N + gn] = acc[i][j] + (bias ? bias[gn] : 0.f);
    }
  }
}

// ---------------------------------------------------------------------------
// In-place: H[r,c] = BN(relu(H[r,c] + b[c])) over batch axis (rows).
// grid = N columns, block = BATCH threads (=256).
// ---------------------------------------------------------------------------
__global__ __launch_bounds__(256) void bias_relu_bn(
    float* __restrict__ H, const float* __restrict__ b,
    const float* __restrict__ g, const float* __restrict__ be, int N) {
  const int c = blockIdx.x;
  const int r = threadIdx.x;
  float v = fmaxf(H[(size_t)r * N + c] + b[c], 0.f);
  __shared__ float red[BATCH];
  red[r] = v; __syncthreads();
  for (int s = BATCH / 2; s > 0; s >>= 1) { if (r < s) red[r] += red[r + s]; __syncthreads(); }
  const float mean = red[0] * (1.f / BATCH);
  __syncthreads();
  const float d = v - mean;
  red[r] = d * d; __syncthreads();
  for (int s = BATCH / 2; s > 0; s >>= 1) { if (r < s) red[r] += red[r + s]; __syncthreads(); }
  const float var = red[0] * (1.f / BATCH);
  H[(size_t)r * N + c] = d * rsqrtf(var + BN_EPS) * g[c] + be[c];
}

// ---------------------------------------------------------------------------
// Per batch row: kl contribution + theta = softmax(mu). block=128, grid=BATCH.
// ---------------------------------------------------------------------------
__global__ __launch_bounds__(128) void row_kl_theta(
    const float* __restrict__ muR, const float* __restrict__ lsR,
    const float* __restrict__ mu_b, const float* __restrict__ ls_b,
    float* __restrict__ theta, float* __restrict__ kl_out) {
  const int b = blockIdx.x;
  const int t = threadIdx.x;
  const bool act = (t < NT);
  float mu = 0.f, ls = 0.f, term = 0.f;
  if (act) {
    mu = muR[(size_t)b * NT + t] + mu_b[t];
    ls = 2.f * (lsR[(size_t)b * NT + t] + ls_b[t]);
    term = 1.f + ls - mu * mu - expf(ls);
  }
  __shared__ float red[128];
  red[t] = act ? term : 0.f; __syncthreads();
  for (int s = 64; s > 0; s >>= 1) { if (t < s) red[t] += red[t + s]; __syncthreads(); }
  if (t == 0) atomicAdd(kl_out, -0.5f * red[0] * (1.f / BATCH));
  __syncthreads();
  red[t] = act ? mu : -INFINITY; __syncthreads();
  for (int s = 64; s > 0; s >>= 1) { if (t < s) red[t] = fmaxf(red[t], red[t + s]); __syncthreads(); }
  const float mx = red[0];
  __syncthreads();
  const float e = act ? expf(mu - mx) : 0.f;
  red[t] = e; __syncthreads();
  for (int s = 64; s > 0; s >>= 1) { if (t < s) red[t] += red[t + s]; __syncthreads(); }
  if (act) theta[(size_t)b * NT + t] = e / red[0];
}

// --------------------------- GAT edge kernels ------------------------------
__device__ __forceinline__ unsigned f2o(float f) {
  unsigned u = __float_as_uint(f);
  return (u & 0x80000000u) ? ~u : (u | 0x80000000u);
}
__device__ __forceinline__ float o2f(unsigned u) {
  return (u & 0x80000000u) ? __uint_as_float(u & 0x7fffffffu) : __uint_as_float(~u);
}

__global__ __launch_bounds__(256) void fill_u32(unsigned* __restrict__ p, unsigned v, int n) {
  int i = blockIdx.x * 256 + threadIdx.x;
  if (i < n) p[i] = v;
}

// wave per edge: logit = att . leaky_relu(xl[src]+xr[dst]); segment max via atomicMax
__global__ __launch_bounds__(256) void edge_logit(
    const float* __restrict__ xl, const float* __restrict__ xr,
    const float* __restrict__ att, const int* __restrict__ ei,
    float* __restrict__ elog, unsigned* __restrict__ menc, int C) {
  const int wid = (blockIdx.x * 256 + threadIdx.x) >> 6;
  const int lane = threadIdx.x & 63;
  if (wid >= E_TOTAL) return;
  int s, d;
  if (wid < N_EDGES) { s = ei[wid]; d = ei[N_EDGES + wid]; }
  else { s = d = wid - N_EDGES; }
  float v = 0.f;
  for (int c = lane; c < C; c += 64) {
    float x = xl[(size_t)s * C + c] + xr[(size_t)d * C + c];
    x = (x > 0.f) ? x : 0.2f * x;
    v += x * att[c];
  }
  for (int o = 32; o > 0; o >>= 1) v += __shfl_down(v, o);
  if (lane == 0) {
    elog[wid] = v;
    atomicMax(&menc[d], f2o(v));
  }
}

// thread per edge: ex = exp(logit - m[dst]); den[dst] += ex  (elog in-place)
__global__ __launch_bounds__(256) void edge_softmax_den(
    float* __restrict__ elog, const unsigned* __restrict__ menc,
    const int* __restrict__ ei, float* __restrict__ den) {
  const int e = blockIdx.x * 256 + threadIdx.x;
  if (e >= E_TOTAL) return;
  const int d = (e < N_EDGES) ? ei[N_EDGES + e] : e - N_EDGES;
  const float ex = expf(elog[e] - o2f(menc[d]));
  elog[e] = ex;
  atomicAdd(&den[d], ex);
}

// wave per edge: out[dst] += alpha * xl[src]
__global__ __launch_bounds__(256) void edge_aggregate(
    const float* __restrict__ ex, const float* __restrict__ den,
    const float* __restrict__ xl, const int* __restrict__ ei,
    float* __restrict__ out, int C) {
  const int wid = (blockIdx.x * 256 + threadIdx.x) >> 6;
  const int lane = threadIdx.x & 63;
  if (wid >= E_TOTAL) return;
  int s, d;
  if (wid < N_EDGES) { s = ei[wid]; d = ei[N_EDGES + wid]; }
  else { s = d = wid - N_EDGES; }
  const float alpha = ex[wid] / (den[d] + 1e-16f);
  for (int c = lane; c < C; c += 64)
    atomicAdd(&out[(size_t)d * C + c], alpha * xl[(size_t)s * C + c]);
}

__global__ __launch_bounds__(256) void bias_relu_rows(
    float* __restrict__ x, const float* __restrict__ bias, size_t n, int cmask) {
  size_t i = (size_t)blockIdx.x * 256 + threadIdx.x;
  const size_t stride = (size_t)gridDim.x * 256;
  for (; i < n; i += stride) x[i] = fmaxf(x[i] + bias[i & (size_t)cmask], 0.f);
}

// column softmax over axis 0 (in place). grid = NT columns, block = 256.
__global__ __launch_bounds__(256) void col_softmax(float* __restrict__ L, int M) {
  const int c = blockIdx.x;
  const int tid = threadIdx.x;
  __shared__ float red[256];
  float mx = -INFINITY;
  for (int j = tid; j < M; j += 256) mx = fmaxf(mx, L[(size_t)j * NT + c]);
  red[tid] = mx; __syncthreads();
  for (int s = 128; s > 0; s >>= 1) { if (tid < s) red[tid] = fmaxf(red[tid], red[tid + s]); __syncthreads(); }
  mx = red[0]; __syncthreads();
  float sm = 0.f;
  for (int j = tid; j < M; j += 256) sm += expf(L[(size_t)j * NT + c] - mx);
  red[tid] = sm; __syncthreads();
  for (int s = 128; s > 0; s >>= 1) { if (tid < s) red[tid] += red[tid + s]; __syncthreads(); }
  const float inv = 1.f / red[0];
  for (int j = tid; j < M; j += 256) {
    size_t idx = (size_t)j * NT + c;
    L[idx] = expf(L[idx] - mx) * inv;
  }
}

// recon partial: out[0] += -scale * sum(X * log(preds + 1e-6))
__global__ __launch_bounds__(256) void recon_reduce(
    const float* __restrict__ preds, const float* __restrict__ X,
    float* __restrict__ out, size_t n, float scale) {
  size_t i = (size_t)blockIdx.x * 256 + threadIdx.x;
  const size_t stride = (size_t)gridDim.x * 256;
  float local = 0.f;
  for (; i < n; i += stride) local += X[i] * logf(preds[i] + 1e-6f);
  for (int o = 32; o > 0; o >>= 1) local += __shfl_down(local, o);
  if ((threadIdx.x & 63) == 0) atomicAdd(out, -scale * local);
}

// ---------------------------------------------------------------------------
extern "C" void kernel_launch(void* const* d_in, const int* in_sizes, int n_in,
                              void* d_out, int out_size, void* d_ws, size_t ws_size,
                              hipStream_t stream) {
  const float* Gene   = (const float*)d_in[0];
  const float* GeneN  = (const float*)d_in[1];
  const float* Peak   = (const float*)d_in[2];
  const float* PeakN  = (const float*)d_in[3];
  const float* feat   = (const float*)d_in[4];
  const float* Wl1 = (const float*)d_in[5];  const float* bl1 = (const float*)d_in[6];
  const float* Wr1 = (const float*)d_in[7];  const float* br1 = (const float*)d_in[8];
  const float* att1 = (const float*)d_in[9]; const float* bias1 = (const float*)d_in[10];
  const float* Wl2 = (const float*)d_in[11]; const float* bl2 = (const float*)d_in[12];
  const float* Wr2 = (const float*)d_in[13]; const float* br2 = (const float*)d_in[14];
  const float* att2 = (const float*)d_in[15]; const float* bias2 = (const float*)d_in[16];
  const float* gW1 = (const float*)d_in[17]; const float* gb1 = (const float*)d_in[18];
  const float* gg1 = (const float*)d_in[19]; const float* gbe1 = (const float*)d_in[20];
  const float* gW2 = (const float*)d_in[21]; const float* gb2 = (const float*)d_in[22];
  const float* gg2 = (const float*)d_in[23]; const float* gbe2 = (const float*)d_in[24];
  const float* pW1 = (const float*)d_in[25]; const float* pb1 = (const float*)d_in[26];
  const float* pg1 = (const float*)d_in[27]; const float* pbe1 = (const float*)d_in[28];
  const float* pW2 = (const float*)d_in[29]; const float* pb2 = (const float*)d_in[30];
  const float* pg2 = (const float*)d_in[31]; const float* pbe2 = (const float*)d_in[32];
  const float* mu_W = (const float*)d_in[33]; const float* mu_b = (const float*)d_in[34];
  const float* ls_W = (const float*)d_in[35]; const float* ls_b = (const float*)d_in[36];
  const float* alphas_W = (const float*)d_in[37];
  const float* alphas_star_W = (const float*)d_in[38];
  const int* ei = (const int*)d_in[39];

  float* out = (float*)d_out;

  // ---- workspace layout (floats) ----
  float* W = (float*)d_ws;
  size_t o = 0;
  auto alloc = [&](size_t n) { float* p = W + o; o += n; return p; };
  float* xl1  = alloc((size_t)N_NODES * HID);
  float* xr1  = alloc((size_t)N_NODES * HID);
  float* agg1 = alloc((size_t)N_NODES * HID);
  float* xl2  = alloc((size_t)N_NODES * EMB);
  float* xr2  = alloc((size_t)N_NODES * EMB);
  float* emb  = alloc((size_t)N_NODES * EMB);
  float* elog = alloc((size_t)E_TOTAL);
  float* den  = alloc((size_t)N_NODES);
  unsigned* menc = (unsigned*)alloc((size_t)N_NODES);
  float* h1g = alloc((size_t)BATCH * TH);
  float* h2g = alloc((size_t)BATCH * TH);
  float* h1p = alloc((size_t)BATCH * TH);
  float* h2p = alloc((size_t)BATCH * TH);
  float* mu_d = alloc((size_t)BATCH * NT);
  float* ls_d = alloc((size_t)BATCH * NT);
  float* th_d = alloc((size_t)BATCH * NT);
  float* mu_j = alloc((size_t)BATCH * NT);
  float* ls_j = alloc((size_t)BATCH * NT);
  float* th_j = alloc((size_t)BATCH * NT);
  float* lgg = alloc((size_t)NUM_GENE * NT);
  float* lgp = alloc((size_t)NUM_PEAK * NT);
  float* pg  = alloc((size_t)BATCH * NUM_GENE);
  float* pp  = alloc((size_t)BATCH * NUM_PEAK);
  (void)ws_size; (void)n_in; (void)in_sizes;

  auto cdiv = [](int a, int b) { return (a + b - 1) / b; };
  auto Z = [&](void* p, size_t bytes) { hipMemsetAsync(p, 0, bytes, stream); };

  Z(d_out, (size_t)out_size * sizeof(float));

  // ================= encoders =================
  // gene
  Z(h1g, (size_t)BATCH * TH * 4);
  gemm_nt<<<dim3(cdiv(TH,64), cdiv(BATCH,64), 8), 256, 0, stream>>>(GeneN, gW1, h1g, nullptr, BATCH, TH, NUM_GENE);
  bias_relu_bn<<<TH, BATCH, 0, stream>>>(h1g, gb1, gg1, gbe1, TH);
  Z(h2g, (size_t)BATCH * TH * 4);
  gemm_nt<<<dim3(cdiv(TH,64), cdiv(BATCH,64), 4), 256, 0, stream>>>(h1g, gW2, h2g, nullptr, BATCH, TH, TH);
  bias_relu_bn<<<TH, BATCH, 0, stream>>>(h2g, gb2, gg2, gbe2, TH);
  Z(mu_d, (size_t)BATCH * NT * 4);
  Z(ls_d, (size_t)BATCH * NT * 4);
  gemm_nt<<<dim3(cdiv(NT,64), cdiv(BATCH,64), 4), 256, 0, stream>>>(h2g, mu_W, mu_d, nullptr, BATCH, NT, TH);
  gemm_nt<<<dim3(cdiv(NT,64), cdiv(BATCH,64), 4), 256, 0, stream>>>(h2g, ls_W, ls_d, nullptr, BATCH, NT, TH);
  row_kl_theta<<<BATCH, 128, 0, stream>>>(mu_d, ls_d, mu_b, ls_b, th_d, out + 1);
  // peak
  Z(h1p, (size_t)BATCH * TH * 4);
  gemm_nt<<<dim3(cdiv(TH,64), cdiv(BATCH,64), 16), 256, 0, stream>>>(PeakN, pW1, h1p, nullptr, BATCH, TH, NUM_PEAK);
  bias_relu_bn<<<TH, BATCH, 0, stream>>>(h1p, pb1, pg1, pbe1, TH);
  Z(h2p, (size_t)BATCH * TH * 4);
  gemm_nt<<<dim3(cdiv(TH,64), cdiv(BATCH,64), 4), 256, 0, stream>>>(h1p, pW2, h2p, nullptr, BATCH, TH, TH);
  bias_relu_bn<<<TH, BATCH, 0, stream>>>(h2p, pb2, pg2, pbe2, TH);
  Z(mu_j, (size_t)BATCH * NT * 4);
  Z(ls_j, (size_t)BATCH * NT * 4);
  gemm_nt<<<dim3(cdiv(NT,64), cdiv(BATCH,64), 4), 256, 0, stream>>>(h2p, mu_W, mu_j, nullptr, BATCH, NT, TH);
  gemm_nt<<<dim3(cdiv(NT,64), cdiv(BATCH,64), 4), 256, 0, stream>>>(h2p, ls_W, ls_j, nullptr, BATCH, NT, TH);
  row_kl_theta<<<BATCH, 128, 0, stream>>>(mu_j, ls_j, mu_b, ls_b, th_j, out + 1);

  // ================= GAT layer 1 =================
  gemm_nt<<<dim3(cdiv(HID,64), cdiv(N_NODES,64), 1), 256, 0, stream>>>(feat, Wl1, xl1, bl1, N_NODES, HID, EMB);
  gemm_nt<<<dim3(cdiv(HID,64), cdiv(N_NODES,64), 1), 256, 0, stream>>>(feat, Wr1, xr1, br1, N_NODES, HID, EMB);
  fill_u32<<<cdiv(N_NODES,256), 256, 0, stream>>>(menc, 0x007FFFFFu, N_NODES); // f2o(-inf)
  Z(den, (size_t)N_NODES * 4);
  Z(agg1, (size_t)N_NODES * HID * 4);
  {
    int blocks = cdiv(E_TOTAL * 64, 256);
    edge_logit<<<blocks, 256, 0, stream>>>(xl1, xr1, att1, ei, elog, menc, HID);
    edge_softmax_den<<<cdiv(E_TOTAL,256), 256, 0, stream>>>(elog, menc, ei, den);
    edge_aggregate<<<blocks, 256, 0, stream>>>(elog, den, xl1, ei, agg1, HID);
  }
  bias_relu_rows<<<2048, 256, 0, stream>>>(agg1, bias1, (size_t)N_NODES * HID, HID - 1);

  // ================= GAT layer 2 =================
  gemm_nt<<<dim3(cdiv(EMB,64), cdiv(N_NODES,64), 1), 256, 0, stream>>>(agg1, Wl2, xl2, bl2, N_NODES, EMB, HID);
  gemm_nt<<<dim3(cdiv(EMB,64), cdiv(N_NODES,64), 1), 256, 0, stream>>>(agg1, Wr2, xr2, br2, N_NODES, EMB, HID);
  fill_u32<<<cdiv(N_NODES,256), 256, 0, stream>>>(menc, 0x007FFFFFu, N_NODES);
  Z(den, (size_t)N_NODES * 4);
  Z(emb, (size_t)N_NODES * EMB * 4);
  {
    int blocks = cdiv(E_TOTAL * 64, 256);
    edge_logit<<<blocks, 256, 0, stream>>>(xl2, xr2, att2, ei, elog, menc, EMB);
    edge_softmax_den<<<cdiv(E_TOTAL,256), 256, 0, stream>>>(elog, menc, ei, den);
    edge_aggregate<<<blocks, 256, 0, stream>>>(elog, den, xl2, ei, emb, EMB);
  }
  bias_relu_rows<<<2048, 256, 0, stream>>>(emb, bias2, (size_t)N_NODES * EMB, EMB - 1);

  // ================= topic heads =================
  // rho = emb[NUM_PEAK:], eta = emb[:NUM_PEAK]
  gemm_nt<<<dim3(cdiv(NT,64), cdiv(NUM_GENE,64), 1), 256, 0, stream>>>(emb + (size_t)NUM_PEAK * EMB, alphas_W, lgg, nullptr, NUM_GENE, NT, EMB);
  gemm_nt<<<dim3(cdiv(NT,64), cdiv(NUM_PEAK,64), 1), 256, 0, stream>>>(emb, alphas_star_W, lgp, nullptr, NUM_PEAK, NT, EMB);
  col_softmax<<<NT, 256, 0, stream>>>(lgg, NUM_GENE);
  col_softmax<<<NT, 256, 0, stream>>>(lgp, NUM_PEAK);

  // preds = theta @ beta  (beta^T is the softmaxed logits, row-major MxNT)
  gemm_nt<<<dim3(cdiv(NUM_GENE,64), cdiv(BATCH,64), 1), 256, 0, stream>>>(th_d, lgg, pg, nullptr, BATCH, NUM_GENE, NT);
  gemm_nt<<<dim3(cdiv(NUM_PEAK,64), cdiv(BATCH,64), 1), 256, 0, stream>>>(th_j, lgp, pp, nullptr, BATCH, NUM_PEAK, NT);

  recon_reduce<<<2048, 256, 0, stream>>>(pg, Gene, out, (size_t)BATCH * NUM_GENE, 1.f / BATCH);
  recon_reduce<<<2048, 256, 0, stream>>>(pp, Peak, out, (size_t)BATCH * NUM_PEAK, 1.f / BATCH);
}

// Round 2
// 1363.364 us; speedup vs baseline: 1.6460x; 1.6460x over previous
//
#include <hip/hip_runtime.h>
#include <cstdint>
#include <cstddef>

using u16 = unsigned short;
using u32 = unsigned int;
typedef __attribute__((ext_vector_type(8))) short bf16x8;
typedef __attribute__((ext_vector_type(4))) float f32x4;

static constexpr int NUM_PEAK = 28000;
static constexpr int NUM_GENE = 12000;
static constexpr int N_NODES  = NUM_PEAK + NUM_GENE;   // 40000
static constexpr int N_EDGES  = 640000;
static constexpr int E_TOTAL  = N_EDGES + N_NODES;     // 680000
static constexpr int NT       = 100;
static constexpr int NTP      = 128;                   // padded topic stride
static constexpr int TH       = 512;
static constexpr int EMB      = 64;
static constexpr int HID      = 128;
static constexpr int BATCH    = 256;
#define BN_EPS 1e-5f

__device__ __forceinline__ u16 f2bf(float f) {
  u32 b = __float_as_uint(f);
  return (u16)((b + 0x7FFFu + ((b >> 16) & 1u)) >> 16);
}
__device__ __forceinline__ u32 f2o(float f) {
  u32 u = __float_as_uint(f);
  return (u & 0x80000000u) ? ~u : (u | 0x80000000u);
}
__device__ __forceinline__ float o2f(u32 u) {
  return (u & 0x80000000u) ? __uint_as_float(u & 0x7fffffffu) : __uint_as_float(~u);
}

// ---------------------------------------------------------------------------
// fp32 -> bf16 convert, 8 elems/thread
// ---------------------------------------------------------------------------
__global__ __launch_bounds__(256) void cvt_f2b(const float* __restrict__ x,
                                               u16* __restrict__ y, size_t n) {
  size_t i = ((size_t)blockIdx.x * 256 + threadIdx.x) * 8;
  const size_t stride = (size_t)gridDim.x * 256 * 8;
  for (; i + 8 <= n; i += stride) {
    float4 a = *(const float4*)(x + i);
    float4 b = *(const float4*)(x + i + 4);
    ushort4 o0{f2bf(a.x), f2bf(a.y), f2bf(a.z), f2bf(a.w)};
    ushort4 o1{f2bf(b.x), f2bf(b.y), f2bf(b.z), f2bf(b.w)};
    *(ushort4*)(y + i) = o0;
    *(ushort4*)(y + i + 4) = o1;
  }
  if (blockIdx.x == 0 && threadIdx.x == 0)
    for (size_t j = n & ~7ull; j < n; ++j) y[j] = f2bf(x[j]);
}

// ---------------------------------------------------------------------------
// bf16 MFMA GEMM: C(M,N) = A(M,K) @ B(N,K)^T. 64x64 tile, 4 waves, BK=32.
// gridDim.z>1: atomicAdd into pre-zeroed C (bias ignored). Else direct store
// (+bias if non-null). chunk must be a multiple of 32.
// ---------------------------------------------------------------------------
__global__ __launch_bounds__(256) void gemm_bt_bf16(
    const u16* __restrict__ A, const u16* __restrict__ B,
    float* __restrict__ C, const float* __restrict__ bias,
    int M, int N, int K, int chunk) {
  __shared__ u16 As[64][32];
  __shared__ u16 Bs[64][32];
  const int tid = threadIdx.x;
  const int bm = blockIdx.y * 64, bn = blockIdx.x * 64;
  const int k0 = blockIdx.z * chunk;
  const int k1 = min(K, k0 + chunk);
  const int w = tid >> 6, lane = tid & 63;
  const int wm = (w >> 1) * 32, wn = (w & 1) * 32;
  const int fr = lane & 15;
  const int ks = (lane >> 4) * 8;
  const int srow = tid >> 2, sseg = (tid & 3) * 8;
  f32x4 acc[2][2] = {};
  for (int kt = k0; kt < k1; kt += 32) {
    const int gk = kt + sseg;
    {
      const int gm = bm + srow;
      bf16x8 v = {0, 0, 0, 0, 0, 0, 0, 0};
      if (gm < M) {
        if (gk + 8 <= k1) v = *(const bf16x8*)(A + (size_t)gm * K + gk);
        else if (gk < k1)
          for (int e = 0; e < k1 - gk; ++e) ((short*)&v)[e] = (short)A[(size_t)gm * K + gk + e];
      }
      *(bf16x8*)&As[srow][sseg] = v;
    }
    {
      const int gn = bn + srow;
      bf16x8 v = {0, 0, 0, 0, 0, 0, 0, 0};
      if (gn < N) {
        if (gk + 8 <= k1) v = *(const bf16x8*)(B + (size_t)gn * K + gk);
        else if (gk < k1)
          for (int e = 0; e < k1 - gk; ++e) ((short*)&v)[e] = (short)B[(size_t)gn * K + gk + e];
      }
      *(bf16x8*)&Bs[srow][sseg] = v;
    }
    __syncthreads();
    bf16x8 a0 = *(const bf16x8*)&As[wm + fr][ks];
    bf16x8 a1 = *(const bf16x8*)&As[wm + 16 + fr][ks];
    bf16x8 b0 = *(const bf16x8*)&Bs[wn + fr][ks];
    bf16x8 b1 = *(const bf16x8*)&Bs[wn + 16 + fr][ks];
    acc[0][0] = __builtin_amdgcn_mfma_f32_16x16x32_bf16(a0, b0, acc[0][0], 0, 0, 0);
    acc[0][1] = __builtin_amdgcn_mfma_f32_16x16x32_bf16(a0, b1, acc[0][1], 0, 0, 0);
    acc[1][0] = __builtin_amdgcn_mfma_f32_16x16x32_bf16(a1, b0, acc[1][0], 0, 0, 0);
    acc[1][1] = __builtin_amdgcn_mfma_f32_16x16x32_bf16(a1, b1, acc[1][1], 0, 0, 0);
    __syncthreads();
  }
  const bool split = (gridDim.z > 1);
#pragma unroll
  for (int fi = 0; fi < 2; ++fi)
#pragma unroll
    for (int fj = 0; fj < 2; ++fj)
#pragma unroll
      for (int r = 0; r < 4; ++r) {
        const int row = bm + wm + fi * 16 + (lane >> 4) * 4 + r;
        const int col = bn + wn + fj * 16 + fr;
        if (row < M && col < N) {
          const float v = acc[fi][fj][r];
          if (split) atomicAdd(&C[(size_t)row * N + col], v);
          else C[(size_t)row * N + col] = v + (bias ? bias[col] : 0.f);
        }
      }
}

// ---------------------------------------------------------------------------
// Recon-fused GEMM: pred = A(256,K)@B(N,K)^T; epilogue accumulates
// -1/BATCH * X[row,col]*log(pred+1e-6) into out[0].
// ---------------------------------------------------------------------------
__global__ __launch_bounds__(256) void gemm_recon_bf16(
    const u16* __restrict__ A, const u16* __restrict__ B,
    const float* __restrict__ X, float* __restrict__ out, int N, int K) {
  __shared__ u16 As[64][32];
  __shared__ u16 Bs[64][32];
  const int tid = threadIdx.x;
  const int bm = blockIdx.y * 64, bn = blockIdx.x * 64;
  const int w = tid >> 6, lane = tid & 63;
  const int wm = (w >> 1) * 32, wn = (w & 1) * 32;
  const int fr = lane & 15;
  const int ks = (lane >> 4) * 8;
  const int srow = tid >> 2, sseg = (tid & 3) * 8;
  f32x4 acc[2][2] = {};
  for (int kt = 0; kt < K; kt += 32) {
    const int gk = kt + sseg;
    {
      bf16x8 v = *(const bf16x8*)(A + (size_t)(bm + srow) * K + gk);  // M=256 exact
      *(bf16x8*)&As[srow][sseg] = v;
    }
    {
      const int gn = bn + srow;
      bf16x8 v = {0, 0, 0, 0, 0, 0, 0, 0};
      if (gn < N) v = *(const bf16x8*)(B + (size_t)gn * K + gk);
      *(bf16x8*)&Bs[srow][sseg] = v;
    }
    __syncthreads();
    bf16x8 a0 = *(const bf16x8*)&As[wm + fr][ks];
    bf16x8 a1 = *(const bf16x8*)&As[wm + 16 + fr][ks];
    bf16x8 b0 = *(const bf16x8*)&Bs[wn + fr][ks];
    bf16x8 b1 = *(const bf16x8*)&Bs[wn + 16 + fr][ks];
    acc[0][0] = __builtin_amdgcn_mfma_f32_16x16x32_bf16(a0, b0, acc[0][0], 0, 0, 0);
    acc[0][1] = __builtin_amdgcn_mfma_f32_16x16x32_bf16(a0, b1, acc[0][1], 0, 0, 0);
    acc[1][0] = __builtin_amdgcn_mfma_f32_16x16x32_bf16(a1, b0, acc[1][0], 0, 0, 0);
    acc[1][1] = __builtin_amdgcn_mfma_f32_16x16x32_bf16(a1, b1, acc[1][1], 0, 0, 0);
    __syncthreads();
  }
  float local = 0.f;
#pragma unroll
  for (int fi = 0; fi < 2; ++fi)
#pragma unroll
    for (int fj = 0; fj < 2; ++fj)
#pragma unroll
      for (int r = 0; r < 4; ++r) {
        const int row = bm + wm + fi * 16 + (lane >> 4) * 4 + r;
        const int col = bn + wn + fj * 16 + fr;
        if (col < N)
          local += X[(size_t)row * N + col] * logf(acc[fi][fj][r] + 1e-6f);
      }
  for (int o = 32; o > 0; o >>= 1) local += __shfl_down(local, o);
  if (lane == 0) atomicAdd(out, -local * (1.f / BATCH));
}

// ---------------------------------------------------------------------------
// H fp32 (BATCH x N): out_b = bf16(BN(relu(H + b))). grid=N, block=BATCH.
// ---------------------------------------------------------------------------
__global__ __launch_bounds__(256) void bias_relu_bn(
    const float* __restrict__ H, const float* __restrict__ b,
    const float* __restrict__ g, const float* __restrict__ be,
    u16* __restrict__ outb, int N) {
  const int c = blockIdx.x;
  const int r = threadIdx.x;
  float v = fmaxf(H[(size_t)r * N + c] + b[c], 0.f);
  __shared__ float red[BATCH];
  red[r] = v; __syncthreads();
  for (int s = BATCH / 2; s > 0; s >>= 1) { if (r < s) red[r] += red[r + s]; __syncthreads(); }
  const float mean = red[0] * (1.f / BATCH);
  __syncthreads();
  const float d = v - mean;
  red[r] = d * d; __syncthreads();
  for (int s = BATCH / 2; s > 0; s >>= 1) { if (r < s) red[r] += red[r + s]; __syncthreads(); }
  const float var = red[0] * (1.f / BATCH);
  outb[(size_t)r * N + c] = f2bf(d * rsqrtf(var + BN_EPS) * g[c] + be[c]);
}

// ---------------------------------------------------------------------------
// KL + theta = softmax(mu) -> bf16 padded to NTP. grid=BATCH, block=128.
// ---------------------------------------------------------------------------
__global__ __launch_bounds__(128) void row_kl_theta(
    const float* __restrict__ muR, const float* __restrict__ lsR,
    const float* __restrict__ mu_b, const float* __restrict__ ls_b,
    u16* __restrict__ thb, float* __restrict__ kl_out) {
  const int b = blockIdx.x;
  const int t = threadIdx.x;
  const bool act = (t < NT);
  float mu = 0.f, ls = 0.f, term = 0.f;
  if (act) {
    mu = muR[(size_t)b * NT + t] + mu_b[t];
    ls = 2.f * (lsR[(size_t)b * NT + t] + ls_b[t]);
    term = 1.f + ls - mu * mu - expf(ls);
  }
  __shared__ float red[128];
  red[t] = act ? term : 0.f; __syncthreads();
  for (int s = 64; s > 0; s >>= 1) { if (t < s) red[t] += red[t + s]; __syncthreads(); }
  if (t == 0) atomicAdd(kl_out, -0.5f * red[0] * (1.f / BATCH));
  __syncthreads();
  red[t] = act ? mu : -INFINITY; __syncthreads();
  for (int s = 64; s > 0; s >>= 1) { if (t < s) red[t] = fmaxf(red[t], red[t + s]); __syncthreads(); }
  const float mx = red[0];
  __syncthreads();
  const float e = act ? expf(mu - mx) : 0.f;
  red[t] = e; __syncthreads();
  for (int s = 64; s > 0; s >>= 1) { if (t < s) red[t] += red[t + s]; __syncthreads(); }
  thb[(size_t)b * NTP + t] = act ? f2bf(e / red[0]) : (u16)0;
}

// --------------------------- GAT edge kernels ------------------------------
__global__ __launch_bounds__(256) void fill_u32(u32* __restrict__ p, u32 v, int n) {
  int i = blockIdx.x * 256 + threadIdx.x;
  if (i < n) p[i] = v;
}

__global__ __launch_bounds__(256) void edge_logit(
    const float* __restrict__ xl, const float* __restrict__ xr,
    const float* __restrict__ att, const int* __restrict__ ei,
    float* __restrict__ elog, u32* __restrict__ menc, int C) {
  const int wid = (blockIdx.x * 256 + threadIdx.x) >> 6;
  const int lane = threadIdx.x & 63;
  if (wid >= E_TOTAL) return;
  int s, d;
  if (wid < N_EDGES) { s = ei[wid]; d = ei[N_EDGES + wid]; }
  else { s = d = wid - N_EDGES; }
  float v = 0.f;
  for (int c = lane; c < C; c += 64) {
    float x = xl[(size_t)s * C + c] + xr[(size_t)d * C + c];
    x = (x > 0.f) ? x : 0.2f * x;
    v += x * att[c];
  }
  for (int o = 32; o > 0; o >>= 1) v += __shfl_down(v, o);
  if (lane == 0) {
    elog[wid] = v;
    atomicMax(&menc[d], f2o(v));
  }
}

__global__ __launch_bounds__(256) void edge_softmax_den(
    float* __restrict__ elog, const u32* __restrict__ menc,
    const int* __restrict__ ei, float* __restrict__ den) {
  const int e = blockIdx.x * 256 + threadIdx.x;
  if (e >= E_TOTAL) return;
  const int d = (e < N_EDGES) ? ei[N_EDGES + e] : e - N_EDGES;
  const float ex = expf(elog[e] - o2f(menc[d]));
  elog[e] = ex;
  atomicAdd(&den[d], ex);
}

__global__ __launch_bounds__(256) void edge_aggregate(
    const float* __restrict__ ex, const float* __restrict__ den,
    const float* __restrict__ xl, const int* __restrict__ ei,
    float* __restrict__ out, int C) {
  const int wid = (blockIdx.x * 256 + threadIdx.x) >> 6;
  const int lane = threadIdx.x & 63;
  if (wid >= E_TOTAL) return;
  int s, d;
  if (wid < N_EDGES) { s = ei[wid]; d = ei[N_EDGES + wid]; }
  else { s = d = wid - N_EDGES; }
  const float alpha = ex[wid] / (den[d] + 1e-16f);
  for (int c = lane; c < C; c += 64)
    atomicAdd(&out[(size_t)d * C + c], alpha * xl[(size_t)s * C + c]);
}

// relu(x + bias[col]) -> bf16
__global__ __launch_bounds__(256) void relu_bias_b(
    const float* __restrict__ x, const float* __restrict__ bias,
    u16* __restrict__ y, size_t n, int cmask) {
  size_t i = (size_t)blockIdx.x * 256 + threadIdx.x;
  const size_t stride = (size_t)gridDim.x * 256;
  for (; i < n; i += stride) y[i] = f2bf(fmaxf(x[i] + bias[i & (size_t)cmask], 0.f));
}

// ----------------------- column softmax statistics -------------------------
__global__ __launch_bounds__(256) void col_max(
    const float* __restrict__ L, u32* __restrict__ gmx, int M) {
  __shared__ u32 s[NT];
  for (int i = threadIdx.x; i < NT; i += 256) s[i] = 0x007FFFFFu;  // f2o(-inf)
  __syncthreads();
  const int r0 = blockIdx.x * 128;
  const int cnt = min(128, M - r0) * NT;
  const float* base = L + (size_t)r0 * NT;
  for (int i = threadIdx.x; i < cnt; i += 256) {
    const int c = i % NT;
    atomicMax(&s[c], f2o(base[i]));
  }
  __syncthreads();
  for (int i = threadIdx.x; i < NT; i += 256) atomicMax(&gmx[i], s[i]);
}

__global__ __launch_bounds__(256) void col_sumexp(
    const float* __restrict__ L, const u32* __restrict__ gmx,
    float* __restrict__ gden, int M) {
  __shared__ float mx[NT];
  __shared__ float s[NT];
  for (int i = threadIdx.x; i < NT; i += 256) { mx[i] = o2f(gmx[i]); s[i] = 0.f; }
  __syncthreads();
  const int r0 = blockIdx.x * 128;
  const int cnt = min(128, M - r0) * NT;
  const float* base = L + (size_t)r0 * NT;
  for (int i = threadIdx.x; i < cnt; i += 256) {
    const int c = i % NT;
    atomicAdd(&s[c], expf(base[i] - mx[c]));
  }
  __syncthreads();
  for (int i = threadIdx.x; i < NT; i += 256) atomicAdd(&gden[i], s[i]);
}

// beta_b[g*NTP + t] = bf16(exp(L[g,t]-mx[t])/den[t]), zero-padded t>=NT
__global__ __launch_bounds__(256) void beta_norm(
    const float* __restrict__ L, const u32* __restrict__ gmx,
    const float* __restrict__ gden, u16* __restrict__ out, int M) {
  __shared__ float mx[NT], inv[NT];
  for (int i = threadIdx.x; i < NT; i += 256) { mx[i] = o2f(gmx[i]); inv[i] = 1.f / gden[i]; }
  __syncthreads();
  const size_t total = (size_t)M * NTP;
  size_t i = (size_t)blockIdx.x * 256 + threadIdx.x;
  const size_t stride = (size_t)gridDim.x * 256;
  for (; i < total; i += stride) {
    const int c = (int)(i & (NTP - 1));
    u16 v = 0;
    if (c < NT) {
      const size_t r = i >> 7;
      v = f2bf(expf(L[r * NT + c] - mx[c]) * inv[c]);
    }
    out[i] = v;
  }
}

// ---------------------------------------------------------------------------
extern "C" void kernel_launch(void* const* d_in, const int* in_sizes, int n_in,
                              void* d_out, int out_size, void* d_ws, size_t ws_size,
                              hipStream_t stream) {
  const float* Gene  = (const float*)d_in[0];
  const float* GeneN = (const float*)d_in[1];
  const float* Peak  = (const float*)d_in[2];
  const float* PeakN = (const float*)d_in[3];
  const float* feat  = (const float*)d_in[4];
  const float* Wl1 = (const float*)d_in[5];  const float* bl1 = (const float*)d_in[6];
  const float* Wr1 = (const float*)d_in[7];  const float* br1 = (const float*)d_in[8];
  const float* att1 = (const float*)d_in[9]; const float* bias1 = (const float*)d_in[10];
  const float* Wl2 = (const float*)d_in[11]; const float* bl2 = (const float*)d_in[12];
  const float* Wr2 = (const float*)d_in[13]; const float* br2 = (const float*)d_in[14];
  const float* att2 = (const float*)d_in[15]; const float* bias2 = (const float*)d_in[16];
  const float* gW1 = (const float*)d_in[17]; const float* gb1 = (const float*)d_in[18];
  const float* gg1 = (const float*)d_in[19]; const float* gbe1 = (const float*)d_in[20];
  const float* gW2 = (const float*)d_in[21]; const float* gb2 = (const float*)d_in[22];
  const float* gg2 = (const float*)d_in[23]; const float* gbe2 = (const float*)d_in[24];
  const float* pW1 = (const float*)d_in[25]; const float* pb1 = (const float*)d_in[26];
  const float* pg1 = (const float*)d_in[27]; const float* pbe1 = (const float*)d_in[28];
  const float* pW2 = (const float*)d_in[29]; const float* pb2 = (const float*)d_in[30];
  const float* pg2 = (const float*)d_in[31]; const float* pbe2 = (const float*)d_in[32];
  const float* mu_W = (const float*)d_in[33]; const float* mu_b = (const float*)d_in[34];
  const float* ls_W = (const float*)d_in[35]; const float* ls_b = (const float*)d_in[36];
  const float* alphas_W = (const float*)d_in[37];
  const float* alphas_star_W = (const float*)d_in[38];
  const int* ei = (const int*)d_in[39];
  float* out = (float*)d_out;
  (void)in_sizes; (void)n_in; (void)ws_size;

  // ---- workspace layout (bytes) ----
  char* base = (char*)d_ws;
  size_t off = 0;
  auto A = [&](size_t bytes) { void* p = base + off; off += (bytes + 255) & ~(size_t)255; return p; };
  float* elog = (float*)A((size_t)E_TOTAL * 4);
  float* den  = (float*)A((size_t)N_NODES * 4);
  u32*   menc = (u32*)A((size_t)N_NODES * 4);
  float* h1g = (float*)A((size_t)BATCH * TH * 4);
  float* h2g = (float*)A((size_t)BATCH * TH * 4);
  float* h1p = (float*)A((size_t)BATCH * TH * 4);
  float* h2p = (float*)A((size_t)BATCH * TH * 4);
  u16* h1gb = (u16*)A((size_t)BATCH * TH * 2);
  u16* h2gb = (u16*)A((size_t)BATCH * TH * 2);
  u16* h1pb = (u16*)A((size_t)BATCH * TH * 2);
  u16* h2pb = (u16*)A((size_t)BATCH * TH * 2);
  float* mu_d = (float*)A((size_t)BATCH * NT * 4);
  float* ls_d = (float*)A((size_t)BATCH * NT * 4);
  float* mu_j = (float*)A((size_t)BATCH * NT * 4);
  float* ls_j = (float*)A((size_t)BATCH * NT * 4);
  u16* th_db = (u16*)A((size_t)BATCH * NTP * 2);
  u16* th_jb = (u16*)A((size_t)BATCH * NTP * 2);
  float* lgg = (float*)A((size_t)NUM_GENE * NT * 4);
  float* lgp = (float*)A((size_t)NUM_PEAK * NT * 4);
  u16* betagb = (u16*)A((size_t)NUM_GENE * NTP * 2);
  u16* betapb = (u16*)A((size_t)NUM_PEAK * NTP * 2);
  u16* featb = (u16*)A((size_t)N_NODES * EMB * 2);
  u16* gW2b = (u16*)A((size_t)TH * TH * 2);
  u16* pW2b = (u16*)A((size_t)TH * TH * 2);
  u16* muWb = (u16*)A((size_t)NT * TH * 2);
  u16* lsWb = (u16*)A((size_t)NT * TH * 2);
  u16* Wl1b = (u16*)A((size_t)HID * EMB * 2);
  u16* Wr1b = (u16*)A((size_t)HID * EMB * 2);
  u16* Wl2b = (u16*)A((size_t)EMB * HID * 2);
  u16* Wr2b = (u16*)A((size_t)EMB * HID * 2);
  u16* aWb  = (u16*)A((size_t)NT * EMB * 2);
  u16* aSWb = (u16*)A((size_t)NT * EMB * 2);
  u16* agg1b = (u16*)A((size_t)N_NODES * HID * 2);
  u16* embb  = (u16*)A((size_t)N_NODES * EMB * 2);
  u32* cmax = (u32*)A(2 * NT * 4);          // [gene, peak]
  float* cden = (float*)A(2 * NT * 4);
  // overlap region: encoder bf16 staging, then GAT fp32 buffers
  char* R = (char*)A(61440000);
  u16* GeneNb = (u16*)R;                               // 6,144,000 B
  u16* gW1b   = (u16*)(R + 6144000);                   // 12,288,000 B
  u16* PeakNb = (u16*)(R + 18432000);                  // 14,336,000 B
  u16* pW1b   = (u16*)(R + 32768000);                  // 28,672,000 B
  float* xl1  = (float*)R;                             // 20,480,000 B
  float* xr1  = (float*)(R + 20480000);
  float* agg1 = (float*)(R + 40960000);
  float* xl2  = (float*)R;                             // reuse xl1 space
  float* xr2  = (float*)(R + 10240000);
  float* emb  = (float*)(R + 20480000);                // reuse xr1 space

  auto cdiv = [](int a, int b) { return (a + b - 1) / b; };
  auto Z = [&](void* p, size_t bytes) { hipMemsetAsync(p, 0, bytes, stream); };
  auto cvt = [&](const float* s, u16* d, size_t n) {
    int blk = (int)min((size_t)2048, (n / (256 * 8)) + 1);
    cvt_f2b<<<blk, 256, 0, stream>>>(s, d, n);
  };

  Z(d_out, (size_t)out_size * sizeof(float));

  // ---- conversions for encoder L1 ----
  cvt(GeneN, GeneNb, (size_t)BATCH * NUM_GENE);
  cvt(PeakN, PeakNb, (size_t)BATCH * NUM_PEAK);
  cvt(gW1, gW1b, (size_t)TH * NUM_GENE);
  cvt(pW1, pW1b, (size_t)TH * NUM_PEAK);
  cvt(gW2, gW2b, (size_t)TH * TH);
  cvt(pW2, pW2b, (size_t)TH * TH);
  cvt(mu_W, muWb, (size_t)NT * TH);
  cvt(ls_W, lsWb, (size_t)NT * TH);

  // ================= encoders =================
  const int ksp = 16;
  const int chG = ((cdiv(NUM_GENE, ksp) + 31) / 32) * 32;   // 768
  const int chP = ((cdiv(NUM_PEAK, ksp) + 31) / 32) * 32;   // 1760
  Z(h1g, (size_t)BATCH * TH * 4);
  Z(h1p, (size_t)BATCH * TH * 4);
  gemm_bt_bf16<<<dim3(TH / 64, BATCH / 64, ksp), 256, 0, stream>>>(GeneNb, gW1b, h1g, nullptr, BATCH, TH, NUM_GENE, chG);
  gemm_bt_bf16<<<dim3(TH / 64, BATCH / 64, ksp), 256, 0, stream>>>(PeakNb, pW1b, h1p, nullptr, BATCH, TH, NUM_PEAK, chP);
  bias_relu_bn<<<TH, BATCH, 0, stream>>>(h1g, gb1, gg1, gbe1, h1gb, TH);
  bias_relu_bn<<<TH, BATCH, 0, stream>>>(h1p, pb1, pg1, pbe1, h1pb, TH);
  gemm_bt_bf16<<<dim3(TH / 64, BATCH / 64, 1), 256, 0, stream>>>(h1gb, gW2b, h2g, nullptr, BATCH, TH, TH, TH);
  gemm_bt_bf16<<<dim3(TH / 64, BATCH / 64, 1), 256, 0, stream>>>(h1pb, pW2b, h2p, nullptr, BATCH, TH, TH, TH);
  bias_relu_bn<<<TH, BATCH, 0, stream>>>(h2g, gb2, gg2, gbe2, h2gb, TH);
  bias_relu_bn<<<TH, BATCH, 0, stream>>>(h2p, pb2, pg2, pbe2, h2pb, TH);
  gemm_bt_bf16<<<dim3(2, BATCH / 64, 1), 256, 0, stream>>>(h2gb, muWb, mu_d, nullptr, BATCH, NT, TH, TH);
  gemm_bt_bf16<<<dim3(2, BATCH / 64, 1), 256, 0, stream>>>(h2gb, lsWb, ls_d, nullptr, BATCH, NT, TH, TH);
  gemm_bt_bf16<<<dim3(2, BATCH / 64, 1), 256, 0, stream>>>(h2pb, muWb, mu_j, nullptr, BATCH, NT, TH, TH);
  gemm_bt_bf16<<<dim3(2, BATCH / 64, 1), 256, 0, stream>>>(h2pb, lsWb, ls_j, nullptr, BATCH, NT, TH, TH);
  row_kl_theta<<<BATCH, 128, 0, stream>>>(mu_d, ls_d, mu_b, ls_b, th_db, out + 1);
  row_kl_theta<<<BATCH, 128, 0, stream>>>(mu_j, ls_j, mu_b, ls_b, th_jb, out + 1);

  // ---- conversions for GAT ----
  cvt(feat, featb, (size_t)N_NODES * EMB);
  cvt(Wl1, Wl1b, (size_t)HID * EMB);
  cvt(Wr1, Wr1b, (size_t)HID * EMB);
  cvt(Wl2, Wl2b, (size_t)EMB * HID);
  cvt(Wr2, Wr2b, (size_t)EMB * HID);
  cvt(alphas_W, aWb, (size_t)NT * EMB);
  cvt(alphas_star_W, aSWb, (size_t)NT * EMB);

  // ================= GAT layer 1 =================
  gemm_bt_bf16<<<dim3(HID / 64, N_NODES / 64, 1), 256, 0, stream>>>(featb, Wl1b, xl1, bl1, N_NODES, HID, EMB, EMB);
  gemm_bt_bf16<<<dim3(HID / 64, N_NODES / 64, 1), 256, 0, stream>>>(featb, Wr1b, xr1, br1, N_NODES, HID, EMB, EMB);
  fill_u32<<<cdiv(N_NODES, 256), 256, 0, stream>>>(menc, 0x007FFFFFu, N_NODES);
  Z(den, (size_t)N_NODES * 4);
  Z(agg1, (size_t)N_NODES * HID * 4);
  {
    const int blocks = cdiv(E_TOTAL * 64, 256);
    edge_logit<<<blocks, 256, 0, stream>>>(xl1, xr1, att1, ei, elog, menc, HID);
    edge_softmax_den<<<cdiv(E_TOTAL, 256), 256, 0, stream>>>(elog, menc, ei, den);
    edge_aggregate<<<blocks, 256, 0, stream>>>(elog, den, xl1, ei, agg1, HID);
  }
  relu_bias_b<<<2048, 256, 0, stream>>>(agg1, bias1, agg1b, (size_t)N_NODES * HID, HID - 1);

  // ================= GAT layer 2 =================
  gemm_bt_bf16<<<dim3(EMB / 64, N_NODES / 64, 1), 256, 0, stream>>>(agg1b, Wl2b, xl2, bl2, N_NODES, EMB, HID, HID);
  gemm_bt_bf16<<<dim3(EMB / 64, N_NODES / 64, 1), 256, 0, stream>>>(agg1b, Wr2b, xr2, br2, N_NODES, EMB, HID, HID);
  fill_u32<<<cdiv(N_NODES, 256), 256, 0, stream>>>(menc, 0x007FFFFFu, N_NODES);
  Z(den, (size_t)N_NODES * 4);
  Z(emb, (size_t)N_NODES * EMB * 4);
  {
    const int blocks = cdiv(E_TOTAL * 64, 256);
    edge_logit<<<blocks, 256, 0, stream>>>(xl2, xr2, att2, ei, elog, menc, EMB);
    edge_softmax_den<<<cdiv(E_TOTAL, 256), 256, 0, stream>>>(elog, menc, ei, den);
    edge_aggregate<<<blocks, 256, 0, stream>>>(elog, den, xl2, ei, emb, EMB);
  }
  relu_bias_b<<<2048, 256, 0, stream>>>(emb, bias2, embb, (size_t)N_NODES * EMB, EMB - 1);

  // ================= topic heads =================
  // logits: rho @ alphas_W^T  (rho = emb[NUM_PEAK:]), eta @ alphas_star_W^T
  gemm_bt_bf16<<<dim3(2, cdiv(NUM_GENE, 64), 1), 256, 0, stream>>>(embb + (size_t)NUM_PEAK * EMB, aWb, lgg, nullptr, NUM_GENE, NT, EMB, EMB);
  gemm_bt_bf16<<<dim3(2, cdiv(NUM_PEAK, 64), 1), 256, 0, stream>>>(embb, aSWb, lgp, nullptr, NUM_PEAK, NT, EMB, EMB);
  fill_u32<<<1, 256, 0, stream>>>(cmax, 0x007FFFFFu, 2 * NT);
  Z(cden, 2 * NT * 4);
  col_max<<<cdiv(NUM_GENE, 128), 256, 0, stream>>>(lgg, cmax, NUM_GENE);
  col_max<<<cdiv(NUM_PEAK, 128), 256, 0, stream>>>(lgp, cmax + NT, NUM_PEAK);
  col_sumexp<<<cdiv(NUM_GENE, 128), 256, 0, stream>>>(lgg, cmax, cden, NUM_GENE);
  col_sumexp<<<cdiv(NUM_PEAK, 128), 256, 0, stream>>>(lgp, cmax + NT, cden + NT, NUM_PEAK);
  beta_norm<<<2048, 256, 0, stream>>>(lgg, cmax, cden, betagb, NUM_GENE);
  beta_norm<<<2048, 256, 0, stream>>>(lgp, cmax + NT, cden + NT, betapb, NUM_PEAK);

  // ================= fused preds + recon =================
  gemm_recon_bf16<<<dim3(cdiv(NUM_GENE, 64), BATCH / 64, 1), 256, 0, stream>>>(th_db, betagb, Gene, out, NUM_GENE, NTP);
  gemm_recon_bf16<<<dim3(cdiv(NUM_PEAK, 64), BATCH / 64, 1), 256, 0, stream>>>(th_jb, betapb, Peak, out, NUM_PEAK, NTP);
}

// Round 3
// 889.776 us; speedup vs baseline: 2.5221x; 1.5323x over previous
//
#include <hip/hip_runtime.h>
#include <cstdint>
#include <cstddef>

using u16 = unsigned short;
using u32 = unsigned int;
typedef __attribute__((ext_vector_type(8))) short bf16x8;
typedef __attribute__((ext_vector_type(4))) float f32x4;

static constexpr int NUM_PEAK = 28000;
static constexpr int NUM_GENE = 12000;
static constexpr int N_NODES  = NUM_PEAK + NUM_GENE;   // 40000
static constexpr int N_EDGES  = 640000;
static constexpr int E_TOTAL  = N_EDGES + N_NODES;     // 680000
static constexpr int NT       = 100;
static constexpr int NTP      = 128;                   // padded topic stride
static constexpr int TH       = 512;
static constexpr int EMB      = 64;
static constexpr int HID      = 128;
static constexpr int BATCH    = 256;
#define BN_EPS 1e-5f

__device__ __forceinline__ u16 f2bf(float f) {
  u32 b = __float_as_uint(f);
  return (u16)((b + 0x7FFFu + ((b >> 16) & 1u)) >> 16);
}
__device__ __forceinline__ u32 f2o(float f) {
  u32 u = __float_as_uint(f);
  return (u & 0x80000000u) ? ~u : (u | 0x80000000u);
}
__device__ __forceinline__ float o2f(u32 u) {
  return (u & 0x80000000u) ? __uint_as_float(u & 0x7fffffffu) : __uint_as_float(~u);
}

// ---------------------------------------------------------------------------
// fp32 -> bf16 convert, 8 elems/thread
// ---------------------------------------------------------------------------
__global__ __launch_bounds__(256) void cvt_f2b(const float* __restrict__ x,
                                               u16* __restrict__ y, size_t n) {
  size_t i = ((size_t)blockIdx.x * 256 + threadIdx.x) * 8;
  const size_t stride = (size_t)gridDim.x * 256 * 8;
  for (; i + 8 <= n; i += stride) {
    float4 a = *(const float4*)(x + i);
    float4 b = *(const float4*)(x + i + 4);
    ushort4 o0{f2bf(a.x), f2bf(a.y), f2bf(a.z), f2bf(a.w)};
    ushort4 o1{f2bf(b.x), f2bf(b.y), f2bf(b.z), f2bf(b.w)};
    *(ushort4*)(y + i) = o0;
    *(ushort4*)(y + i + 4) = o1;
  }
  if (blockIdx.x == 0 && threadIdx.x == 0)
    for (size_t j = n & ~7ull; j < n; ++j) y[j] = f2bf(x[j]);
}

// ---------------------------------------------------------------------------
// bf16 MFMA GEMM: C(M,N) = A(M,K) @ B(N,K)^T. 64x64 tile, 4 waves, BK=32.
// ---------------------------------------------------------------------------
__global__ __launch_bounds__(256) void gemm_bt_bf16(
    const u16* __restrict__ A, const u16* __restrict__ B,
    float* __restrict__ C, const float* __restrict__ bias,
    int M, int N, int K, int chunk) {
  __shared__ u16 As[64][32];
  __shared__ u16 Bs[64][32];
  const int tid = threadIdx.x;
  const int bm = blockIdx.y * 64, bn = blockIdx.x * 64;
  const int k0 = blockIdx.z * chunk;
  const int k1 = min(K, k0 + chunk);
  const int w = tid >> 6, lane = tid & 63;
  const int wm = (w >> 1) * 32, wn = (w & 1) * 32;
  const int fr = lane & 15;
  const int ks = (lane >> 4) * 8;
  const int srow = tid >> 2, sseg = (tid & 3) * 8;
  f32x4 acc[2][2] = {};
  for (int kt = k0; kt < k1; kt += 32) {
    const int gk = kt + sseg;
    {
      const int gm = bm + srow;
      bf16x8 v = {0, 0, 0, 0, 0, 0, 0, 0};
      if (gm < M) {
        if (gk + 8 <= k1) v = *(const bf16x8*)(A + (size_t)gm * K + gk);
        else if (gk < k1)
          for (int e = 0; e < k1 - gk; ++e) ((short*)&v)[e] = (short)A[(size_t)gm * K + gk + e];
      }
      *(bf16x8*)&As[srow][sseg] = v;
    }
    {
      const int gn = bn + srow;
      bf16x8 v = {0, 0, 0, 0, 0, 0, 0, 0};
      if (gn < N) {
        if (gk + 8 <= k1) v = *(const bf16x8*)(B + (size_t)gn * K + gk);
        else if (gk < k1)
          for (int e = 0; e < k1 - gk; ++e) ((short*)&v)[e] = (short)B[(size_t)gn * K + gk + e];
      }
      *(bf16x8*)&Bs[srow][sseg] = v;
    }
    __syncthreads();
    bf16x8 a0 = *(const bf16x8*)&As[wm + fr][ks];
    bf16x8 a1 = *(const bf16x8*)&As[wm + 16 + fr][ks];
    bf16x8 b0 = *(const bf16x8*)&Bs[wn + fr][ks];
    bf16x8 b1 = *(const bf16x8*)&Bs[wn + 16 + fr][ks];
    acc[0][0] = __builtin_amdgcn_mfma_f32_16x16x32_bf16(a0, b0, acc[0][0], 0, 0, 0);
    acc[0][1] = __builtin_amdgcn_mfma_f32_16x16x32_bf16(a0, b1, acc[0][1], 0, 0, 0);
    acc[1][0] = __builtin_amdgcn_mfma_f32_16x16x32_bf16(a1, b0, acc[1][0], 0, 0, 0);
    acc[1][1] = __builtin_amdgcn_mfma_f32_16x16x32_bf16(a1, b1, acc[1][1], 0, 0, 0);
    __syncthreads();
  }
  const bool split = (gridDim.z > 1);
#pragma unroll
  for (int fi = 0; fi < 2; ++fi)
#pragma unroll
    for (int fj = 0; fj < 2; ++fj)
#pragma unroll
      for (int r = 0; r < 4; ++r) {
        const int row = bm + wm + fi * 16 + (lane >> 4) * 4 + r;
        const int col = bn + wn + fj * 16 + fr;
        if (row < M && col < N) {
          const float v = acc[fi][fj][r];
          if (split) atomicAdd(&C[(size_t)row * N + col], v);
          else C[(size_t)row * N + col] = v + (bias ? bias[col] : 0.f);
        }
      }
}

// ---------------------------------------------------------------------------
// Recon-fused GEMM: pred = A(256,K)@B(N,K)^T; epilogue accumulates
// -1/BATCH * X[row,col]*log(pred+1e-6) into out[0].
// ---------------------------------------------------------------------------
__global__ __launch_bounds__(256) void gemm_recon_bf16(
    const u16* __restrict__ A, const u16* __restrict__ B,
    const float* __restrict__ X, float* __restrict__ out, int N, int K) {
  __shared__ u16 As[64][32];
  __shared__ u16 Bs[64][32];
  const int tid = threadIdx.x;
  const int bm = blockIdx.y * 64, bn = blockIdx.x * 64;
  const int w = tid >> 6, lane = tid & 63;
  const int wm = (w >> 1) * 32, wn = (w & 1) * 32;
  const int fr = lane & 15;
  const int ks = (lane >> 4) * 8;
  const int srow = tid >> 2, sseg = (tid & 3) * 8;
  f32x4 acc[2][2] = {};
  for (int kt = 0; kt < K; kt += 32) {
    const int gk = kt + sseg;
    {
      bf16x8 v = *(const bf16x8*)(A + (size_t)(bm + srow) * K + gk);  // M=256 exact
      *(bf16x8*)&As[srow][sseg] = v;
    }
    {
      const int gn = bn + srow;
      bf16x8 v = {0, 0, 0, 0, 0, 0, 0, 0};
      if (gn < N) v = *(const bf16x8*)(B + (size_t)gn * K + gk);
      *(bf16x8*)&Bs[srow][sseg] = v;
    }
    __syncthreads();
    bf16x8 a0 = *(const bf16x8*)&As[wm + fr][ks];
    bf16x8 a1 = *(const bf16x8*)&As[wm + 16 + fr][ks];
    bf16x8 b0 = *(const bf16x8*)&Bs[wn + fr][ks];
    bf16x8 b1 = *(const bf16x8*)&Bs[wn + 16 + fr][ks];
    acc[0][0] = __builtin_amdgcn_mfma_f32_16x16x32_bf16(a0, b0, acc[0][0], 0, 0, 0);
    acc[0][1] = __builtin_amdgcn_mfma_f32_16x16x32_bf16(a0, b1, acc[0][1], 0, 0, 0);
    acc[1][0] = __builtin_amdgcn_mfma_f32_16x16x32_bf16(a1, b0, acc[1][0], 0, 0, 0);
    acc[1][1] = __builtin_amdgcn_mfma_f32_16x16x32_bf16(a1, b1, acc[1][1], 0, 0, 0);
    __syncthreads();
  }
  float local = 0.f;
#pragma unroll
  for (int fi = 0; fi < 2; ++fi)
#pragma unroll
    for (int fj = 0; fj < 2; ++fj)
#pragma unroll
      for (int r = 0; r < 4; ++r) {
        const int row = bm + wm + fi * 16 + (lane >> 4) * 4 + r;
        const int col = bn + wn + fj * 16 + fr;
        if (col < N)
          local += X[(size_t)row * N + col] * logf(acc[fi][fj][r] + 1e-6f);
      }
  for (int o = 32; o > 0; o >>= 1) local += __shfl_down(local, o);
  if (lane == 0) atomicAdd(out, -local * (1.f / BATCH));
}

// ---------------------------------------------------------------------------
// H fp32 (BATCH x N): out_b = bf16(BN(relu(H + b))). grid=N, block=BATCH.
// ---------------------------------------------------------------------------
__global__ __launch_bounds__(256) void bias_relu_bn(
    const float* __restrict__ H, const float* __restrict__ b,
    const float* __restrict__ g, const float* __restrict__ be,
    u16* __restrict__ outb, int N) {
  const int c = blockIdx.x;
  const int r = threadIdx.x;
  float v = fmaxf(H[(size_t)r * N + c] + b[c], 0.f);
  __shared__ float red[BATCH];
  red[r] = v; __syncthreads();
  for (int s = BATCH / 2; s > 0; s >>= 1) { if (r < s) red[r] += red[r + s]; __syncthreads(); }
  const float mean = red[0] * (1.f / BATCH);
  __syncthreads();
  const float d = v - mean;
  red[r] = d * d; __syncthreads();
  for (int s = BATCH / 2; s > 0; s >>= 1) { if (r < s) red[r] += red[r + s]; __syncthreads(); }
  const float var = red[0] * (1.f / BATCH);
  outb[(size_t)r * N + c] = f2bf(d * rsqrtf(var + BN_EPS) * g[c] + be[c]);
}

// ---------------------------------------------------------------------------
// KL + theta = softmax(mu) -> bf16 padded to NTP. grid=BATCH, block=128.
// ---------------------------------------------------------------------------
__global__ __launch_bounds__(128) void row_kl_theta(
    const float* __restrict__ muR, const float* __restrict__ lsR,
    const float* __restrict__ mu_b, const float* __restrict__ ls_b,
    u16* __restrict__ thb, float* __restrict__ kl_out) {
  const int b = blockIdx.x;
  const int t = threadIdx.x;
  const bool act = (t < NT);
  float mu = 0.f, ls = 0.f, term = 0.f;
  if (act) {
    mu = muR[(size_t)b * NT + t] + mu_b[t];
    ls = 2.f * (lsR[(size_t)b * NT + t] + ls_b[t]);
    term = 1.f + ls - mu * mu - expf(ls);
  }
  __shared__ float red[128];
  red[t] = act ? term : 0.f; __syncthreads();
  for (int s = 64; s > 0; s >>= 1) { if (t < s) red[t] += red[t + s]; __syncthreads(); }
  if (t == 0) atomicAdd(kl_out, -0.5f * red[0] * (1.f / BATCH));
  __syncthreads();
  red[t] = act ? mu : -INFINITY; __syncthreads();
  for (int s = 64; s > 0; s >>= 1) { if (t < s) red[t] = fmaxf(red[t], red[t + s]); __syncthreads(); }
  const float mx = red[0];
  __syncthreads();
  const float e = act ? expf(mu - mx) : 0.f;
  red[t] = e; __syncthreads();
  for (int s = 64; s > 0; s >>= 1) { if (t < s) red[t] += red[t + s]; __syncthreads(); }
  thb[(size_t)b * NTP + t] = act ? f2bf(e / red[0]) : (u16)0;
}

// --------------------------- CSR build kernels -----------------------------
__global__ __launch_bounds__(256) void deg_count(
    const int* __restrict__ ei, int* __restrict__ deg) {
  int e = blockIdx.x * 256 + threadIdx.x;
  if (e >= E_TOTAL) return;
  const int d = (e < N_EDGES) ? ei[N_EDGES + e] : e - N_EDGES;
  atomicAdd(&deg[d], 1);
}

// single block, 1024 threads: exclusive scan of deg -> row_ptr
__global__ __launch_bounds__(1024) void scan_deg(
    const int* __restrict__ deg, int* __restrict__ row_ptr) {
  __shared__ int sums[1024];
  const int t = threadIdx.x;
  constexpr int PER = (N_NODES + 1023) / 1024;   // 40
  const int base = t * PER;
  int local = 0;
  for (int i = 0; i < PER; ++i) {
    int idx = base + i;
    if (idx < N_NODES) local += deg[idx];
  }
  sums[t] = local; __syncthreads();
  for (int o = 1; o < 1024; o <<= 1) {
    int v = (t >= o) ? sums[t - o] : 0;
    __syncthreads();
    sums[t] += v;
    __syncthreads();
  }
  int run = (t == 0) ? 0 : sums[t - 1];
  for (int i = 0; i < PER; ++i) {
    int idx = base + i;
    if (idx < N_NODES) { row_ptr[idx] = run; run += deg[idx]; }
  }
  if (t == 1023) row_ptr[N_NODES] = sums[1023];
}

__global__ __launch_bounds__(256) void csr_scatter(
    const int* __restrict__ ei, const int* __restrict__ row_ptr,
    int* __restrict__ cur, int* __restrict__ csr_src) {
  int e = blockIdx.x * 256 + threadIdx.x;
  if (e >= E_TOTAL) return;
  int s, d;
  if (e < N_EDGES) { s = ei[e]; d = ei[N_EDGES + e]; }
  else { s = d = e - N_EDGES; }
  const int pos = atomicAdd(&cur[d], 1);
  csr_src[row_ptr[d] + pos] = s;
}

// ---------------------------------------------------------------------------
// Fused GATv2 layer: one wave per destination node. Online softmax over the
// destination's incoming edges + aggregation in registers; epilogue fuses
// +bias, relu, bf16 cast. C = 128 (layer1) or 64 (layer2).
// ---------------------------------------------------------------------------
template <int C>
__global__ __launch_bounds__(256) void gat_fused(
    const float* __restrict__ xl, const float* __restrict__ xr,
    const float* __restrict__ att, const float* __restrict__ bias,
    const int* __restrict__ row_ptr, const int* __restrict__ csr_src,
    u16* __restrict__ out_b) {
  constexpr int CPL = C / 64;          // channels per lane
  const int lane = threadIdx.x & 63;
  const int d = blockIdx.x * 4 + (threadIdx.x >> 6);
  if (d >= N_NODES) return;
  float xrv[CPL], attv[CPL], acc[CPL];
#pragma unroll
  for (int i = 0; i < CPL; ++i) {
    const int c = lane + i * 64;
    xrv[i] = xr[(size_t)d * C + c];
    attv[i] = att[c];
    acc[i] = 0.f;
  }
  float m = -INFINITY, den = 0.f;
  const int beg = row_ptr[d], end = row_ptr[d + 1];
  for (int p = beg; p < end; ++p) {
    const int s = csr_src[p];
    float xlv[CPL];
    float part = 0.f;
#pragma unroll
    for (int i = 0; i < CPL; ++i) {
      const int c = lane + i * 64;
      xlv[i] = xl[(size_t)s * C + c];
      float x = xlv[i] + xrv[i];
      x = (x > 0.f) ? x : 0.2f * x;
      part += x * attv[i];
    }
    for (int o = 32; o > 0; o >>= 1) part += __shfl_down(part, o);
    const float logit = __shfl(part, 0);
    const float nm = fmaxf(m, logit);
    const float scale = expf(m - nm);        // 0 on first iteration
    const float ex = expf(logit - nm);
    den = den * scale + ex;
#pragma unroll
    for (int i = 0; i < CPL; ++i) acc[i] = acc[i] * scale + ex * xlv[i];
    m = nm;
  }
  const float inv = 1.f / (den + 1e-16f);
#pragma unroll
  for (int i = 0; i < CPL; ++i) {
    const int c = lane + i * 64;
    out_b[(size_t)d * C + c] = f2bf(fmaxf(acc[i] * inv + bias[c], 0.f));
  }
}

__global__ __launch_bounds__(256) void fill_u32(u32* __restrict__ p, u32 v, int n) {
  int i = blockIdx.x * 256 + threadIdx.x;
  if (i < n) p[i] = v;
}

// ----------------------- column softmax statistics -------------------------
__global__ __launch_bounds__(256) void col_max(
    const float* __restrict__ L, u32* __restrict__ gmx, int M) {
  __shared__ u32 s[NT];
  for (int i = threadIdx.x; i < NT; i += 256) s[i] = 0x007FFFFFu;  // f2o(-inf)
  __syncthreads();
  const int r0 = blockIdx.x * 128;
  const int cnt = min(128, M - r0) * NT;
  const float* base = L + (size_t)r0 * NT;
  for (int i = threadIdx.x; i < cnt; i += 256) {
    const int c = i % NT;
    atomicMax(&s[c], f2o(base[i]));
  }
  __syncthreads();
  for (int i = threadIdx.x; i < NT; i += 256) atomicMax(&gmx[i], s[i]);
}

__global__ __launch_bounds__(256) void col_sumexp(
    const float* __restrict__ L, const u32* __restrict__ gmx,
    float* __restrict__ gden, int M) {
  __shared__ float mx[NT];
  __shared__ float s[NT];
  for (int i = threadIdx.x; i < NT; i += 256) { mx[i] = o2f(gmx[i]); s[i] = 0.f; }
  __syncthreads();
  const int r0 = blockIdx.x * 128;
  const int cnt = min(128, M - r0) * NT;
  const float* base = L + (size_t)r0 * NT;
  for (int i = threadIdx.x; i < cnt; i += 256) {
    const int c = i % NT;
    atomicAdd(&s[c], expf(base[i] - mx[c]));
  }
  __syncthreads();
  for (int i = threadIdx.x; i < NT; i += 256) atomicAdd(&gden[i], s[i]);
}

__global__ __launch_bounds__(256) void beta_norm(
    const float* __restrict__ L, const u32* __restrict__ gmx,
    const float* __restrict__ gden, u16* __restrict__ out, int M) {
  __shared__ float mx[NT], inv[NT];
  for (int i = threadIdx.x; i < NT; i += 256) { mx[i] = o2f(gmx[i]); inv[i] = 1.f / gden[i]; }
  __syncthreads();
  const size_t total = (size_t)M * NTP;
  size_t i = (size_t)blockIdx.x * 256 + threadIdx.x;
  const size_t stride = (size_t)gridDim.x * 256;
  for (; i < total; i += stride) {
    const int c = (int)(i & (NTP - 1));
    u16 v = 0;
    if (c < NT) {
      const size_t r = i >> 7;
      v = f2bf(expf(L[r * NT + c] - mx[c]) * inv[c]);
    }
    out[i] = v;
  }
}

// ---------------------------------------------------------------------------
extern "C" void kernel_launch(void* const* d_in, const int* in_sizes, int n_in,
                              void* d_out, int out_size, void* d_ws, size_t ws_size,
                              hipStream_t stream) {
  const float* Gene  = (const float*)d_in[0];
  const float* GeneN = (const float*)d_in[1];
  const float* Peak  = (const float*)d_in[2];
  const float* PeakN = (const float*)d_in[3];
  const float* feat  = (const float*)d_in[4];
  const float* Wl1 = (const float*)d_in[5];  const float* bl1 = (const float*)d_in[6];
  const float* Wr1 = (const float*)d_in[7];  const float* br1 = (const float*)d_in[8];
  const float* att1 = (const float*)d_in[9]; const float* bias1 = (const float*)d_in[10];
  const float* Wl2 = (const float*)d_in[11]; const float* bl2 = (const float*)d_in[12];
  const float* Wr2 = (const float*)d_in[13]; const float* br2 = (const float*)d_in[14];
  const float* att2 = (const float*)d_in[15]; const float* bias2 = (const float*)d_in[16];
  const float* gW1 = (const float*)d_in[17]; const float* gb1 = (const float*)d_in[18];
  const float* gg1 = (const float*)d_in[19]; const float* gbe1 = (const float*)d_in[20];
  const float* gW2 = (const float*)d_in[21]; const float* gb2 = (const float*)d_in[22];
  const float* gg2 = (const float*)d_in[23]; const float* gbe2 = (const float*)d_in[24];
  const float* pW1 = (const float*)d_in[25]; const float* pb1 = (const float*)d_in[26];
  const float* pg1 = (const float*)d_in[27]; const float* pbe1 = (const float*)d_in[28];
  const float* pW2 = (const float*)d_in[29]; const float* pb2 = (const float*)d_in[30];
  const float* pg2 = (const float*)d_in[31]; const float* pbe2 = (const float*)d_in[32];
  const float* mu_W = (const float*)d_in[33]; const float* mu_b = (const float*)d_in[34];
  const float* ls_W = (const float*)d_in[35]; const float* ls_b = (const float*)d_in[36];
  const float* alphas_W = (const float*)d_in[37];
  const float* alphas_star_W = (const float*)d_in[38];
  const int* ei = (const int*)d_in[39];
  float* out = (float*)d_out;
  (void)in_sizes; (void)n_in; (void)ws_size;

  // ---- workspace layout (bytes) ----
  char* base = (char*)d_ws;
  size_t off = 0;
  auto A = [&](size_t bytes) { void* p = base + off; off += (bytes + 255) & ~(size_t)255; return p; };
  int* deg     = (int*)A((size_t)N_NODES * 4);
  int* row_ptr = (int*)A((size_t)(N_NODES + 1) * 4);
  int* cur     = (int*)A((size_t)N_NODES * 4);
  int* csr_src = (int*)A((size_t)E_TOTAL * 4);
  float* h1g = (float*)A((size_t)BATCH * TH * 4);
  float* h2g = (float*)A((size_t)BATCH * TH * 4);
  float* h1p = (float*)A((size_t)BATCH * TH * 4);
  float* h2p = (float*)A((size_t)BATCH * TH * 4);
  u16* h1gb = (u16*)A((size_t)BATCH * TH * 2);
  u16* h2gb = (u16*)A((size_t)BATCH * TH * 2);
  u16* h1pb = (u16*)A((size_t)BATCH * TH * 2);
  u16* h2pb = (u16*)A((size_t)BATCH * TH * 2);
  float* mu_d = (float*)A((size_t)BATCH * NT * 4);
  float* ls_d = (float*)A((size_t)BATCH * NT * 4);
  float* mu_j = (float*)A((size_t)BATCH * NT * 4);
  float* ls_j = (float*)A((size_t)BATCH * NT * 4);
  u16* th_db = (u16*)A((size_t)BATCH * NTP * 2);
  u16* th_jb = (u16*)A((size_t)BATCH * NTP * 2);
  float* lgg = (float*)A((size_t)NUM_GENE * NT * 4);
  float* lgp = (float*)A((size_t)NUM_PEAK * NT * 4);
  u16* betagb = (u16*)A((size_t)NUM_GENE * NTP * 2);
  u16* betapb = (u16*)A((size_t)NUM_PEAK * NTP * 2);
  u16* featb = (u16*)A((size_t)N_NODES * EMB * 2);
  u16* gW2b = (u16*)A((size_t)TH * TH * 2);
  u16* pW2b = (u16*)A((size_t)TH * TH * 2);
  u16* muWb = (u16*)A((size_t)NT * TH * 2);
  u16* lsWb = (u16*)A((size_t)NT * TH * 2);
  u16* Wl1b = (u16*)A((size_t)HID * EMB * 2);
  u16* Wr1b = (u16*)A((size_t)HID * EMB * 2);
  u16* Wl2b = (u16*)A((size_t)EMB * HID * 2);
  u16* Wr2b = (u16*)A((size_t)EMB * HID * 2);
  u16* aWb  = (u16*)A((size_t)NT * EMB * 2);
  u16* aSWb = (u16*)A((size_t)NT * EMB * 2);
  u16* agg1b = (u16*)A((size_t)N_NODES * HID * 2);
  u16* embb  = (u16*)A((size_t)N_NODES * EMB * 2);
  u32* cmax = (u32*)A(2 * NT * 4);
  float* cden = (float*)A(2 * NT * 4);
  // overlap region: encoder bf16 staging, then GAT fp32 projection buffers
  char* R = (char*)A(61440000);
  u16* GeneNb = (u16*)R;                               // 6,144,000 B
  u16* gW1b   = (u16*)(R + 6144000);                   // 12,288,000 B
  u16* PeakNb = (u16*)(R + 18432000);                  // 14,336,000 B
  u16* pW1b   = (u16*)(R + 32768000);                  // 28,672,000 B
  float* xl1  = (float*)R;                             // 20,480,000 B
  float* xr1  = (float*)(R + 20480000);                // 20,480,000 B
  float* xl2  = (float*)R;                             // 10,240,000 B (after L1 done)
  float* xr2  = (float*)(R + 10240000);                // 10,240,000 B

  auto cdiv = [](int a, int b) { return (a + b - 1) / b; };
  auto Z = [&](void* p, size_t bytes) { hipMemsetAsync(p, 0, bytes, stream); };
  auto cvt = [&](const float* s, u16* d, size_t n) {
    int blk = (int)min((size_t)2048, (n / (256 * 8)) + 1);
    cvt_f2b<<<blk, 256, 0, stream>>>(s, d, n);
  };

  Z(d_out, (size_t)out_size * sizeof(float));

  // ---- CSR build (edge structure shared by both GAT layers) ----
  Z(deg, (size_t)N_NODES * 4);
  Z(cur, (size_t)N_NODES * 4);
  deg_count<<<cdiv(E_TOTAL, 256), 256, 0, stream>>>(ei, deg);
  scan_deg<<<1, 1024, 0, stream>>>(deg, row_ptr);
  csr_scatter<<<cdiv(E_TOTAL, 256), 256, 0, stream>>>(ei, row_ptr, cur, csr_src);

  // ---- conversions for encoder L1 ----
  cvt(GeneN, GeneNb, (size_t)BATCH * NUM_GENE);
  cvt(PeakN, PeakNb, (size_t)BATCH * NUM_PEAK);
  cvt(gW1, gW1b, (size_t)TH * NUM_GENE);
  cvt(pW1, pW1b, (size_t)TH * NUM_PEAK);
  cvt(gW2, gW2b, (size_t)TH * TH);
  cvt(pW2, pW2b, (size_t)TH * TH);
  cvt(mu_W, muWb, (size_t)NT * TH);
  cvt(ls_W, lsWb, (size_t)NT * TH);

  // ================= encoders =================
  const int ksp = 16;
  const int chG = ((cdiv(NUM_GENE, ksp) + 31) / 32) * 32;   // 768
  const int chP = ((cdiv(NUM_PEAK, ksp) + 31) / 32) * 32;   // 1760
  Z(h1g, (size_t)BATCH * TH * 4);
  Z(h1p, (size_t)BATCH * TH * 4);
  gemm_bt_bf16<<<dim3(TH / 64, BATCH / 64, ksp), 256, 0, stream>>>(GeneNb, gW1b, h1g, nullptr, BATCH, TH, NUM_GENE, chG);
  gemm_bt_bf16<<<dim3(TH / 64, BATCH / 64, ksp), 256, 0, stream>>>(PeakNb, pW1b, h1p, nullptr, BATCH, TH, NUM_PEAK, chP);
  bias_relu_bn<<<TH, BATCH, 0, stream>>>(h1g, gb1, gg1, gbe1, h1gb, TH);
  bias_relu_bn<<<TH, BATCH, 0, stream>>>(h1p, pb1, pg1, pbe1, h1pb, TH);
  gemm_bt_bf16<<<dim3(TH / 64, BATCH / 64, 1), 256, 0, stream>>>(h1gb, gW2b, h2g, nullptr, BATCH, TH, TH, TH);
  gemm_bt_bf16<<<dim3(TH / 64, BATCH / 64, 1), 256, 0, stream>>>(h1pb, pW2b, h2p, nullptr, BATCH, TH, TH, TH);
  bias_relu_bn<<<TH, BATCH, 0, stream>>>(h2g, gb2, gg2, gbe2, h2gb, TH);
  bias_relu_bn<<<TH, BATCH, 0, stream>>>(h2p, pb2, pg2, pbe2, h2pb, TH);
  gemm_bt_bf16<<<dim3(2, BATCH / 64, 1), 256, 0, stream>>>(h2gb, muWb, mu_d, nullptr, BATCH, NT, TH, TH);
  gemm_bt_bf16<<<dim3(2, BATCH / 64, 1), 256, 0, stream>>>(h2gb, lsWb, ls_d, nullptr, BATCH, NT, TH, TH);
  gemm_bt_bf16<<<dim3(2, BATCH / 64, 1), 256, 0, stream>>>(h2pb, muWb, mu_j, nullptr, BATCH, NT, TH, TH);
  gemm_bt_bf16<<<dim3(2, BATCH / 64, 1), 256, 0, stream>>>(h2pb, lsWb, ls_j, nullptr, BATCH, NT, TH, TH);
  row_kl_theta<<<BATCH, 128, 0, stream>>>(mu_d, ls_d, mu_b, ls_b, th_db, out + 1);
  row_kl_theta<<<BATCH, 128, 0, stream>>>(mu_j, ls_j, mu_b, ls_b, th_jb, out + 1);

  // ---- conversions for GAT ----
  cvt(feat, featb, (size_t)N_NODES * EMB);
  cvt(Wl1, Wl1b, (size_t)HID * EMB);
  cvt(Wr1, Wr1b, (size_t)HID * EMB);
  cvt(Wl2, Wl2b, (size_t)EMB * HID);
  cvt(Wr2, Wr2b, (size_t)EMB * HID);
  cvt(alphas_W, aWb, (size_t)NT * EMB);
  cvt(alphas_star_W, aSWb, (size_t)NT * EMB);

  // ================= GAT layer 1 =================
  gemm_bt_bf16<<<dim3(HID / 64, N_NODES / 64, 1), 256, 0, stream>>>(featb, Wl1b, xl1, bl1, N_NODES, HID, EMB, EMB);
  gemm_bt_bf16<<<dim3(HID / 64, N_NODES / 64, 1), 256, 0, stream>>>(featb, Wr1b, xr1, br1, N_NODES, HID, EMB, EMB);
  gat_fused<HID><<<N_NODES / 4, 256, 0, stream>>>(xl1, xr1, att1, bias1, row_ptr, csr_src, agg1b);

  // ================= GAT layer 2 =================
  gemm_bt_bf16<<<dim3(EMB / 64, N_NODES / 64, 1), 256, 0, stream>>>(agg1b, Wl2b, xl2, bl2, N_NODES, EMB, HID, HID);
  gemm_bt_bf16<<<dim3(EMB / 64, N_NODES / 64, 1), 256, 0, stream>>>(agg1b, Wr2b, xr2, br2, N_NODES, EMB, HID, HID);
  gat_fused<EMB><<<N_NODES / 4, 256, 0, stream>>>(xl2, xr2, att2, bias2, row_ptr, csr_src, embb);

  // ================= topic heads =================
  gemm_bt_bf16<<<dim3(2, cdiv(NUM_GENE, 64), 1), 256, 0, stream>>>(embb + (size_t)NUM_PEAK * EMB, aWb, lgg, nullptr, NUM_GENE, NT, EMB, EMB);
  gemm_bt_bf16<<<dim3(2, cdiv(NUM_PEAK, 64), 1), 256, 0, stream>>>(embb, aSWb, lgp, nullptr, NUM_PEAK, NT, EMB, EMB);
  fill_u32<<<1, 256, 0, stream>>>(cmax, 0x007FFFFFu, 2 * NT);
  Z(cden, 2 * NT * 4);
  col_max<<<cdiv(NUM_GENE, 128), 256, 0, stream>>>(lgg, cmax, NUM_GENE);
  col_max<<<cdiv(NUM_PEAK, 128), 256, 0, stream>>>(lgp, cmax + NT, NUM_PEAK);
  col_sumexp<<<cdiv(NUM_GENE, 128), 256, 0, stream>>>(lgg, cmax, cden, NUM_GENE);
  col_sumexp<<<cdiv(NUM_PEAK, 128), 256, 0, stream>>>(lgp, cmax + NT, cden + NT, NUM_PEAK);
  beta_norm<<<2048, 256, 0, stream>>>(lgg, cmax, cden, betagb, NUM_GENE);
  beta_norm<<<2048, 256, 0, stream>>>(lgp, cmax + NT, cden + NT, betapb, NUM_PEAK);

  // ================= fused preds + recon =================
  gemm_recon_bf16<<<dim3(cdiv(NUM_GENE, 64), BATCH / 64, 1), 256, 0, stream>>>(th_db, betagb, Gene, out, NUM_GENE, NTP);
  gemm_recon_bf16<<<dim3(cdiv(NUM_PEAK, 64), BATCH / 64, 1), 256, 0, stream>>>(th_jb, betapb, Peak, out, NUM_PEAK, NTP);
}

// Round 4
// 746.473 us; speedup vs baseline: 3.0063x; 1.1920x over previous
//
#include <hip/hip_runtime.h>
#include <cstdint>
#include <cstddef>

using u16 = unsigned short;
using u32 = unsigned int;
typedef __attribute__((ext_vector_type(8))) short bf16x8;
typedef __attribute__((ext_vector_type(4))) float f32x4;

static constexpr int NUM_PEAK = 28000;
static constexpr int NUM_GENE = 12000;
static constexpr int N_NODES  = NUM_PEAK + NUM_GENE;   // 40000
static constexpr int N_EDGES  = 640000;
static constexpr int E_TOTAL  = N_EDGES + N_NODES;     // 680000
static constexpr int NT       = 100;
static constexpr int NT2      = 200;                   // mu+ls combined
static constexpr int NTP      = 128;                   // padded topic stride
static constexpr int TH       = 512;
static constexpr int EMB      = 64;
static constexpr int HID      = 128;
static constexpr int BATCH    = 256;
#define BN_EPS 1e-5f

__device__ __forceinline__ u16 f2bf(float f) {
  u32 b = __float_as_uint(f);
  return (u16)((b + 0x7FFFu + ((b >> 16) & 1u)) >> 16);
}
__device__ __forceinline__ float bf2f(u16 u) {
  return __uint_as_float((u32)u << 16);
}
__device__ __forceinline__ u32 f2o(float f) {
  u32 u = __float_as_uint(f);
  return (u & 0x80000000u) ? ~u : (u | 0x80000000u);
}
__device__ __forceinline__ float o2f(u32 u) {
  return (u & 0x80000000u) ? __uint_as_float(u & 0x7fffffffu) : __uint_as_float(~u);
}

// ---------------------------------------------------------------------------
// fp32 -> bf16 convert, 8 elems/thread
// ---------------------------------------------------------------------------
__global__ __launch_bounds__(256) void cvt_f2b(const float* __restrict__ x,
                                               u16* __restrict__ y, size_t n) {
  size_t i = ((size_t)blockIdx.x * 256 + threadIdx.x) * 8;
  const size_t stride = (size_t)gridDim.x * 256 * 8;
  for (; i + 8 <= n; i += stride) {
    float4 a = *(const float4*)(x + i);
    float4 b = *(const float4*)(x + i + 4);
    ushort4 o0{f2bf(a.x), f2bf(a.y), f2bf(a.z), f2bf(a.w)};
    ushort4 o1{f2bf(b.x), f2bf(b.y), f2bf(b.z), f2bf(b.w)};
    *(ushort4*)(y + i) = o0;
    *(ushort4*)(y + i + 4) = o1;
  }
  if (blockIdx.x == 0 && threadIdx.x == 0)
    for (size_t j = n & ~7ull; j < n; ++j) y[j] = f2bf(x[j]);
}

// ---------------------------------------------------------------------------
// bf16 MFMA GEMM: C(M,N) = A(M,K) @ B(N,K)^T. 64x64 tile, 4 waves, BK=32.
// split (gridDim.z>1): atomicAdd into pre-zeroed fp32 C.
// else if Cb: bf16 store of (v + bias). else: fp32 store of (v + bias).
// ---------------------------------------------------------------------------
__global__ __launch_bounds__(256) void gemm_bt_bf16(
    const u16* __restrict__ A, const u16* __restrict__ B,
    float* __restrict__ C, u16* __restrict__ Cb, const float* __restrict__ bias,
    int M, int N, int K, int chunk) {
  __shared__ u16 As[64][32];
  __shared__ u16 Bs[64][32];
  const int tid = threadIdx.x;
  const int bm = blockIdx.y * 64, bn = blockIdx.x * 64;
  const int k0 = blockIdx.z * chunk;
  const int k1 = min(K, k0 + chunk);
  const int w = tid >> 6, lane = tid & 63;
  const int wm = (w >> 1) * 32, wn = (w & 1) * 32;
  const int fr = lane & 15;
  const int ks = (lane >> 4) * 8;
  const int srow = tid >> 2, sseg = (tid & 3) * 8;
  f32x4 acc[2][2] = {};
  for (int kt = k0; kt < k1; kt += 32) {
    const int gk = kt + sseg;
    {
      const int gm = bm + srow;
      bf16x8 v = {0, 0, 0, 0, 0, 0, 0, 0};
      if (gm < M) {
        if (gk + 8 <= k1) v = *(const bf16x8*)(A + (size_t)gm * K + gk);
        else if (gk < k1)
          for (int e = 0; e < k1 - gk; ++e) ((short*)&v)[e] = (short)A[(size_t)gm * K + gk + e];
      }
      *(bf16x8*)&As[srow][sseg] = v;
    }
    {
      const int gn = bn + srow;
      bf16x8 v = {0, 0, 0, 0, 0, 0, 0, 0};
      if (gn < N) {
        if (gk + 8 <= k1) v = *(const bf16x8*)(B + (size_t)gn * K + gk);
        else if (gk < k1)
          for (int e = 0; e < k1 - gk; ++e) ((short*)&v)[e] = (short)B[(size_t)gn * K + gk + e];
      }
      *(bf16x8*)&Bs[srow][sseg] = v;
    }
    __syncthreads();
    bf16x8 a0 = *(const bf16x8*)&As[wm + fr][ks];
    bf16x8 a1 = *(const bf16x8*)&As[wm + 16 + fr][ks];
    bf16x8 b0 = *(const bf16x8*)&Bs[wn + fr][ks];
    bf16x8 b1 = *(const bf16x8*)&Bs[wn + 16 + fr][ks];
    acc[0][0] = __builtin_amdgcn_mfma_f32_16x16x32_bf16(a0, b0, acc[0][0], 0, 0, 0);
    acc[0][1] = __builtin_amdgcn_mfma_f32_16x16x32_bf16(a0, b1, acc[0][1], 0, 0, 0);
    acc[1][0] = __builtin_amdgcn_mfma_f32_16x16x32_bf16(a1, b0, acc[1][0], 0, 0, 0);
    acc[1][1] = __builtin_amdgcn_mfma_f32_16x16x32_bf16(a1, b1, acc[1][1], 0, 0, 0);
    __syncthreads();
  }
  const bool split = (gridDim.z > 1);
#pragma unroll
  for (int fi = 0; fi < 2; ++fi)
#pragma unroll
    for (int fj = 0; fj < 2; ++fj)
#pragma unroll
      for (int r = 0; r < 4; ++r) {
        const int row = bm + wm + fi * 16 + (lane >> 4) * 4 + r;
        const int col = bn + wn + fj * 16 + fr;
        if (row < M && col < N) {
          const float v = acc[fi][fj][r];
          if (split) atomicAdd(&C[(size_t)row * N + col], v);
          else if (Cb) Cb[(size_t)row * N + col] = f2bf(v + (bias ? bias[col] : 0.f));
          else C[(size_t)row * N + col] = v + (bias ? bias[col] : 0.f);
        }
      }
}

// ---------------------------------------------------------------------------
// Recon-fused GEMM: pred = A(256,K)@B(N,K)^T; epilogue accumulates
// -1/BATCH * X[row,col]*log(pred+1e-6) into out[0].
// ---------------------------------------------------------------------------
__global__ __launch_bounds__(256) void gemm_recon_bf16(
    const u16* __restrict__ A, const u16* __restrict__ B,
    const float* __restrict__ X, float* __restrict__ out, int N, int K) {
  __shared__ u16 As[64][32];
  __shared__ u16 Bs[64][32];
  const int tid = threadIdx.x;
  const int bm = blockIdx.y * 64, bn = blockIdx.x * 64;
  const int w = tid >> 6, lane = tid & 63;
  const int wm = (w >> 1) * 32, wn = (w & 1) * 32;
  const int fr = lane & 15;
  const int ks = (lane >> 4) * 8;
  const int srow = tid >> 2, sseg = (tid & 3) * 8;
  f32x4 acc[2][2] = {};
  for (int kt = 0; kt < K; kt += 32) {
    const int gk = kt + sseg;
    {
      bf16x8 v = *(const bf16x8*)(A + (size_t)(bm + srow) * K + gk);  // M=256 exact
      *(bf16x8*)&As[srow][sseg] = v;
    }
    {
      const int gn = bn + srow;
      bf16x8 v = {0, 0, 0, 0, 0, 0, 0, 0};
      if (gn < N) v = *(const bf16x8*)(B + (size_t)gn * K + gk);
      *(bf16x8*)&Bs[srow][sseg] = v;
    }
    __syncthreads();
    bf16x8 a0 = *(const bf16x8*)&As[wm + fr][ks];
    bf16x8 a1 = *(const bf16x8*)&As[wm + 16 + fr][ks];
    bf16x8 b0 = *(const bf16x8*)&Bs[wn + fr][ks];
    bf16x8 b1 = *(const bf16x8*)&Bs[wn + 16 + fr][ks];
    acc[0][0] = __builtin_amdgcn_mfma_f32_16x16x32_bf16(a0, b0, acc[0][0], 0, 0, 0);
    acc[0][1] = __builtin_amdgcn_mfma_f32_16x16x32_bf16(a0, b1, acc[0][1], 0, 0, 0);
    acc[1][0] = __builtin_amdgcn_mfma_f32_16x16x32_bf16(a1, b0, acc[1][0], 0, 0, 0);
    acc[1][1] = __builtin_amdgcn_mfma_f32_16x16x32_bf16(a1, b1, acc[1][1], 0, 0, 0);
    __syncthreads();
  }
  float local = 0.f;
#pragma unroll
  for (int fi = 0; fi < 2; ++fi)
#pragma unroll
    for (int fj = 0; fj < 2; ++fj)
#pragma unroll
      for (int r = 0; r < 4; ++r) {
        const int row = bm + wm + fi * 16 + (lane >> 4) * 4 + r;
        const int col = bn + wn + fj * 16 + fr;
        if (col < N)
          local += X[(size_t)row * N + col] * logf(acc[fi][fj][r] + 1e-6f);
      }
  for (int o = 32; o > 0; o >>= 1) local += __shfl_down(local, o);
  if (lane == 0) atomicAdd(out, -local * (1.f / BATCH));
}

// ---------------------------------------------------------------------------
// H fp32 (BATCH x N): out_b = bf16(BN(relu(H + b))). grid=N, block=BATCH.
// ---------------------------------------------------------------------------
__global__ __launch_bounds__(256) void bias_relu_bn(
    const float* __restrict__ H, const float* __restrict__ b,
    const float* __restrict__ g, const float* __restrict__ be,
    u16* __restrict__ outb, int N) {
  const int c = blockIdx.x;
  const int r = threadIdx.x;
  float v = fmaxf(H[(size_t)r * N + c] + b[c], 0.f);
  __shared__ float red[BATCH];
  red[r] = v; __syncthreads();
  for (int s = BATCH / 2; s > 0; s >>= 1) { if (r < s) red[r] += red[r + s]; __syncthreads(); }
  const float mean = red[0] * (1.f / BATCH);
  __syncthreads();
  const float d = v - mean;
  red[r] = d * d; __syncthreads();
  for (int s = BATCH / 2; s > 0; s >>= 1) { if (r < s) red[r] += red[r + s]; __syncthreads(); }
  const float var = red[0] * (1.f / BATCH);
  outb[(size_t)r * N + c] = f2bf(d * rsqrtf(var + BN_EPS) * g[c] + be[c]);
}

// ---------------------------------------------------------------------------
// KL + theta = softmax(mu) -> bf16 padded to NTP. ml holds [mu|ls] rows of
// length NT2. grid=BATCH, block=128.
// ---------------------------------------------------------------------------
__global__ __launch_bounds__(128) void row_kl_theta(
    const float* __restrict__ ml,
    const float* __restrict__ mu_b, const float* __restrict__ ls_b,
    u16* __restrict__ thb, float* __restrict__ kl_out) {
  const int b = blockIdx.x;
  const int t = threadIdx.x;
  const bool act = (t < NT);
  float mu = 0.f, ls = 0.f, term = 0.f;
  if (act) {
    mu = ml[(size_t)b * NT2 + t] + mu_b[t];
    ls = 2.f * (ml[(size_t)b * NT2 + NT + t] + ls_b[t]);
    term = 1.f + ls - mu * mu - expf(ls);
  }
  __shared__ float red[128];
  red[t] = act ? term : 0.f; __syncthreads();
  for (int s = 64; s > 0; s >>= 1) { if (t < s) red[t] += red[t + s]; __syncthreads(); }
  if (t == 0) atomicAdd(kl_out, -0.5f * red[0] * (1.f / BATCH));
  __syncthreads();
  red[t] = act ? mu : -INFINITY; __syncthreads();
  for (int s = 64; s > 0; s >>= 1) { if (t < s) red[t] = fmaxf(red[t], red[t + s]); __syncthreads(); }
  const float mx = red[0];
  __syncthreads();
  const float e = act ? expf(mu - mx) : 0.f;
  red[t] = e; __syncthreads();
  for (int s = 64; s > 0; s >>= 1) { if (t < s) red[t] += red[t + s]; __syncthreads(); }
  thb[(size_t)b * NTP + t] = act ? f2bf(e / red[0]) : (u16)0;
}

// --------------------------- CSR build kernels -----------------------------
__global__ __launch_bounds__(256) void deg_count(
    const int* __restrict__ ei, int* __restrict__ deg) {
  int e = blockIdx.x * 256 + threadIdx.x;
  if (e >= E_TOTAL) return;
  const int d = (e < N_EDGES) ? ei[N_EDGES + e] : e - N_EDGES;
  atomicAdd(&deg[d], 1);
}

__global__ __launch_bounds__(1024) void scan_deg(
    const int* __restrict__ deg, int* __restrict__ row_ptr) {
  __shared__ int sums[1024];
  const int t = threadIdx.x;
  constexpr int PER = (N_NODES + 1023) / 1024;   // 40
  const int base = t * PER;
  int local = 0;
  for (int i = 0; i < PER; ++i) {
    int idx = base + i;
    if (idx < N_NODES) local += deg[idx];
  }
  sums[t] = local; __syncthreads();
  for (int o = 1; o < 1024; o <<= 1) {
    int v = (t >= o) ? sums[t - o] : 0;
    __syncthreads();
    sums[t] += v;
    __syncthreads();
  }
  int run = (t == 0) ? 0 : sums[t - 1];
  for (int i = 0; i < PER; ++i) {
    int idx = base + i;
    if (idx < N_NODES) { row_ptr[idx] = run; run += deg[idx]; }
  }
  if (t == 1023) row_ptr[N_NODES] = sums[1023];
}

__global__ __launch_bounds__(256) void csr_scatter(
    const int* __restrict__ ei, const int* __restrict__ row_ptr,
    int* __restrict__ cur, int* __restrict__ csr_src) {
  int e = blockIdx.x * 256 + threadIdx.x;
  if (e >= E_TOTAL) return;
  int s, d;
  if (e < N_EDGES) { s = ei[e]; d = ei[N_EDGES + e]; }
  else { s = d = e - N_EDGES; }
  const int pos = atomicAdd(&cur[d], 1);
  csr_src[row_ptr[d] + pos] = s;
}

// ---------------------------------------------------------------------------
// Fused GATv2 layer, 4-way edge-parallel. One wave per destination; four
// 16-lane groups each run an independent online softmax over every 4th
// incoming edge, merged at the end. bf16 inputs (xl, xr), bf16 output.
// ---------------------------------------------------------------------------
template <int C>
__global__ __launch_bounds__(256) void gat_fused(
    const u16* __restrict__ xl, const u16* __restrict__ xr,
    const float* __restrict__ att, const float* __restrict__ bias,
    const int* __restrict__ row_ptr, const int* __restrict__ csr_src,
    u16* __restrict__ out_b) {
  constexpr int CPL = C / 16;          // channels per lane (8 or 4)
  const int lane = threadIdx.x & 63;
  const int g = lane >> 4, li = lane & 15;
  const int d = blockIdx.x * 4 + (threadIdx.x >> 6);
  if (d >= N_NODES) return;
  const int c0 = li * CPL;
  float xrv[CPL], attv[CPL], acc[CPL];
#pragma unroll
  for (int i = 0; i < CPL; ++i) {
    xrv[i] = bf2f(xr[(size_t)d * C + c0 + i]);
    attv[i] = att[c0 + i];
    acc[i] = 0.f;
  }
  float m = -INFINITY, den = 0.f;
  const int end = row_ptr[d + 1];
  int p = row_ptr[d] + g;
  int s = (p < end) ? csr_src[p] : 0;
  while (p < end) {
    const int sn = (p + 4 < end) ? csr_src[p + 4] : 0;
    float xlv[CPL];
    float part = 0.f;
#pragma unroll
    for (int i = 0; i < CPL; ++i) {
      xlv[i] = bf2f(xl[(size_t)s * C + c0 + i]);
      float x = xlv[i] + xrv[i];
      x = (x > 0.f) ? x : 0.2f * x;
      part += x * attv[i];
    }
    part += __shfl_xor(part, 1);
    part += __shfl_xor(part, 2);
    part += __shfl_xor(part, 4);
    part += __shfl_xor(part, 8);
    const float logit = part;
    const float nm = fmaxf(m, logit);
    const float scale = expf(m - nm);
    const float ex = expf(logit - nm);
    den = den * scale + ex;
#pragma unroll
    for (int i = 0; i < CPL; ++i) acc[i] = acc[i] * scale + ex * xlv[i];
    m = nm;
    p += 4;
    s = sn;
  }
  // merge the 4 group states (flash-style)
  float M = m;
  M = fmaxf(M, __shfl_xor(M, 16));
  M = fmaxf(M, __shfl_xor(M, 32));
  const float gs = expf(m - M);          // 0 for empty groups (m = -inf)
  den *= gs;
  den += __shfl_xor(den, 16);
  den += __shfl_xor(den, 32);
  const float inv = 1.f / (den + 1e-16f);
  float va[CPL];
#pragma unroll
  for (int i = 0; i < CPL; ++i) {
    float a = acc[i] * gs;
    a += __shfl_xor(a, 16);
    a += __shfl_xor(a, 32);
    va[i] = a;
  }
  if (g == 0) {
#pragma unroll
    for (int i = 0; i < CPL; ++i)
      out_b[(size_t)d * C + c0 + i] = f2bf(fmaxf(va[i] * inv + bias[c0 + i], 0.f));
  }
}

__global__ __launch_bounds__(256) void fill_u32(u32* __restrict__ p, u32 v, int n) {
  int i = blockIdx.x * 256 + threadIdx.x;
  if (i < n) p[i] = v;
}

// ----------------------- column softmax statistics -------------------------
__global__ __launch_bounds__(256) void col_max(
    const float* __restrict__ L, u32* __restrict__ gmx, int M) {
  __shared__ u32 s[NT];
  for (int i = threadIdx.x; i < NT; i += 256) s[i] = 0x007FFFFFu;  // f2o(-inf)
  __syncthreads();
  const int r0 = blockIdx.x * 128;
  const int cnt = min(128, M - r0) * NT;
  const float* base = L + (size_t)r0 * NT;
  for (int i = threadIdx.x; i < cnt; i += 256) {
    const int c = i % NT;
    atomicMax(&s[c], f2o(base[i]));
  }
  __syncthreads();
  for (int i = threadIdx.x; i < NT; i += 256) atomicMax(&gmx[i], s[i]);
}

__global__ __launch_bounds__(256) void col_sumexp(
    const float* __restrict__ L, const u32* __restrict__ gmx,
    float* __restrict__ gden, int M) {
  __shared__ float mx[NT];
  __shared__ float s[NT];
  for (int i = threadIdx.x; i < NT; i += 256) { mx[i] = o2f(gmx[i]); s[i] = 0.f; }
  __syncthreads();
  const int r0 = blockIdx.x * 128;
  const int cnt = min(128, M - r0) * NT;
  const float* base = L + (size_t)r0 * NT;
  for (int i = threadIdx.x; i < cnt; i += 256) {
    const int c = i % NT;
    atomicAdd(&s[c], expf(base[i] - mx[c]));
  }
  __syncthreads();
  for (int i = threadIdx.x; i < NT; i += 256) atomicAdd(&gden[i], s[i]);
}

__global__ __launch_bounds__(256) void beta_norm(
    const float* __restrict__ L, const u32* __restrict__ gmx,
    const float* __restrict__ gden, u16* __restrict__ out, int M) {
  __shared__ float mx[NT], inv[NT];
  for (int i = threadIdx.x; i < NT; i += 256) { mx[i] = o2f(gmx[i]); inv[i] = 1.f / gden[i]; }
  __syncthreads();
  const size_t total = (size_t)M * NTP;
  size_t i = (size_t)blockIdx.x * 256 + threadIdx.x;
  const size_t stride = (size_t)gridDim.x * 256;
  for (; i < total; i += stride) {
    const int c = (int)(i & (NTP - 1));
    u16 v = 0;
    if (c < NT) {
      const size_t r = i >> 7;
      v = f2bf(expf(L[r * NT + c] - mx[c]) * inv[c]);
    }
    out[i] = v;
  }
}

// ---------------------------------------------------------------------------
extern "C" void kernel_launch(void* const* d_in, const int* in_sizes, int n_in,
                              void* d_out, int out_size, void* d_ws, size_t ws_size,
                              hipStream_t stream) {
  const float* Gene  = (const float*)d_in[0];
  const float* GeneN = (const float*)d_in[1];
  const float* Peak  = (const float*)d_in[2];
  const float* PeakN = (const float*)d_in[3];
  const float* feat  = (const float*)d_in[4];
  const float* Wl1 = (const float*)d_in[5];  const float* bl1 = (const float*)d_in[6];
  const float* Wr1 = (const float*)d_in[7];  const float* br1 = (const float*)d_in[8];
  const float* att1 = (const float*)d_in[9]; const float* bias1 = (const float*)d_in[10];
  const float* Wl2 = (const float*)d_in[11]; const float* bl2 = (const float*)d_in[12];
  const float* Wr2 = (const float*)d_in[13]; const float* br2 = (const float*)d_in[14];
  const float* att2 = (const float*)d_in[15]; const float* bias2 = (const float*)d_in[16];
  const float* gW1 = (const float*)d_in[17]; const float* gb1 = (const float*)d_in[18];
  const float* gg1 = (const float*)d_in[19]; const float* gbe1 = (const float*)d_in[20];
  const float* gW2 = (const float*)d_in[21]; const float* gb2 = (const float*)d_in[22];
  const float* gg2 = (const float*)d_in[23]; const float* gbe2 = (const float*)d_in[24];
  const float* pW1 = (const float*)d_in[25]; const float* pb1 = (const float*)d_in[26];
  const float* pg1 = (const float*)d_in[27]; const float* pbe1 = (const float*)d_in[28];
  const float* pW2 = (const float*)d_in[29]; const float* pb2 = (const float*)d_in[30];
  const float* pg2 = (const float*)d_in[31]; const float* pbe2 = (const float*)d_in[32];
  const float* mu_W = (const float*)d_in[33]; const float* mu_b = (const float*)d_in[34];
  const float* ls_W = (const float*)d_in[35]; const float* ls_b = (const float*)d_in[36];
  const float* alphas_W = (const float*)d_in[37];
  const float* alphas_star_W = (const float*)d_in[38];
  const int* ei = (const int*)d_in[39];
  float* out = (float*)d_out;
  (void)in_sizes; (void)n_in; (void)ws_size;

  // ---- workspace layout (bytes) ----
  char* base = (char*)d_ws;
  size_t off = 0;
  auto A = [&](size_t bytes) { void* p = base + off; off += (bytes + 255) & ~(size_t)255; return p; };
  int* deg     = (int*)A((size_t)N_NODES * 4);
  int* row_ptr = (int*)A((size_t)(N_NODES + 1) * 4);
  int* cur     = (int*)A((size_t)N_NODES * 4);
  int* csr_src = (int*)A((size_t)E_TOTAL * 4);
  float* h1g = (float*)A((size_t)BATCH * TH * 4);
  float* h2g = (float*)A((size_t)BATCH * TH * 4);
  float* h1p = (float*)A((size_t)BATCH * TH * 4);
  float* h2p = (float*)A((size_t)BATCH * TH * 4);
  u16* h1gb = (u16*)A((size_t)BATCH * TH * 2);
  u16* h2gb = (u16*)A((size_t)BATCH * TH * 2);
  u16* h1pb = (u16*)A((size_t)BATCH * TH * 2);
  u16* h2pb = (u16*)A((size_t)BATCH * TH * 2);
  float* ml_d = (float*)A((size_t)BATCH * NT2 * 4);
  float* ml_j = (float*)A((size_t)BATCH * NT2 * 4);
  u16* th_db = (u16*)A((size_t)BATCH * NTP * 2);
  u16* th_jb = (u16*)A((size_t)BATCH * NTP * 2);
  float* lgg = (float*)A((size_t)NUM_GENE * NT * 4);
  float* lgp = (float*)A((size_t)NUM_PEAK * NT * 4);
  u16* betagb = (u16*)A((size_t)NUM_GENE * NTP * 2);
  u16* betapb = (u16*)A((size_t)NUM_PEAK * NTP * 2);
  u16* featb = (u16*)A((size_t)N_NODES * EMB * 2);
  u16* gW2b = (u16*)A((size_t)TH * TH * 2);
  u16* pW2b = (u16*)A((size_t)TH * TH * 2);
  u16* mlWb = (u16*)A((size_t)NT2 * TH * 2);
  u16* Wl1b = (u16*)A((size_t)HID * EMB * 2);
  u16* Wr1b = (u16*)A((size_t)HID * EMB * 2);
  u16* Wl2b = (u16*)A((size_t)EMB * HID * 2);
  u16* Wr2b = (u16*)A((size_t)EMB * HID * 2);
  u16* aWb  = (u16*)A((size_t)NT * EMB * 2);
  u16* aSWb = (u16*)A((size_t)NT * EMB * 2);
  u16* agg1b = (u16*)A((size_t)N_NODES * HID * 2);
  u16* embb  = (u16*)A((size_t)N_NODES * EMB * 2);
  u32* cmax = (u32*)A(2 * NT * 4);
  float* cden = (float*)A(2 * NT * 4);
  // overlap region: encoder bf16 staging, then GAT bf16 projection buffers
  char* R = (char*)A(61440000);
  u16* GeneNb = (u16*)R;                               // 6,144,000 B
  u16* gW1b   = (u16*)(R + 6144000);                   // 12,288,000 B
  u16* PeakNb = (u16*)(R + 18432000);                  // 14,336,000 B
  u16* pW1b   = (u16*)(R + 32768000);                  // 28,672,000 B
  u16* xl1b   = (u16*)R;                               // 10,240,000 B
  u16* xr1b   = (u16*)(R + 10240000);                  // 10,240,000 B
  u16* xl2b   = (u16*)(R + 20480000);                  //  5,120,000 B
  u16* xr2b   = (u16*)(R + 25600000);                  //  5,120,000 B

  auto cdiv = [](int a, int b) { return (a + b - 1) / b; };
  auto Z = [&](void* p, size_t bytes) { hipMemsetAsync(p, 0, bytes, stream); };
  auto cvt = [&](const float* s, u16* d, size_t n) {
    int blk = (int)min((size_t)2048, (n / (256 * 8)) + 1);
    cvt_f2b<<<blk, 256, 0, stream>>>(s, d, n);
  };

  Z(d_out, (size_t)out_size * sizeof(float));

  // ---- CSR build (edge structure shared by both GAT layers) ----
  Z(deg, (size_t)N_NODES * 4);
  Z(cur, (size_t)N_NODES * 4);
  deg_count<<<cdiv(E_TOTAL, 256), 256, 0, stream>>>(ei, deg);
  scan_deg<<<1, 1024, 0, stream>>>(deg, row_ptr);
  csr_scatter<<<cdiv(E_TOTAL, 256), 256, 0, stream>>>(ei, row_ptr, cur, csr_src);

  // ---- conversions for encoder ----
  cvt(GeneN, GeneNb, (size_t)BATCH * NUM_GENE);
  cvt(PeakN, PeakNb, (size_t)BATCH * NUM_PEAK);
  cvt(gW1, gW1b, (size_t)TH * NUM_GENE);
  cvt(pW1, pW1b, (size_t)TH * NUM_PEAK);
  cvt(gW2, gW2b, (size_t)TH * TH);
  cvt(pW2, pW2b, (size_t)TH * TH);
  cvt(mu_W, mlWb, (size_t)NT * TH);
  cvt(ls_W, mlWb + (size_t)NT * TH, (size_t)NT * TH);

  // ================= encoders =================
  const int ksp = 16;
  const int chG = ((cdiv(NUM_GENE, ksp) + 31) / 32) * 32;   // 768
  const int chP = ((cdiv(NUM_PEAK, ksp) + 31) / 32) * 32;   // 1760
  Z(h1g, (size_t)BATCH * TH * 4);
  Z(h1p, (size_t)BATCH * TH * 4);
  gemm_bt_bf16<<<dim3(TH / 64, BATCH / 64, ksp), 256, 0, stream>>>(GeneNb, gW1b, h1g, nullptr, nullptr, BATCH, TH, NUM_GENE, chG);
  gemm_bt_bf16<<<dim3(TH / 64, BATCH / 64, ksp), 256, 0, stream>>>(PeakNb, pW1b, h1p, nullptr, nullptr, BATCH, TH, NUM_PEAK, chP);
  bias_relu_bn<<<TH, BATCH, 0, stream>>>(h1g, gb1, gg1, gbe1, h1gb, TH);
  bias_relu_bn<<<TH, BATCH, 0, stream>>>(h1p, pb1, pg1, pbe1, h1pb, TH);
  gemm_bt_bf16<<<dim3(TH / 64, BATCH / 64, 1), 256, 0, stream>>>(h1gb, gW2b, h2g, nullptr, nullptr, BATCH, TH, TH, TH);
  gemm_bt_bf16<<<dim3(TH / 64, BATCH / 64, 1), 256, 0, stream>>>(h1pb, pW2b, h2p, nullptr, nullptr, BATCH, TH, TH, TH);
  bias_relu_bn<<<TH, BATCH, 0, stream>>>(h2g, gb2, gg2, gbe2, h2gb, TH);
  bias_relu_bn<<<TH, BATCH, 0, stream>>>(h2p, pb2, pg2, pbe2, h2pb, TH);
  gemm_bt_bf16<<<dim3(cdiv(NT2, 64), BATCH / 64, 1), 256, 0, stream>>>(h2gb, mlWb, ml_d, nullptr, nullptr, BATCH, NT2, TH, TH);
  gemm_bt_bf16<<<dim3(cdiv(NT2, 64), BATCH / 64, 1), 256, 0, stream>>>(h2pb, mlWb, ml_j, nullptr, nullptr, BATCH, NT2, TH, TH);
  row_kl_theta<<<BATCH, 128, 0, stream>>>(ml_d, mu_b, ls_b, th_db, out + 1);
  row_kl_theta<<<BATCH, 128, 0, stream>>>(ml_j, mu_b, ls_b, th_jb, out + 1);

  // ---- conversions for GAT ----
  cvt(feat, featb, (size_t)N_NODES * EMB);
  cvt(Wl1, Wl1b, (size_t)HID * EMB);
  cvt(Wr1, Wr1b, (size_t)HID * EMB);
  cvt(Wl2, Wl2b, (size_t)EMB * HID);
  cvt(Wr2, Wr2b, (size_t)EMB * HID);
  cvt(alphas_W, aWb, (size_t)NT * EMB);
  cvt(alphas_star_W, aSWb, (size_t)NT * EMB);

  // ================= GAT layer 1 =================
  gemm_bt_bf16<<<dim3(HID / 64, N_NODES / 64, 1), 256, 0, stream>>>(featb, Wl1b, nullptr, xl1b, bl1, N_NODES, HID, EMB, EMB);
  gemm_bt_bf16<<<dim3(HID / 64, N_NODES / 64, 1), 256, 0, stream>>>(featb, Wr1b, nullptr, xr1b, br1, N_NODES, HID, EMB, EMB);
  gat_fused<HID><<<N_NODES / 4, 256, 0, stream>>>(xl1b, xr1b, att1, bias1, row_ptr, csr_src, agg1b);

  // ================= GAT layer 2 =================
  gemm_bt_bf16<<<dim3(EMB / 64, N_NODES / 64, 1), 256, 0, stream>>>(agg1b, Wl2b, nullptr, xl2b, bl2, N_NODES, EMB, HID, HID);
  gemm_bt_bf16<<<dim3(EMB / 64, N_NODES / 64, 1), 256, 0, stream>>>(agg1b, Wr2b, nullptr, xr2b, br2, N_NODES, EMB, HID, HID);
  gat_fused<EMB><<<N_NODES / 4, 256, 0, stream>>>(xl2b, xr2b, att2, bias2, row_ptr, csr_src, embb);

  // ================= topic heads =================
  gemm_bt_bf16<<<dim3(2, cdiv(NUM_GENE, 64), 1), 256, 0, stream>>>(embb + (size_t)NUM_PEAK * EMB, aWb, lgg, nullptr, nullptr, NUM_GENE, NT, EMB, EMB);
  gemm_bt_bf16<<<dim3(2, cdiv(NUM_PEAK, 64), 1), 256, 0, stream>>>(embb, aSWb, lgp, nullptr, nullptr, NUM_PEAK, NT, EMB, EMB);
  fill_u32<<<1, 256, 0, stream>>>(cmax, 0x007FFFFFu, 2 * NT);
  Z(cden, 2 * NT * 4);
  col_max<<<cdiv(NUM_GENE, 128), 256, 0, stream>>>(lgg, cmax, NUM_GENE);
  col_max<<<cdiv(NUM_PEAK, 128), 256, 0, stream>>>(lgp, cmax + NT, NUM_PEAK);
  col_sumexp<<<cdiv(NUM_GENE, 128), 256, 0, stream>>>(lgg, cmax, cden, NUM_GENE);
  col_sumexp<<<cdiv(NUM_PEAK, 128), 256, 0, stream>>>(lgp, cmax + NT, cden + NT, NUM_PEAK);
  beta_norm<<<2048, 256, 0, stream>>>(lgg, cmax, cden, betagb, NUM_GENE);
  beta_norm<<<2048, 256, 0, stream>>>(lgp, cmax + NT, cden + NT, betapb, NUM_PEAK);

  // ================= fused preds + recon =================
  gemm_recon_bf16<<<dim3(cdiv(NUM_GENE, 64), BATCH / 64, 1), 256, 0, stream>>>(th_db, betagb, Gene, out, NUM_GENE, NTP);
  gemm_recon_bf16<<<dim3(cdiv(NUM_PEAK, 64), BATCH / 64, 1), 256, 0, stream>>>(th_jb, betapb, Peak, out, NUM_PEAK, NTP);
}

// Round 5
// 639.814 us; speedup vs baseline: 3.5074x; 1.1667x over previous
//
#include <hip/hip_runtime.h>
#include <cstdint>
#include <cstddef>

using u16 = unsigned short;
using u32 = unsigned int;
typedef __attribute__((ext_vector_type(8))) short bf16x8;
typedef __attribute__((ext_vector_type(4))) float f32x4;

static constexpr int NUM_PEAK = 28000;
static constexpr int NUM_GENE = 12000;
static constexpr int N_NODES  = NUM_PEAK + NUM_GENE;   // 40000
static constexpr int N_EDGES  = 640000;
static constexpr int E_TOTAL  = N_EDGES + N_NODES;     // 680000
static constexpr int NT       = 100;
static constexpr int NT2      = 200;                   // mu+ls combined
static constexpr int NTP      = 128;                   // padded topic stride
static constexpr int TH       = 512;
static constexpr int EMB      = 64;
static constexpr int HID      = 128;
static constexpr int BATCH    = 256;
#define BN_EPS 1e-5f

__device__ __forceinline__ u16 f2bf(float f) {
  u32 b = __float_as_uint(f);
  return (u16)((b + 0x7FFFu + ((b >> 16) & 1u)) >> 16);
}
__device__ __forceinline__ float bf2f(u16 u) {
  return __uint_as_float((u32)u << 16);
}
__device__ __forceinline__ u32 f2o(float f) {
  u32 u = __float_as_uint(f);
  return (u & 0x80000000u) ? ~u : (u | 0x80000000u);
}
__device__ __forceinline__ float o2f(u32 u) {
  return (u & 0x80000000u) ? __uint_as_float(u & 0x7fffffffu) : __uint_as_float(~u);
}

// ---------------------------------------------------------------------------
// Batched fp32->bf16 conversion: all tensors in ONE launch. Each block does
// exactly 2048 elements of its segment (found via start-block table).
// ---------------------------------------------------------------------------
struct CvtJobs {
  const float* src[16];
  u16* dst[16];
  u32 n[16];
  u32 start[16];   // first block of segment i
  int count;
};

__global__ __launch_bounds__(256) void cvt_all(CvtJobs J) {
  const int bid = blockIdx.x;
  int seg = 0;
  while (seg + 1 < J.count && bid >= (int)J.start[seg + 1]) ++seg;
  const float* __restrict__ src = J.src[seg];
  u16* __restrict__ dst = J.dst[seg];
  const u32 n = J.n[seg];
  const u32 i = (u32)(bid - J.start[seg]) * 2048u + threadIdx.x * 8u;
  if (i + 8 <= n) {
    float4 a = *(const float4*)(src + i);
    float4 b = *(const float4*)(src + i + 4);
    ushort4 o0{f2bf(a.x), f2bf(a.y), f2bf(a.z), f2bf(a.w)};
    ushort4 o1{f2bf(b.x), f2bf(b.y), f2bf(b.z), f2bf(b.w)};
    *(ushort4*)(dst + i) = o0;
    *(ushort4*)(dst + i + 4) = o1;
  } else {
    for (u32 j = i; j < n; ++j) dst[j] = f2bf(src[j]);
  }
}

// ---------------------------------------------------------------------------
// bf16 MFMA GEMM: C(M,N) = A(M,K) @ B(N,K)^T. 64x64 tile, 4 waves, BK=32.
// Dual mode (dual=1, gridDim.z=2): blockIdx.z selects problem g0/g1.
// Split mode (dual=0, gridDim.z>1): k-split with atomicAdd into zeroed C.
// ---------------------------------------------------------------------------
struct GP {
  const u16* A; const u16* B; float* C; u16* Cb; const float* bias;
  int M, N, K, chunk;
};

__global__ __launch_bounds__(256) void gemm_bt_bf16(GP g0, GP g1, int dual) {
  const GP& g = (dual && blockIdx.z) ? g1 : g0;
  const int M = g.M, N = g.N, K = g.K;
  __shared__ u16 As[64][32];
  __shared__ u16 Bs[64][32];
  const int tid = threadIdx.x;
  const int bm = blockIdx.y * 64, bn = blockIdx.x * 64;
  if (bm >= M || bn >= N) return;
  const int k0 = dual ? 0 : blockIdx.z * g.chunk;
  const int k1 = min(K, k0 + g.chunk);
  const int w = tid >> 6, lane = tid & 63;
  const int wm = (w >> 1) * 32, wn = (w & 1) * 32;
  const int fr = lane & 15;
  const int ks = (lane >> 4) * 8;
  const int srow = tid >> 2, sseg = (tid & 3) * 8;
  f32x4 acc[2][2] = {};
  for (int kt = k0; kt < k1; kt += 32) {
    const int gk = kt + sseg;
    {
      const int gm = bm + srow;
      bf16x8 v = {0, 0, 0, 0, 0, 0, 0, 0};
      if (gm < M) {
        if (gk + 8 <= k1) v = *(const bf16x8*)(g.A + (size_t)gm * K + gk);
        else if (gk < k1)
          for (int e = 0; e < k1 - gk; ++e) ((short*)&v)[e] = (short)g.A[(size_t)gm * K + gk + e];
      }
      *(bf16x8*)&As[srow][sseg] = v;
    }
    {
      const int gn = bn + srow;
      bf16x8 v = {0, 0, 0, 0, 0, 0, 0, 0};
      if (gn < N) {
        if (gk + 8 <= k1) v = *(const bf16x8*)(g.B + (size_t)gn * K + gk);
        else if (gk < k1)
          for (int e = 0; e < k1 - gk; ++e) ((short*)&v)[e] = (short)g.B[(size_t)gn * K + gk + e];
      }
      *(bf16x8*)&Bs[srow][sseg] = v;
    }
    __syncthreads();
    bf16x8 a0 = *(const bf16x8*)&As[wm + fr][ks];
    bf16x8 a1 = *(const bf16x8*)&As[wm + 16 + fr][ks];
    bf16x8 b0 = *(const bf16x8*)&Bs[wn + fr][ks];
    bf16x8 b1 = *(const bf16x8*)&Bs[wn + 16 + fr][ks];
    acc[0][0] = __builtin_amdgcn_mfma_f32_16x16x32_bf16(a0, b0, acc[0][0], 0, 0, 0);
    acc[0][1] = __builtin_amdgcn_mfma_f32_16x16x32_bf16(a0, b1, acc[0][1], 0, 0, 0);
    acc[1][0] = __builtin_amdgcn_mfma_f32_16x16x32_bf16(a1, b0, acc[1][0], 0, 0, 0);
    acc[1][1] = __builtin_amdgcn_mfma_f32_16x16x32_bf16(a1, b1, acc[1][1], 0, 0, 0);
    __syncthreads();
  }
  const bool split = (!dual && gridDim.z > 1);
#pragma unroll
  for (int fi = 0; fi < 2; ++fi)
#pragma unroll
    for (int fj = 0; fj < 2; ++fj)
#pragma unroll
      for (int r = 0; r < 4; ++r) {
        const int row = bm + wm + fi * 16 + (lane >> 4) * 4 + r;
        const int col = bn + wn + fj * 16 + fr;
        if (row < M && col < N) {
          const float v = acc[fi][fj][r];
          if (split) atomicAdd(&g.C[(size_t)row * N + col], v);
          else if (g.Cb) g.Cb[(size_t)row * N + col] = f2bf(v + (g.bias ? g.bias[col] : 0.f));
          else g.C[(size_t)row * N + col] = v + (g.bias ? g.bias[col] : 0.f);
        }
      }
}

// ---------------------------------------------------------------------------
// Fused recon for BOTH matrices in one launch. pred = theta @ beta^T (K=128
// exact). Theta fragments hoisted to registers; beta fragments read straight
// from global (L2-resident); pred staged in LDS; X-pass coalesced; __logf.
// grid = (tiles_g + tiles_p, 4 row-blocks).
// ---------------------------------------------------------------------------
__global__ __launch_bounds__(256) void recon_fused(
    const u16* __restrict__ thg, const u16* __restrict__ betag,
    const float* __restrict__ Xg, int Ng, int tiles_g,
    const u16* __restrict__ thp, const u16* __restrict__ betap,
    const float* __restrict__ Xp, int Np, float* __restrict__ out) {
  __shared__ float pred[64][65];
  int ct = blockIdx.x;
  const u16* A; const u16* B; const float* X; int N;
  if (ct < tiles_g) { A = thg; B = betag; X = Xg; N = Ng; }
  else { ct -= tiles_g; A = thp; B = betap; X = Xp; N = Np; }
  const int bm = blockIdx.y * 64, bn = ct * 64;
  const int tid = threadIdx.x, w = tid >> 6, lane = tid & 63;
  const int wm = (w >> 1) * 32, wn = (w & 1) * 32;
  const int fr = lane & 15, ks = (lane >> 4) * 8;
  const u16* Ar0 = A + (size_t)(bm + wm + fr) * NTP;
  const u16* Ar1 = A + (size_t)(bm + wm + 16 + fr) * NTP;
  bf16x8 a0[4], a1[4];
#pragma unroll
  for (int kt = 0; kt < 4; ++kt) {
    a0[kt] = *(const bf16x8*)(Ar0 + kt * 32 + ks);
    a1[kt] = *(const bf16x8*)(Ar1 + kt * 32 + ks);
  }
  const int gn0 = min(bn + wn + fr, N - 1);
  const int gn1 = min(bn + wn + 16 + fr, N - 1);
  const u16* Br0 = B + (size_t)gn0 * NTP;
  const u16* Br1 = B + (size_t)gn1 * NTP;
  f32x4 acc[2][2] = {};
#pragma unroll
  for (int kt = 0; kt < 4; ++kt) {
    bf16x8 b0 = *(const bf16x8*)(Br0 + kt * 32 + ks);
    bf16x8 b1 = *(const bf16x8*)(Br1 + kt * 32 + ks);
    acc[0][0] = __builtin_amdgcn_mfma_f32_16x16x32_bf16(a0[kt], b0, acc[0][0], 0, 0, 0);
    acc[0][1] = __builtin_amdgcn_mfma_f32_16x16x32_bf16(a0[kt], b1, acc[0][1], 0, 0, 0);
    acc[1][0] = __builtin_amdgcn_mfma_f32_16x16x32_bf16(a1[kt], b0, acc[1][0], 0, 0, 0);
    acc[1][1] = __builtin_amdgcn_mfma_f32_16x16x32_bf16(a1[kt], b1, acc[1][1], 0, 0, 0);
  }
#pragma unroll
  for (int fi = 0; fi < 2; ++fi)
#pragma unroll
    for (int fj = 0; fj < 2; ++fj)
#pragma unroll
      for (int r = 0; r < 4; ++r)
        pred[wm + fi * 16 + (lane >> 4) * 4 + r][wn + fj * 16 + fr] = acc[fi][fj][r];
  __syncthreads();
  float local = 0.f;
#pragma unroll
  for (int k = 0; k < 16; ++k) {
    const int idx = k * 256 + tid, row = idx >> 6, col = idx & 63;
    if (bn + col < N)
      local += X[(size_t)(bm + row) * N + bn + col] * __logf(pred[row][col] + 1e-6f);
  }
  for (int o = 32; o > 0; o >>= 1) local += __shfl_down(local, o);
  if (lane == 0) atomicAdd(out, -local * (1.f / BATCH));
}

// ---------------------------------------------------------------------------
// Paired bias+relu+BN: gene columns [0,TH), peak columns [TH,2TH).
// ---------------------------------------------------------------------------
__global__ __launch_bounds__(256) void bias_relu_bn2(
    const float* __restrict__ Hg, const float* __restrict__ bg,
    const float* __restrict__ gg, const float* __restrict__ beg,
    u16* __restrict__ og,
    const float* __restrict__ Hp, const float* __restrict__ bp,
    const float* __restrict__ gp, const float* __restrict__ bep,
    u16* __restrict__ op) {
  int c = blockIdx.x;
  const float *H, *b, *gma, *be; u16* ob;
  if (c < TH) { H = Hg; b = bg; gma = gg; be = beg; ob = og; }
  else { c -= TH; H = Hp; b = bp; gma = gp; be = bep; ob = op; }
  const int r = threadIdx.x;
  float v = fmaxf(H[(size_t)r * TH + c] + b[c], 0.f);
  __shared__ float red[BATCH];
  red[r] = v; __syncthreads();
  for (int s = BATCH / 2; s > 0; s >>= 1) { if (r < s) red[r] += red[r + s]; __syncthreads(); }
  const float mean = red[0] * (1.f / BATCH);
  __syncthreads();
  const float d = v - mean;
  red[r] = d * d; __syncthreads();
  for (int s = BATCH / 2; s > 0; s >>= 1) { if (r < s) red[r] += red[r + s]; __syncthreads(); }
  const float var = red[0] * (1.f / BATCH);
  ob[(size_t)r * TH + c] = f2bf(d * rsqrtf(var + BN_EPS) * gma[c] + be[c]);
}

// ---------------------------------------------------------------------------
// KL + theta for both encoders. grid=(BATCH,2); blockIdx.y selects d/j.
// ---------------------------------------------------------------------------
__global__ __launch_bounds__(128) void row_kl_theta(
    const float* __restrict__ mld, const float* __restrict__ mlj,
    const float* __restrict__ mu_b, const float* __restrict__ ls_b,
    u16* __restrict__ thd, u16* __restrict__ thj, float* __restrict__ kl_out) {
  const float* ml = blockIdx.y ? mlj : mld;
  u16* thb = blockIdx.y ? thj : thd;
  const int b = blockIdx.x;
  const int t = threadIdx.x;
  const bool act = (t < NT);
  float mu = 0.f, ls = 0.f, term = 0.f;
  if (act) {
    mu = ml[(size_t)b * NT2 + t] + mu_b[t];
    ls = 2.f * (ml[(size_t)b * NT2 + NT + t] + ls_b[t]);
    term = 1.f + ls - mu * mu - expf(ls);
  }
  __shared__ float red[128];
  red[t] = act ? term : 0.f; __syncthreads();
  for (int s = 64; s > 0; s >>= 1) { if (t < s) red[t] += red[t + s]; __syncthreads(); }
  if (t == 0) atomicAdd(kl_out, -0.5f * red[0] * (1.f / BATCH));
  __syncthreads();
  red[t] = act ? mu : -INFINITY; __syncthreads();
  for (int s = 64; s > 0; s >>= 1) { if (t < s) red[t] = fmaxf(red[t], red[t + s]); __syncthreads(); }
  const float mx = red[0];
  __syncthreads();
  const float e = act ? expf(mu - mx) : 0.f;
  red[t] = e; __syncthreads();
  for (int s = 64; s > 0; s >>= 1) { if (t < s) red[t] += red[t + s]; __syncthreads(); }
  thb[(size_t)b * NTP + t] = act ? f2bf(e / red[0]) : (u16)0;
}

// --------------------------- CSR build kernels -----------------------------
__global__ __launch_bounds__(256) void deg_count(
    const int* __restrict__ ei, int* __restrict__ deg) {
  int e = blockIdx.x * 256 + threadIdx.x;
  if (e >= E_TOTAL) return;
  const int d = (e < N_EDGES) ? ei[N_EDGES + e] : e - N_EDGES;
  atomicAdd(&deg[d], 1);
}

__global__ __launch_bounds__(1024) void scan_deg(
    const int* __restrict__ deg, int* __restrict__ row_ptr) {
  __shared__ int sums[1024];
  const int t = threadIdx.x;
  constexpr int PER = (N_NODES + 1023) / 1024;   // 40
  const int base = t * PER;
  int local = 0;
  for (int i = 0; i < PER; ++i) {
    int idx = base + i;
    if (idx < N_NODES) local += deg[idx];
  }
  sums[t] = local; __syncthreads();
  for (int o = 1; o < 1024; o <<= 1) {
    int v = (t >= o) ? sums[t - o] : 0;
    __syncthreads();
    sums[t] += v;
    __syncthreads();
  }
  int run = (t == 0) ? 0 : sums[t - 1];
  for (int i = 0; i < PER; ++i) {
    int idx = base + i;
    if (idx < N_NODES) { row_ptr[idx] = run; run += deg[idx]; }
  }
  if (t == 1023) row_ptr[N_NODES] = sums[1023];
}

__global__ __launch_bounds__(256) void csr_scatter(
    const int* __restrict__ ei, const int* __restrict__ row_ptr,
    int* __restrict__ cur, int* __restrict__ csr_src) {
  int e = blockIdx.x * 256 + threadIdx.x;
  if (e >= E_TOTAL) return;
  int s, d;
  if (e < N_EDGES) { s = ei[e]; d = ei[N_EDGES + e]; }
  else { s = d = e - N_EDGES; }
  const int pos = atomicAdd(&cur[d], 1);
  csr_src[row_ptr[d] + pos] = s;
}

// ---------------------------------------------------------------------------
// Fused GATv2 layer, 4-way edge-parallel (16-lane groups), bf16 in/out.
// ---------------------------------------------------------------------------
template <int C>
__global__ __launch_bounds__(256) void gat_fused(
    const u16* __restrict__ xl, const u16* __restrict__ xr,
    const float* __restrict__ att, const float* __restrict__ bias,
    const int* __restrict__ row_ptr, const int* __restrict__ csr_src,
    u16* __restrict__ out_b) {
  constexpr int CPL = C / 16;
  const int lane = threadIdx.x & 63;
  const int g = lane >> 4, li = lane & 15;
  const int d = blockIdx.x * 4 + (threadIdx.x >> 6);
  if (d >= N_NODES) return;
  const int c0 = li * CPL;
  float xrv[CPL], attv[CPL], acc[CPL];
#pragma unroll
  for (int i = 0; i < CPL; ++i) {
    xrv[i] = bf2f(xr[(size_t)d * C + c0 + i]);
    attv[i] = att[c0 + i];
    acc[i] = 0.f;
  }
  float m = -INFINITY, den = 0.f;
  const int end = row_ptr[d + 1];
  int p = row_ptr[d] + g;
  int s = (p < end) ? csr_src[p] : 0;
  while (p < end) {
    const int sn = (p + 4 < end) ? csr_src[p + 4] : 0;
    float xlv[CPL];
    float part = 0.f;
#pragma unroll
    for (int i = 0; i < CPL; ++i) {
      xlv[i] = bf2f(xl[(size_t)s * C + c0 + i]);
      float x = xlv[i] + xrv[i];
      x = (x > 0.f) ? x : 0.2f * x;
      part += x * attv[i];
    }
    part += __shfl_xor(part, 1);
    part += __shfl_xor(part, 2);
    part += __shfl_xor(part, 4);
    part += __shfl_xor(part, 8);
    const float logit = part;
    const float nm = fmaxf(m, logit);
    const float scale = expf(m - nm);
    const float ex = expf(logit - nm);
    den = den * scale + ex;
#pragma unroll
    for (int i = 0; i < CPL; ++i) acc[i] = acc[i] * scale + ex * xlv[i];
    m = nm;
    p += 4;
    s = sn;
  }
  float M = m;
  M = fmaxf(M, __shfl_xor(M, 16));
  M = fmaxf(M, __shfl_xor(M, 32));
  const float gs = expf(m - M);
  den *= gs;
  den += __shfl_xor(den, 16);
  den += __shfl_xor(den, 32);
  const float inv = 1.f / (den + 1e-16f);
  float va[CPL];
#pragma unroll
  for (int i = 0; i < CPL; ++i) {
    float a = acc[i] * gs;
    a += __shfl_xor(a, 16);
    a += __shfl_xor(a, 32);
    va[i] = a;
  }
  if (g == 0) {
#pragma unroll
    for (int i = 0; i < CPL; ++i)
      out_b[(size_t)d * C + c0 + i] = f2bf(fmaxf(va[i] * inv + bias[c0 + i], 0.f));
  }
}

__global__ __launch_bounds__(256) void fill_u32(u32* __restrict__ p, u32 v, int n) {
  int i = blockIdx.x * 256 + threadIdx.x;
  if (i < n) p[i] = v;
}

// ----------------------- column softmax statistics -------------------------
__global__ __launch_bounds__(256) void col_max(
    const float* __restrict__ Lg, const float* __restrict__ Lp,
    u32* __restrict__ gmx) {
  const float* L = blockIdx.y ? Lp : Lg;
  const int M = blockIdx.y ? NUM_PEAK : NUM_GENE;
  u32* mx = gmx + blockIdx.y * NT;
  const int r0 = blockIdx.x * 128;
  if (r0 >= M) return;
  __shared__ u32 s[NT];
  for (int i = threadIdx.x; i < NT; i += 256) s[i] = 0x007FFFFFu;  // f2o(-inf)
  __syncthreads();
  const int cnt = min(128, M - r0) * NT;
  const float* base = L + (size_t)r0 * NT;
  for (int i = threadIdx.x; i < cnt; i += 256) {
    const int c = i % NT;
    atomicMax(&s[c], f2o(base[i]));
  }
  __syncthreads();
  for (int i = threadIdx.x; i < NT; i += 256) atomicMax(&mx[i], s[i]);
}

__global__ __launch_bounds__(256) void col_sumexp(
    const float* __restrict__ Lg, const float* __restrict__ Lp,
    const u32* __restrict__ gmx, float* __restrict__ gden) {
  const float* L = blockIdx.y ? Lp : Lg;
  const int M = blockIdx.y ? NUM_PEAK : NUM_GENE;
  const u32* mxg = gmx + blockIdx.y * NT;
  float* dng = gden + blockIdx.y * NT;
  const int r0 = blockIdx.x * 128;
  if (r0 >= M) return;
  __shared__ float mx[NT];
  __shared__ float s[NT];
  for (int i = threadIdx.x; i < NT; i += 256) { mx[i] = o2f(mxg[i]); s[i] = 0.f; }
  __syncthreads();
  const int cnt = min(128, M - r0) * NT;
  const float* base = L + (size_t)r0 * NT;
  for (int i = threadIdx.x; i < cnt; i += 256) {
    const int c = i % NT;
    atomicAdd(&s[c], expf(base[i] - mx[c]));
  }
  __syncthreads();
  for (int i = threadIdx.x; i < NT; i += 256) atomicAdd(&dng[i], s[i]);
}

__global__ __launch_bounds__(256) void beta_norm(
    const float* __restrict__ Lg, const float* __restrict__ Lp,
    const u32* __restrict__ gmx, const float* __restrict__ gden,
    u16* __restrict__ og, u16* __restrict__ op) {
  const float* L = blockIdx.y ? Lp : Lg;
  const int M = blockIdx.y ? NUM_PEAK : NUM_GENE;
  const u32* mxg = gmx + blockIdx.y * NT;
  const float* dng = gden + blockIdx.y * NT;
  u16* o = blockIdx.y ? op : og;
  __shared__ float mx[NT], inv[NT];
  for (int i = threadIdx.x; i < NT; i += 256) { mx[i] = o2f(mxg[i]); inv[i] = 1.f / dng[i]; }
  __syncthreads();
  const size_t total = (size_t)M * NTP;
  size_t i = (size_t)blockIdx.x * 256 + threadIdx.x;
  const size_t stride = (size_t)gridDim.x * 256;
  for (; i < total; i += stride) {
    const int c = (int)(i & (NTP - 1));
    u16 v = 0;
    if (c < NT) {
      const size_t r = i >> 7;
      v = f2bf(expf(L[r * NT + c] - mx[c]) * inv[c]);
    }
    o[i] = v;
  }
}

// ---------------------------------------------------------------------------
extern "C" void kernel_launch(void* const* d_in, const int* in_sizes, int n_in,
                              void* d_out, int out_size, void* d_ws, size_t ws_size,
                              hipStream_t stream) {
  const float* Gene  = (const float*)d_in[0];
  const float* GeneN = (const float*)d_in[1];
  const float* Peak  = (const float*)d_in[2];
  const float* PeakN = (const float*)d_in[3];
  const float* feat  = (const float*)d_in[4];
  const float* Wl1 = (const float*)d_in[5];  const float* bl1 = (const float*)d_in[6];
  const float* Wr1 = (const float*)d_in[7];  const float* br1 = (const float*)d_in[8];
  const float* att1 = (const float*)d_in[9]; const float* bias1 = (const float*)d_in[10];
  const float* Wl2 = (const float*)d_in[11]; const float* bl2 = (const float*)d_in[12];
  const float* Wr2 = (const float*)d_in[13]; const float* br2 = (const float*)d_in[14];
  const float* att2 = (const float*)d_in[15]; const float* bias2 = (const float*)d_in[16];
  const float* gW1 = (const float*)d_in[17]; const float* gb1 = (const float*)d_in[18];
  const float* gg1 = (const float*)d_in[19]; const float* gbe1 = (const float*)d_in[20];
  const float* gW2 = (const float*)d_in[21]; const float* gb2 = (const float*)d_in[22];
  const float* gg2 = (const float*)d_in[23]; const float* gbe2 = (const float*)d_in[24];
  const float* pW1 = (const float*)d_in[25]; const float* pb1 = (const float*)d_in[26];
  const float* pg1 = (const float*)d_in[27]; const float* pbe1 = (const float*)d_in[28];
  const float* pW2 = (const float*)d_in[29]; const float* pb2 = (const float*)d_in[30];
  const float* pg2 = (const float*)d_in[31]; const float* pbe2 = (const float*)d_in[32];
  const float* mu_W = (const float*)d_in[33]; const float* mu_b = (const float*)d_in[34];
  const float* ls_W = (const float*)d_in[35]; const float* ls_b = (const float*)d_in[36];
  const float* alphas_W = (const float*)d_in[37];
  const float* alphas_star_W = (const float*)d_in[38];
  const int* ei = (const int*)d_in[39];
  float* out = (float*)d_out;
  (void)in_sizes; (void)n_in; (void)ws_size;

  // ---- workspace layout (bytes) ----
  char* base = (char*)d_ws;
  size_t off = 0;
  auto A = [&](size_t bytes) { void* p = base + off; off += (bytes + 255) & ~(size_t)255; return p; };
  int* deg     = (int*)A((size_t)N_NODES * 4);      // deg+cur adjacent (one memset)
  int* cur     = (int*)A((size_t)N_NODES * 4);
  int* row_ptr = (int*)A((size_t)(N_NODES + 1) * 4);
  int* csr_src = (int*)A((size_t)E_TOTAL * 4);
  float* h1g = (float*)A((size_t)BATCH * TH * 4);   // h1g+h1p adjacent (one memset)
  float* h1p = (float*)A((size_t)BATCH * TH * 4);
  float* h2g = (float*)A((size_t)BATCH * TH * 4);
  float* h2p = (float*)A((size_t)BATCH * TH * 4);
  u16* h1gb = (u16*)A((size_t)BATCH * TH * 2);
  u16* h2gb = (u16*)A((size_t)BATCH * TH * 2);
  u16* h1pb = (u16*)A((size_t)BATCH * TH * 2);
  u16* h2pb = (u16*)A((size_t)BATCH * TH * 2);
  float* ml_d = (float*)A((size_t)BATCH * NT2 * 4);
  float* ml_j = (float*)A((size_t)BATCH * NT2 * 4);
  u16* th_db = (u16*)A((size_t)BATCH * NTP * 2);
  u16* th_jb = (u16*)A((size_t)BATCH * NTP * 2);
  float* lgg = (float*)A((size_t)NUM_GENE * NT * 4);
  float* lgp = (float*)A((size_t)NUM_PEAK * NT * 4);
  u16* betagb = (u16*)A((size_t)NUM_GENE * NTP * 2);
  u16* betapb = (u16*)A((size_t)NUM_PEAK * NTP * 2);
  u16* featb = (u16*)A((size_t)N_NODES * EMB * 2);
  u16* gW2b = (u16*)A((size_t)TH * TH * 2);
  u16* pW2b = (u16*)A((size_t)TH * TH * 2);
  u16* mlWb = (u16*)A((size_t)NT2 * TH * 2);
  u16* Wl1b = (u16*)A((size_t)HID * EMB * 2);
  u16* Wr1b = (u16*)A((size_t)HID * EMB * 2);
  u16* Wl2b = (u16*)A((size_t)EMB * HID * 2);
  u16* Wr2b = (u16*)A((size_t)EMB * HID * 2);
  u16* aWb  = (u16*)A((size_t)NT * EMB * 2);
  u16* aSWb = (u16*)A((size_t)NT * EMB * 2);
  u16* agg1b = (u16*)A((size_t)N_NODES * HID * 2);
  u16* embb  = (u16*)A((size_t)N_NODES * EMB * 2);
  u32* cmax = (u32*)A(2 * NT * 4);
  float* cden = (float*)A(2 * NT * 4);
  // overlap region: encoder bf16 staging, then GAT bf16 projection buffers
  char* R = (char*)A(61440000);
  u16* GeneNb = (u16*)R;                               // 6,144,000 B
  u16* gW1b   = (u16*)(R + 6144000);                   // 12,288,000 B
  u16* PeakNb = (u16*)(R + 18432000);                  // 14,336,000 B
  u16* pW1b   = (u16*)(R + 32768000);                  // 28,672,000 B
  u16* xl1b   = (u16*)R;                               // 10,240,000 B
  u16* xr1b   = (u16*)(R + 10240000);                  // 10,240,000 B
  u16* xl2b   = (u16*)(R + 20480000);                  //  5,120,000 B
  u16* xr2b   = (u16*)(R + 25600000);                  //  5,120,000 B

  auto cdiv = [](int a, int b) { return (a + b - 1) / b; };
  auto Z = [&](void* p, size_t bytes) { hipMemsetAsync(p, 0, bytes, stream); };

  Z(d_out, (size_t)out_size * sizeof(float));
  Z(deg, 2 * (size_t)N_NODES * 4);                    // deg + cur

  // ---- CSR build ----
  deg_count<<<cdiv(E_TOTAL, 256), 256, 0, stream>>>(ei, deg);
  scan_deg<<<1, 1024, 0, stream>>>(deg, row_ptr);
  csr_scatter<<<cdiv(E_TOTAL, 256), 256, 0, stream>>>(ei, row_ptr, cur, csr_src);

  // ---- ALL fp32->bf16 conversions in one launch ----
  {
    CvtJobs J = {};
    int c = 0; u32 blocks = 0;
    auto add = [&](const float* s, u16* d, size_t n) {
      J.src[c] = s; J.dst[c] = d; J.n[c] = (u32)n; J.start[c] = blocks;
      blocks += (u32)((n + 2047) / 2048); ++c;
    };
    add(GeneN, GeneNb, (size_t)BATCH * NUM_GENE);
    add(PeakN, PeakNb, (size_t)BATCH * NUM_PEAK);
    add(gW1, gW1b, (size_t)TH * NUM_GENE);
    add(pW1, pW1b, (size_t)TH * NUM_PEAK);
    add(gW2, gW2b, (size_t)TH * TH);
    add(pW2, pW2b, (size_t)TH * TH);
    add(mu_W, mlWb, (size_t)NT * TH);
    add(ls_W, mlWb + (size_t)NT * TH, (size_t)NT * TH);
    add(feat, featb, (size_t)N_NODES * EMB);
    add(Wl1, Wl1b, (size_t)HID * EMB);
    add(Wr1, Wr1b, (size_t)HID * EMB);
    add(Wl2, Wl2b, (size_t)EMB * HID);
    add(Wr2, Wr2b, (size_t)EMB * HID);
    add(alphas_W, aWb, (size_t)NT * EMB);
    add(alphas_star_W, aSWb, (size_t)NT * EMB);
    J.count = c;
    cvt_all<<<blocks, 256, 0, stream>>>(J);
  }

  GP Zp = {};   // zero template

  // ================= encoders =================
  const int ksp = 16;
  const int chG = ((cdiv(NUM_GENE, ksp) + 31) / 32) * 32;   // 768
  const int chP = ((cdiv(NUM_PEAK, ksp) + 31) / 32) * 32;   // 1760
  Z(h1g, 2 * (size_t)BATCH * TH * 4);                 // h1g + h1p
  {
    GP g = {GeneNb, gW1b, h1g, nullptr, nullptr, BATCH, TH, NUM_GENE, chG};
    gemm_bt_bf16<<<dim3(TH / 64, BATCH / 64, ksp), 256, 0, stream>>>(g, Zp, 0);
    GP p = {PeakNb, pW1b, h1p, nullptr, nullptr, BATCH, TH, NUM_PEAK, chP};
    gemm_bt_bf16<<<dim3(TH / 64, BATCH / 64, ksp), 256, 0, stream>>>(p, Zp, 0);
  }
  bias_relu_bn2<<<2 * TH, BATCH, 0, stream>>>(h1g, gb1, gg1, gbe1, h1gb,
                                              h1p, pb1, pg1, pbe1, h1pb);
  {
    GP g = {h1gb, gW2b, h2g, nullptr, nullptr, BATCH, TH, TH, TH};
    GP p = {h1pb, pW2b, h2p, nullptr, nullptr, BATCH, TH, TH, TH};
    gemm_bt_bf16<<<dim3(TH / 64, BATCH / 64, 2), 256, 0, stream>>>(g, p, 1);
  }
  bias_relu_bn2<<<2 * TH, BATCH, 0, stream>>>(h2g, gb2, gg2, gbe2, h2gb,
                                              h2p, pb2, pg2, pbe2, h2pb);
  {
    GP g = {h2gb, mlWb, ml_d, nullptr, nullptr, BATCH, NT2, TH, TH};
    GP p = {h2pb, mlWb, ml_j, nullptr, nullptr, BATCH, NT2, TH, TH};
    gemm_bt_bf16<<<dim3(cdiv(NT2, 64), BATCH / 64, 2), 256, 0, stream>>>(g, p, 1);
  }
  row_kl_theta<<<dim3(BATCH, 2), 128, 0, stream>>>(ml_d, ml_j, mu_b, ls_b, th_db, th_jb, out + 1);

  // ================= GAT layer 1 =================
  {
    GP l = {featb, Wl1b, nullptr, xl1b, bl1, N_NODES, HID, EMB, EMB};
    GP r = {featb, Wr1b, nullptr, xr1b, br1, N_NODES, HID, EMB, EMB};
    gemm_bt_bf16<<<dim3(HID / 64, N_NODES / 64, 2), 256, 0, stream>>>(l, r, 1);
  }
  gat_fused<HID><<<N_NODES / 4, 256, 0, stream>>>(xl1b, xr1b, att1, bias1, row_ptr, csr_src, agg1b);

  // ================= GAT layer 2 =================
  {
    GP l = {agg1b, Wl2b, nullptr, xl2b, bl2, N_NODES, EMB, HID, HID};
    GP r = {agg1b, Wr2b, nullptr, xr2b, br2, N_NODES, EMB, HID, HID};
    gemm_bt_bf16<<<dim3(EMB / 64, N_NODES / 64, 2), 256, 0, stream>>>(l, r, 1);
  }
  gat_fused<EMB><<<N_NODES / 4, 256, 0, stream>>>(xl2b, xr2b, att2, bias2, row_ptr, csr_src, embb);

  // ================= topic heads =================
  {
    GP g = {embb + (size_t)NUM_PEAK * EMB, aWb, lgg, nullptr, nullptr, NUM_GENE, NT, EMB, EMB};
    GP p = {embb, aSWb, lgp, nullptr, nullptr, NUM_PEAK, NT, EMB, EMB};
    gemm_bt_bf16<<<dim3(2, cdiv(NUM_PEAK, 64), 2), 256, 0, stream>>>(g, p, 1);
  }
  fill_u32<<<1, 256, 0, stream>>>(cmax, 0x007FFFFFu, 2 * NT);
  Z(cden, 2 * NT * 4);
  col_max<<<dim3(cdiv(NUM_PEAK, 128), 2), 256, 0, stream>>>(lgg, lgp, cmax);
  col_sumexp<<<dim3(cdiv(NUM_PEAK, 128), 2), 256, 0, stream>>>(lgg, lgp, cmax, cden);
  beta_norm<<<dim3(1024, 2), 256, 0, stream>>>(lgg, lgp, cmax, cden, betagb, betapb);

  // ================= fused preds + recon (one launch) =================
  const int tiles_g = cdiv(NUM_GENE, 64);
  const int tiles_p = cdiv(NUM_PEAK, 64);
  recon_fused<<<dim3(tiles_g + tiles_p, 4), 256, 0, stream>>>(
      th_db, betagb, Gene, NUM_GENE, tiles_g,
      th_jb, betapb, Peak, NUM_PEAK, out);
}

// Round 6
// 528.008 us; speedup vs baseline: 4.2501x; 1.2118x over previous
//
#include <hip/hip_runtime.h>
#include <cstdint>
#include <cstddef>

using u16 = unsigned short;
using u32 = unsigned int;
typedef __attribute__((ext_vector_type(8))) short bf16x8;
typedef __attribute__((ext_vector_type(4))) float f32x4;

static constexpr int NUM_PEAK = 28000;
static constexpr int NUM_GENE = 12000;
static constexpr int N_NODES  = NUM_PEAK + NUM_GENE;   // 40000
static constexpr int N_EDGES  = 640000;
static constexpr int E_TOTAL  = N_EDGES + N_NODES;     // 680000
static constexpr int NT       = 100;
static constexpr int NT2      = 200;                   // mu+ls combined
static constexpr int NTP      = 128;                   // padded topic stride
static constexpr int TH       = 512;
static constexpr int EMB      = 64;
static constexpr int HID      = 128;
static constexpr int BATCH    = 256;
#define BN_EPS 1e-5f

__device__ __forceinline__ u16 f2bf(float f) {
  u32 b = __float_as_uint(f);
  return (u16)((b + 0x7FFFu + ((b >> 16) & 1u)) >> 16);
}
__device__ __forceinline__ float bf2f(u16 u) {
  return __uint_as_float((u32)u << 16);
}
__device__ __forceinline__ u32 f2o(float f) {
  u32 u = __float_as_uint(f);
  return (u & 0x80000000u) ? ~u : (u | 0x80000000u);
}
__device__ __forceinline__ float o2f(u32 u) {
  return (u & 0x80000000u) ? __uint_as_float(u & 0x7fffffffu) : __uint_as_float(~u);
}

// ---------------------------------------------------------------------------
// Batched fp32->bf16 conversion: all tensors in ONE launch.
// ---------------------------------------------------------------------------
struct CvtJobs {
  const float* src[16];
  u16* dst[16];
  u32 n[16];
  u32 start[16];   // first block of segment i
  int count;
};

__global__ __launch_bounds__(256) void cvt_all(CvtJobs J) {
  const int bid = blockIdx.x;
  int seg = 0;
  while (seg + 1 < J.count && bid >= (int)J.start[seg + 1]) ++seg;
  const float* __restrict__ src = J.src[seg];
  u16* __restrict__ dst = J.dst[seg];
  const u32 n = J.n[seg];
  const u32 i = (u32)(bid - J.start[seg]) * 2048u + threadIdx.x * 8u;
  if (i + 8 <= n) {
    float4 a = *(const float4*)(src + i);
    float4 b = *(const float4*)(src + i + 4);
    ushort4 o0{f2bf(a.x), f2bf(a.y), f2bf(a.z), f2bf(a.w)};
    ushort4 o1{f2bf(b.x), f2bf(b.y), f2bf(b.z), f2bf(b.w)};
    *(ushort4*)(dst + i) = o0;
    *(ushort4*)(dst + i + 4) = o1;
  } else {
    for (u32 j = i; j < n; ++j) dst[j] = f2bf(src[j]);
  }
}

// ---------------------------------------------------------------------------
// bf16 MFMA GEMM: C(M,N) = A(M,K) @ B(N,K)^T. 64x64 tile, 4 waves, BK=32.
// Dual mode (dual=1, gridDim.z=2): blockIdx.z selects problem g0/g1.
// Split mode (dual=0, gridDim.z>1): k-split with atomicAdd into zeroed C.
// ---------------------------------------------------------------------------
struct GP {
  const u16* A; const u16* B; float* C; u16* Cb; const float* bias;
  int M, N, K, chunk;
};

__global__ __launch_bounds__(256) void gemm_bt_bf16(GP g0, GP g1, int dual) {
  const GP& g = (dual && blockIdx.z) ? g1 : g0;
  const int M = g.M, N = g.N, K = g.K;
  __shared__ u16 As[64][32];
  __shared__ u16 Bs[64][32];
  const int tid = threadIdx.x;
  const int bm = blockIdx.y * 64, bn = blockIdx.x * 64;
  if (bm >= M || bn >= N) return;
  const int k0 = dual ? 0 : blockIdx.z * g.chunk;
  const int k1 = min(K, k0 + g.chunk);
  const int w = tid >> 6, lane = tid & 63;
  const int wm = (w >> 1) * 32, wn = (w & 1) * 32;
  const int fr = lane & 15;
  const int ks = (lane >> 4) * 8;
  const int srow = tid >> 2, sseg = (tid & 3) * 8;
  f32x4 acc[2][2] = {};
  for (int kt = k0; kt < k1; kt += 32) {
    const int gk = kt + sseg;
    {
      const int gm = bm + srow;
      bf16x8 v = {0, 0, 0, 0, 0, 0, 0, 0};
      if (gm < M) {
        if (gk + 8 <= k1) v = *(const bf16x8*)(g.A + (size_t)gm * K + gk);
        else if (gk < k1)
          for (int e = 0; e < k1 - gk; ++e) ((short*)&v)[e] = (short)g.A[(size_t)gm * K + gk + e];
      }
      *(bf16x8*)&As[srow][sseg] = v;
    }
    {
      const int gn = bn + srow;
      bf16x8 v = {0, 0, 0, 0, 0, 0, 0, 0};
      if (gn < N) {
        if (gk + 8 <= k1) v = *(const bf16x8*)(g.B + (size_t)gn * K + gk);
        else if (gk < k1)
          for (int e = 0; e < k1 - gk; ++e) ((short*)&v)[e] = (short)g.B[(size_t)gn * K + gk + e];
      }
      *(bf16x8*)&Bs[srow][sseg] = v;
    }
    __syncthreads();
    bf16x8 a0 = *(const bf16x8*)&As[wm + fr][ks];
    bf16x8 a1 = *(const bf16x8*)&As[wm + 16 + fr][ks];
    bf16x8 b0 = *(const bf16x8*)&Bs[wn + fr][ks];
    bf16x8 b1 = *(const bf16x8*)&Bs[wn + 16 + fr][ks];
    acc[0][0] = __builtin_amdgcn_mfma_f32_16x16x32_bf16(a0, b0, acc[0][0], 0, 0, 0);
    acc[0][1] = __builtin_amdgcn_mfma_f32_16x16x32_bf16(a0, b1, acc[0][1], 0, 0, 0);
    acc[1][0] = __builtin_amdgcn_mfma_f32_16x16x32_bf16(a1, b0, acc[1][0], 0, 0, 0);
    acc[1][1] = __builtin_amdgcn_mfma_f32_16x16x32_bf16(a1, b1, acc[1][1], 0, 0, 0);
    __syncthreads();
  }
  const bool split = (!dual && gridDim.z > 1);
#pragma unroll
  for (int fi = 0; fi < 2; ++fi)
#pragma unroll
    for (int fj = 0; fj < 2; ++fj)
#pragma unroll
      for (int r = 0; r < 4; ++r) {
        const int row = bm + wm + fi * 16 + (lane >> 4) * 4 + r;
        const int col = bn + wn + fj * 16 + fr;
        if (row < M && col < N) {
          const float v = acc[fi][fj][r];
          if (split) atomicAdd(&g.C[(size_t)row * N + col], v);
          else if (g.Cb) g.Cb[(size_t)row * N + col] = f2bf(v + (g.bias ? g.bias[col] : 0.f));
          else g.C[(size_t)row * N + col] = v + (g.bias ? g.bias[col] : 0.f);
        }
      }
}

// ---------------------------------------------------------------------------
// Fused recon for BOTH matrices in one launch. pred = theta @ beta^T (K=128
// exact). One partial per BLOCK (LDS cross-wave reduce, private slot store) —
// no contended atomics. X-pass float4-vectorized on interior tiles.
// grid = (tiles_g + tiles_p, 4 row-blocks).
// ---------------------------------------------------------------------------
__global__ __launch_bounds__(256) void recon_fused(
    const u16* __restrict__ thg, const u16* __restrict__ betag,
    const float* __restrict__ Xg, int Ng, int tiles_g,
    const u16* __restrict__ thp, const u16* __restrict__ betap,
    const float* __restrict__ Xp, int Np, float* __restrict__ partials) {
  __shared__ float pred[64][65];
  __shared__ float wsum[4];
  int ct = blockIdx.x;
  const u16* A; const u16* B; const float* X; int N;
  if (ct < tiles_g) { A = thg; B = betag; X = Xg; N = Ng; }
  else { ct -= tiles_g; A = thp; B = betap; X = Xp; N = Np; }
  const int bm = blockIdx.y * 64, bn = ct * 64;
  const int tid = threadIdx.x, w = tid >> 6, lane = tid & 63;
  const int wm = (w >> 1) * 32, wn = (w & 1) * 32;
  const int fr = lane & 15, ks = (lane >> 4) * 8;
  const u16* Ar0 = A + (size_t)(bm + wm + fr) * NTP;
  const u16* Ar1 = A + (size_t)(bm + wm + 16 + fr) * NTP;
  bf16x8 a0[4], a1[4];
#pragma unroll
  for (int kt = 0; kt < 4; ++kt) {
    a0[kt] = *(const bf16x8*)(Ar0 + kt * 32 + ks);
    a1[kt] = *(const bf16x8*)(Ar1 + kt * 32 + ks);
  }
  const int gn0 = min(bn + wn + fr, N - 1);
  const int gn1 = min(bn + wn + 16 + fr, N - 1);
  const u16* Br0 = B + (size_t)gn0 * NTP;
  const u16* Br1 = B + (size_t)gn1 * NTP;
  f32x4 acc[2][2] = {};
#pragma unroll
  for (int kt = 0; kt < 4; ++kt) {
    bf16x8 b0 = *(const bf16x8*)(Br0 + kt * 32 + ks);
    bf16x8 b1 = *(const bf16x8*)(Br1 + kt * 32 + ks);
    acc[0][0] = __builtin_amdgcn_mfma_f32_16x16x32_bf16(a0[kt], b0, acc[0][0], 0, 0, 0);
    acc[0][1] = __builtin_amdgcn_mfma_f32_16x16x32_bf16(a0[kt], b1, acc[0][1], 0, 0, 0);
    acc[1][0] = __builtin_amdgcn_mfma_f32_16x16x32_bf16(a1[kt], b0, acc[1][0], 0, 0, 0);
    acc[1][1] = __builtin_amdgcn_mfma_f32_16x16x32_bf16(a1[kt], b1, acc[1][1], 0, 0, 0);
  }
#pragma unroll
  for (int fi = 0; fi < 2; ++fi)
#pragma unroll
    for (int fj = 0; fj < 2; ++fj)
#pragma unroll
      for (int r = 0; r < 4; ++r)
        pred[wm + fi * 16 + (lane >> 4) * 4 + r][wn + fj * 16 + fr] = acc[fi][fj][r];
  __syncthreads();
  float local = 0.f;
  if (bn + 64 <= N) {
    // interior tile: float4 X loads (col = tid*4 & 63, multiple of 4)
#pragma unroll
    for (int k = 0; k < 4; ++k) {
      const int j = k * 1024 + tid * 4;
      const int row = j >> 6, col = j & 63;
      const float4 xv = *(const float4*)(X + (size_t)(bm + row) * N + bn + col);
      local += xv.x * __logf(pred[row][col + 0] + 1e-6f);
      local += xv.y * __logf(pred[row][col + 1] + 1e-6f);
      local += xv.z * __logf(pred[row][col + 2] + 1e-6f);
      local += xv.w * __logf(pred[row][col + 3] + 1e-6f);
    }
  } else {
#pragma unroll
    for (int k = 0; k < 16; ++k) {
      const int idx = k * 256 + tid, row = idx >> 6, col = idx & 63;
      if (bn + col < N)
        local += X[(size_t)(bm + row) * N + bn + col] * __logf(pred[row][col] + 1e-6f);
    }
  }
  for (int o = 32; o > 0; o >>= 1) local += __shfl_down(local, o);
  if (lane == 0) wsum[w] = local;
  __syncthreads();
  if (tid == 0)
    partials[(size_t)blockIdx.y * gridDim.x + blockIdx.x] =
        wsum[0] + wsum[1] + wsum[2] + wsum[3];
}

// single block: out[0] = -sum(partials)/BATCH
__global__ __launch_bounds__(256) void final_recon(
    const float* __restrict__ partials, int n, float* __restrict__ out) {
  float s = 0.f;
  for (int i = threadIdx.x; i < n; i += 256) s += partials[i];
  __shared__ float red[256];
  red[threadIdx.x] = s; __syncthreads();
  for (int o = 128; o > 0; o >>= 1) {
    if (threadIdx.x < o) red[threadIdx.x] += red[threadIdx.x + o];
    __syncthreads();
  }
  if (threadIdx.x == 0) out[0] = -red[0] * (1.f / BATCH);
}

// ---------------------------------------------------------------------------
// Paired bias+relu+BN: gene columns [0,TH), peak columns [TH,2TH).
// ---------------------------------------------------------------------------
__global__ __launch_bounds__(256) void bias_relu_bn2(
    const float* __restrict__ Hg, const float* __restrict__ bg,
    const float* __restrict__ gg, const float* __restrict__ beg,
    u16* __restrict__ og,
    const float* __restrict__ Hp, const float* __restrict__ bp,
    const float* __restrict__ gp, const float* __restrict__ bep,
    u16* __restrict__ op) {
  int c = blockIdx.x;
  const float *H, *b, *gma, *be; u16* ob;
  if (c < TH) { H = Hg; b = bg; gma = gg; be = beg; ob = og; }
  else { c -= TH; H = Hp; b = bp; gma = gp; be = bep; ob = op; }
  const int r = threadIdx.x;
  float v = fmaxf(H[(size_t)r * TH + c] + b[c], 0.f);
  __shared__ float red[BATCH];
  red[r] = v; __syncthreads();
  for (int s = BATCH / 2; s > 0; s >>= 1) { if (r < s) red[r] += red[r + s]; __syncthreads(); }
  const float mean = red[0] * (1.f / BATCH);
  __syncthreads();
  const float d = v - mean;
  red[r] = d * d; __syncthreads();
  for (int s = BATCH / 2; s > 0; s >>= 1) { if (r < s) red[r] += red[r + s]; __syncthreads(); }
  const float var = red[0] * (1.f / BATCH);
  ob[(size_t)r * TH + c] = f2bf(d * rsqrtf(var + BN_EPS) * gma[c] + be[c]);
}

// ---------------------------------------------------------------------------
// KL + theta for both encoders. grid=(BATCH,2); blockIdx.y selects d/j.
// ---------------------------------------------------------------------------
__global__ __launch_bounds__(128) void row_kl_theta(
    const float* __restrict__ mld, const float* __restrict__ mlj,
    const float* __restrict__ mu_b, const float* __restrict__ ls_b,
    u16* __restrict__ thd, u16* __restrict__ thj, float* __restrict__ kl_out) {
  const float* ml = blockIdx.y ? mlj : mld;
  u16* thb = blockIdx.y ? thj : thd;
  const int b = blockIdx.x;
  const int t = threadIdx.x;
  const bool act = (t < NT);
  float mu = 0.f, ls = 0.f, term = 0.f;
  if (act) {
    mu = ml[(size_t)b * NT2 + t] + mu_b[t];
    ls = 2.f * (ml[(size_t)b * NT2 + NT + t] + ls_b[t]);
    term = 1.f + ls - mu * mu - expf(ls);
  }
  __shared__ float red[128];
  red[t] = act ? term : 0.f; __syncthreads();
  for (int s = 64; s > 0; s >>= 1) { if (t < s) red[t] += red[t + s]; __syncthreads(); }
  if (t == 0) atomicAdd(kl_out, -0.5f * red[0] * (1.f / BATCH));
  __syncthreads();
  red[t] = act ? mu : -INFINITY; __syncthreads();
  for (int s = 64; s > 0; s >>= 1) { if (t < s) red[t] = fmaxf(red[t], red[t + s]); __syncthreads(); }
  const float mx = red[0];
  __syncthreads();
  const float e = act ? expf(mu - mx) : 0.f;
  red[t] = e; __syncthreads();
  for (int s = 64; s > 0; s >>= 1) { if (t < s) red[t] += red[t + s]; __syncthreads(); }
  thb[(size_t)b * NTP + t] = act ? f2bf(e / red[0]) : (u16)0;
}

// --------------------------- CSR build kernels -----------------------------
__global__ __launch_bounds__(256) void deg_count(
    const int* __restrict__ ei, int* __restrict__ deg) {
  int e = blockIdx.x * 256 + threadIdx.x;
  if (e >= E_TOTAL) return;
  const int d = (e < N_EDGES) ? ei[N_EDGES + e] : e - N_EDGES;
  atomicAdd(&deg[d], 1);
}

__global__ __launch_bounds__(1024) void scan_deg(
    const int* __restrict__ deg, int* __restrict__ row_ptr) {
  __shared__ int sums[1024];
  const int t = threadIdx.x;
  constexpr int PER = (N_NODES + 1023) / 1024;   // 40
  const int base = t * PER;
  int local = 0;
  for (int i = 0; i < PER; ++i) {
    int idx = base + i;
    if (idx < N_NODES) local += deg[idx];
  }
  sums[t] = local; __syncthreads();
  for (int o = 1; o < 1024; o <<= 1) {
    int v = (t >= o) ? sums[t - o] : 0;
    __syncthreads();
    sums[t] += v;
    __syncthreads();
  }
  int run = (t == 0) ? 0 : sums[t - 1];
  for (int i = 0; i < PER; ++i) {
    int idx = base + i;
    if (idx < N_NODES) { row_ptr[idx] = run; run += deg[idx]; }
  }
  if (t == 1023) row_ptr[N_NODES] = sums[1023];
}

__global__ __launch_bounds__(256) void csr_scatter(
    const int* __restrict__ ei, const int* __restrict__ row_ptr,
    int* __restrict__ cur, int* __restrict__ csr_src) {
  int e = blockIdx.x * 256 + threadIdx.x;
  if (e >= E_TOTAL) return;
  int s, d;
  if (e < N_EDGES) { s = ei[e]; d = ei[N_EDGES + e]; }
  else { s = d = e - N_EDGES; }
  const int pos = atomicAdd(&cur[d], 1);
  csr_src[row_ptr[d] + pos] = s;
}

// ---------------------------------------------------------------------------
// Fused GATv2 layer, 4-way edge-parallel (16-lane groups), bf16 in/out.
// ---------------------------------------------------------------------------
template <int C>
__global__ __launch_bounds__(256) void gat_fused(
    const u16* __restrict__ xl, const u16* __restrict__ xr,
    const float* __restrict__ att, const float* __restrict__ bias,
    const int* __restrict__ row_ptr, const int* __restrict__ csr_src,
    u16* __restrict__ out_b) {
  constexpr int CPL = C / 16;
  const int lane = threadIdx.x & 63;
  const int g = lane >> 4, li = lane & 15;
  const int d = blockIdx.x * 4 + (threadIdx.x >> 6);
  if (d >= N_NODES) return;
  const int c0 = li * CPL;
  float xrv[CPL], attv[CPL], acc[CPL];
#pragma unroll
  for (int i = 0; i < CPL; ++i) {
    xrv[i] = bf2f(xr[(size_t)d * C + c0 + i]);
    attv[i] = att[c0 + i];
    acc[i] = 0.f;
  }
  float m = -INFINITY, den = 0.f;
  const int end = row_ptr[d + 1];
  int p = row_ptr[d] + g;
  int s = (p < end) ? csr_src[p] : 0;
  while (p < end) {
    const int sn = (p + 4 < end) ? csr_src[p + 4] : 0;
    float xlv[CPL];
    float part = 0.f;
#pragma unroll
    for (int i = 0; i < CPL; ++i) {
      xlv[i] = bf2f(xl[(size_t)s * C + c0 + i]);
      float x = xlv[i] + xrv[i];
      x = (x > 0.f) ? x : 0.2f * x;
      part += x * attv[i];
    }
    part += __shfl_xor(part, 1);
    part += __shfl_xor(part, 2);
    part += __shfl_xor(part, 4);
    part += __shfl_xor(part, 8);
    const float logit = part;
    const float nm = fmaxf(m, logit);
    const float scale = expf(m - nm);
    const float ex = expf(logit - nm);
    den = den * scale + ex;
#pragma unroll
    for (int i = 0; i < CPL; ++i) acc[i] = acc[i] * scale + ex * xlv[i];
    m = nm;
    p += 4;
    s = sn;
  }
  float M = m;
  M = fmaxf(M, __shfl_xor(M, 16));
  M = fmaxf(M, __shfl_xor(M, 32));
  const float gs = expf(m - M);
  den *= gs;
  den += __shfl_xor(den, 16);
  den += __shfl_xor(den, 32);
  const float inv = 1.f / (den + 1e-16f);
  float va[CPL];
#pragma unroll
  for (int i = 0; i < CPL; ++i) {
    float a = acc[i] * gs;
    a += __shfl_xor(a, 16);
    a += __shfl_xor(a, 32);
    va[i] = a;
  }
  if (g == 0) {
#pragma unroll
    for (int i = 0; i < CPL; ++i)
      out_b[(size_t)d * C + c0 + i] = f2bf(fmaxf(va[i] * inv + bias[c0 + i], 0.f));
  }
}

__global__ __launch_bounds__(256) void fill_u32(u32* __restrict__ p, u32 v, int n) {
  int i = blockIdx.x * 256 + threadIdx.x;
  if (i < n) p[i] = v;
}

// ----------------------- column softmax statistics -------------------------
__global__ __launch_bounds__(256) void col_max(
    const float* __restrict__ Lg, const float* __restrict__ Lp,
    u32* __restrict__ gmx) {
  const float* L = blockIdx.y ? Lp : Lg;
  const int M = blockIdx.y ? NUM_PEAK : NUM_GENE;
  u32* mx = gmx + blockIdx.y * NT;
  const int r0 = blockIdx.x * 128;
  if (r0 >= M) return;
  __shared__ u32 s[NT];
  for (int i = threadIdx.x; i < NT; i += 256) s[i] = 0x007FFFFFu;  // f2o(-inf)
  __syncthreads();
  const int cnt = min(128, M - r0) * NT;
  const float* base = L + (size_t)r0 * NT;
  for (int i = threadIdx.x; i < cnt; i += 256) {
    const int c = i % NT;
    atomicMax(&s[c], f2o(base[i]));
  }
  __syncthreads();
  for (int i = threadIdx.x; i < NT; i += 256) atomicMax(&mx[i], s[i]);
}

__global__ __launch_bounds__(256) void col_sumexp(
    const float* __restrict__ Lg, const float* __restrict__ Lp,
    const u32* __restrict__ gmx, float* __restrict__ gden) {
  const float* L = blockIdx.y ? Lp : Lg;
  const int M = blockIdx.y ? NUM_PEAK : NUM_GENE;
  const u32* mxg = gmx + blockIdx.y * NT;
  float* dng = gden + blockIdx.y * NT;
  const int r0 = blockIdx.x * 128;
  if (r0 >= M) return;
  __shared__ float mx[NT];
  __shared__ float s[NT];
  for (int i = threadIdx.x; i < NT; i += 256) { mx[i] = o2f(mxg[i]); s[i] = 0.f; }
  __syncthreads();
  const int cnt = min(128, M - r0) * NT;
  const float* base = L + (size_t)r0 * NT;
  for (int i = threadIdx.x; i < cnt; i += 256) {
    const int c = i % NT;
    atomicAdd(&s[c], expf(base[i] - mx[c]));
  }
  __syncthreads();
  for (int i = threadIdx.x; i < NT; i += 256) atomicAdd(&dng[i], s[i]);
}

__global__ __launch_bounds__(256) void beta_norm(
    const float* __restrict__ Lg, const float* __restrict__ Lp,
    const u32* __restrict__ gmx, const float* __restrict__ gden,
    u16* __restrict__ og, u16* __restrict__ op) {
  const float* L = blockIdx.y ? Lp : Lg;
  const int M = blockIdx.y ? NUM_PEAK : NUM_GENE;
  const u32* mxg = gmx + blockIdx.y * NT;
  const float* dng = gden + blockIdx.y * NT;
  u16* o = blockIdx.y ? op : og;
  __shared__ float mx[NT], inv[NT];
  for (int i = threadIdx.x; i < NT; i += 256) { mx[i] = o2f(mxg[i]); inv[i] = 1.f / dng[i]; }
  __syncthreads();
  const size_t total = (size_t)M * NTP;
  size_t i = (size_t)blockIdx.x * 256 + threadIdx.x;
  const size_t stride = (size_t)gridDim.x * 256;
  for (; i < total; i += stride) {
    const int c = (int)(i & (NTP - 1));
    u16 v = 0;
    if (c < NT) {
      const size_t r = i >> 7;
      v = f2bf(expf(L[r * NT + c] - mx[c]) * inv[c]);
    }
    o[i] = v;
  }
}

// ---------------------------------------------------------------------------
extern "C" void kernel_launch(void* const* d_in, const int* in_sizes, int n_in,
                              void* d_out, int out_size, void* d_ws, size_t ws_size,
                              hipStream_t stream) {
  const float* Gene  = (const float*)d_in[0];
  const float* GeneN = (const float*)d_in[1];
  const float* Peak  = (const float*)d_in[2];
  const float* PeakN = (const float*)d_in[3];
  const float* feat  = (const float*)d_in[4];
  const float* Wl1 = (const float*)d_in[5];  const float* bl1 = (const float*)d_in[6];
  const float* Wr1 = (const float*)d_in[7];  const float* br1 = (const float*)d_in[8];
  const float* att1 = (const float*)d_in[9]; const float* bias1 = (const float*)d_in[10];
  const float* Wl2 = (const float*)d_in[11]; const float* bl2 = (const float*)d_in[12];
  const float* Wr2 = (const float*)d_in[13]; const float* br2 = (const float*)d_in[14];
  const float* att2 = (const float*)d_in[15]; const float* bias2 = (const float*)d_in[16];
  const float* gW1 = (const float*)d_in[17]; const float* gb1 = (const float*)d_in[18];
  const float* gg1 = (const float*)d_in[19]; const float* gbe1 = (const float*)d_in[20];
  const float* gW2 = (const float*)d_in[21]; const float* gb2 = (const float*)d_in[22];
  const float* gg2 = (const float*)d_in[23]; const float* gbe2 = (const float*)d_in[24];
  const float* pW1 = (const float*)d_in[25]; const float* pb1 = (const float*)d_in[26];
  const float* pg1 = (const float*)d_in[27]; const float* pbe1 = (const float*)d_in[28];
  const float* pW2 = (const float*)d_in[29]; const float* pb2 = (const float*)d_in[30];
  const float* pg2 = (const float*)d_in[31]; const float* pbe2 = (const float*)d_in[32];
  const float* mu_W = (const float*)d_in[33]; const float* mu_b = (const float*)d_in[34];
  const float* ls_W = (const float*)d_in[35]; const float* ls_b = (const float*)d_in[36];
  const float* alphas_W = (const float*)d_in[37];
  const float* alphas_star_W = (const float*)d_in[38];
  const int* ei = (const int*)d_in[39];
  float* out = (float*)d_out;
  (void)in_sizes; (void)n_in; (void)ws_size;

  // ---- workspace layout (bytes) ----
  char* base = (char*)d_ws;
  size_t off = 0;
  auto A = [&](size_t bytes) { void* p = base + off; off += (bytes + 255) & ~(size_t)255; return p; };
  int* deg     = (int*)A((size_t)N_NODES * 4);      // deg+cur adjacent (one memset)
  int* cur     = (int*)A((size_t)N_NODES * 4);
  int* row_ptr = (int*)A((size_t)(N_NODES + 1) * 4);
  int* csr_src = (int*)A((size_t)E_TOTAL * 4);
  float* h1g = (float*)A((size_t)BATCH * TH * 4);   // h1g+h1p adjacent (one memset)
  float* h1p = (float*)A((size_t)BATCH * TH * 4);
  float* h2g = (float*)A((size_t)BATCH * TH * 4);
  float* h2p = (float*)A((size_t)BATCH * TH * 4);
  u16* h1gb = (u16*)A((size_t)BATCH * TH * 2);
  u16* h2gb = (u16*)A((size_t)BATCH * TH * 2);
  u16* h1pb = (u16*)A((size_t)BATCH * TH * 2);
  u16* h2pb = (u16*)A((size_t)BATCH * TH * 2);
  float* ml_d = (float*)A((size_t)BATCH * NT2 * 4);
  float* ml_j = (float*)A((size_t)BATCH * NT2 * 4);
  u16* th_db = (u16*)A((size_t)BATCH * NTP * 2);
  u16* th_jb = (u16*)A((size_t)BATCH * NTP * 2);
  float* lgg = (float*)A((size_t)NUM_GENE * NT * 4);
  float* lgp = (float*)A((size_t)NUM_PEAK * NT * 4);
  u16* betagb = (u16*)A((size_t)NUM_GENE * NTP * 2);
  u16* betapb = (u16*)A((size_t)NUM_PEAK * NTP * 2);
  u16* featb = (u16*)A((size_t)N_NODES * EMB * 2);
  u16* gW2b = (u16*)A((size_t)TH * TH * 2);
  u16* pW2b = (u16*)A((size_t)TH * TH * 2);
  u16* mlWb = (u16*)A((size_t)NT2 * TH * 2);
  u16* Wl1b = (u16*)A((size_t)HID * EMB * 2);
  u16* Wr1b = (u16*)A((size_t)HID * EMB * 2);
  u16* Wl2b = (u16*)A((size_t)EMB * HID * 2);
  u16* Wr2b = (u16*)A((size_t)EMB * HID * 2);
  u16* aWb  = (u16*)A((size_t)NT * EMB * 2);
  u16* aSWb = (u16*)A((size_t)NT * EMB * 2);
  u16* agg1b = (u16*)A((size_t)N_NODES * HID * 2);
  u16* embb  = (u16*)A((size_t)N_NODES * EMB * 2);
  u32* cmax = (u32*)A(2 * NT * 4);
  float* cden = (float*)A(2 * NT * 4);
  float* partials = (float*)A(4096 * 4);
  // overlap region: encoder bf16 staging, then GAT bf16 projection buffers
  char* R = (char*)A(61440000);
  u16* GeneNb = (u16*)R;                               // 6,144,000 B
  u16* gW1b   = (u16*)(R + 6144000);                   // 12,288,000 B
  u16* PeakNb = (u16*)(R + 18432000);                  // 14,336,000 B
  u16* pW1b   = (u16*)(R + 32768000);                  // 28,672,000 B
  u16* xl1b   = (u16*)R;                               // 10,240,000 B
  u16* xr1b   = (u16*)(R + 10240000);                  // 10,240,000 B
  u16* xl2b   = (u16*)(R + 20480000);                  //  5,120,000 B
  u16* xr2b   = (u16*)(R + 25600000);                  //  5,120,000 B

  auto cdiv = [](int a, int b) { return (a + b - 1) / b; };
  auto Z = [&](void* p, size_t bytes) { hipMemsetAsync(p, 0, bytes, stream); };

  Z(d_out, (size_t)out_size * sizeof(float));
  Z(deg, 2 * (size_t)N_NODES * 4);                    // deg + cur

  // ---- CSR build ----
  deg_count<<<cdiv(E_TOTAL, 256), 256, 0, stream>>>(ei, deg);
  scan_deg<<<1, 1024, 0, stream>>>(deg, row_ptr);
  csr_scatter<<<cdiv(E_TOTAL, 256), 256, 0, stream>>>(ei, row_ptr, cur, csr_src);

  // ---- ALL fp32->bf16 conversions in one launch ----
  {
    CvtJobs J = {};
    int c = 0; u32 blocks = 0;
    auto add = [&](const float* s, u16* d, size_t n) {
      J.src[c] = s; J.dst[c] = d; J.n[c] = (u32)n; J.start[c] = blocks;
      blocks += (u32)((n + 2047) / 2048); ++c;
    };
    add(GeneN, GeneNb, (size_t)BATCH * NUM_GENE);
    add(PeakN, PeakNb, (size_t)BATCH * NUM_PEAK);
    add(gW1, gW1b, (size_t)TH * NUM_GENE);
    add(pW1, pW1b, (size_t)TH * NUM_PEAK);
    add(gW2, gW2b, (size_t)TH * TH);
    add(pW2, pW2b, (size_t)TH * TH);
    add(mu_W, mlWb, (size_t)NT * TH);
    add(ls_W, mlWb + (size_t)NT * TH, (size_t)NT * TH);
    add(feat, featb, (size_t)N_NODES * EMB);
    add(Wl1, Wl1b, (size_t)HID * EMB);
    add(Wr1, Wr1b, (size_t)HID * EMB);
    add(Wl2, Wl2b, (size_t)EMB * HID);
    add(Wr2, Wr2b, (size_t)EMB * HID);
    add(alphas_W, aWb, (size_t)NT * EMB);
    add(alphas_star_W, aSWb, (size_t)NT * EMB);
    J.count = c;
    cvt_all<<<blocks, 256, 0, stream>>>(J);
  }

  GP Zp = {};   // zero template

  // ================= encoders =================
  const int ksp = 16;
  const int chG = ((cdiv(NUM_GENE, ksp) + 31) / 32) * 32;   // 768
  const int chP = ((cdiv(NUM_PEAK, ksp) + 31) / 32) * 32;   // 1760
  Z(h1g, 2 * (size_t)BATCH * TH * 4);                 // h1g + h1p
  {
    GP g = {GeneNb, gW1b, h1g, nullptr, nullptr, BATCH, TH, NUM_GENE, chG};
    gemm_bt_bf16<<<dim3(TH / 64, BATCH / 64, ksp), 256, 0, stream>>>(g, Zp, 0);
    GP p = {PeakNb, pW1b, h1p, nullptr, nullptr, BATCH, TH, NUM_PEAK, chP};
    gemm_bt_bf16<<<dim3(TH / 64, BATCH / 64, ksp), 256, 0, stream>>>(p, Zp, 0);
  }
  bias_relu_bn2<<<2 * TH, BATCH, 0, stream>>>(h1g, gb1, gg1, gbe1, h1gb,
                                              h1p, pb1, pg1, pbe1, h1pb);
  {
    GP g = {h1gb, gW2b, h2g, nullptr, nullptr, BATCH, TH, TH, TH};
    GP p = {h1pb, pW2b, h2p, nullptr, nullptr, BATCH, TH, TH, TH};
    gemm_bt_bf16<<<dim3(TH / 64, BATCH / 64, 2), 256, 0, stream>>>(g, p, 1);
  }
  bias_relu_bn2<<<2 * TH, BATCH, 0, stream>>>(h2g, gb2, gg2, gbe2, h2gb,
                                              h2p, pb2, pg2, pbe2, h2pb);
  {
    GP g = {h2gb, mlWb, ml_d, nullptr, nullptr, BATCH, NT2, TH, TH};
    GP p = {h2pb, mlWb, ml_j, nullptr, nullptr, BATCH, NT2, TH, TH};
    gemm_bt_bf16<<<dim3(cdiv(NT2, 64), BATCH / 64, 2), 256, 0, stream>>>(g, p, 1);
  }
  row_kl_theta<<<dim3(BATCH, 2), 128, 0, stream>>>(ml_d, ml_j, mu_b, ls_b, th_db, th_jb, out + 1);

  // ================= GAT layer 1 =================
  {
    GP l = {featb, Wl1b, nullptr, xl1b, bl1, N_NODES, HID, EMB, EMB};
    GP r = {featb, Wr1b, nullptr, xr1b, br1, N_NODES, HID, EMB, EMB};
    gemm_bt_bf16<<<dim3(HID / 64, N_NODES / 64, 2), 256, 0, stream>>>(l, r, 1);
  }
  gat_fused<HID><<<N_NODES / 4, 256, 0, stream>>>(xl1b, xr1b, att1, bias1, row_ptr, csr_src, agg1b);

  // ================= GAT layer 2 =================
  {
    GP l = {agg1b, Wl2b, nullptr, xl2b, bl2, N_NODES, EMB, HID, HID};
    GP r = {agg1b, Wr2b, nullptr, xr2b, br2, N_NODES, EMB, HID, HID};
    gemm_bt_bf16<<<dim3(EMB / 64, N_NODES / 64, 2), 256, 0, stream>>>(l, r, 1);
  }
  gat_fused<EMB><<<N_NODES / 4, 256, 0, stream>>>(xl2b, xr2b, att2, bias2, row_ptr, csr_src, embb);

  // ================= topic heads =================
  {
    GP g = {embb + (size_t)NUM_PEAK * EMB, aWb, lgg, nullptr, nullptr, NUM_GENE, NT, EMB, EMB};
    GP p = {embb, aSWb, lgp, nullptr, nullptr, NUM_PEAK, NT, EMB, EMB};
    gemm_bt_bf16<<<dim3(2, cdiv(NUM_PEAK, 64), 2), 256, 0, stream>>>(g, p, 1);
  }
  fill_u32<<<1, 256, 0, stream>>>(cmax, 0x007FFFFFu, 2 * NT);
  Z(cden, 2 * NT * 4);
  col_max<<<dim3(cdiv(NUM_PEAK, 128), 2), 256, 0, stream>>>(lgg, lgp, cmax);
  col_sumexp<<<dim3(cdiv(NUM_PEAK, 128), 2), 256, 0, stream>>>(lgg, lgp, cmax, cden);
  beta_norm<<<dim3(1024, 2), 256, 0, stream>>>(lgg, lgp, cmax, cden, betagb, betapb);

  // ================= fused preds + recon (no contended atomics) ============
  const int tiles_g = cdiv(NUM_GENE, 64);
  const int tiles_p = cdiv(NUM_PEAK, 64);
  const int tiles = tiles_g + tiles_p;
  recon_fused<<<dim3(tiles, 4), 256, 0, stream>>>(
      th_db, betagb, Gene, NUM_GENE, tiles_g,
      th_jb, betapb, Peak, NUM_PEAK, partials);
  final_recon<<<1, 256, 0, stream>>>(partials, tiles * 4, out);
}

// Round 7
// 496.276 us; speedup vs baseline: 4.5219x; 1.0639x over previous
//
#include <hip/hip_runtime.h>
#include <cstdint>
#include <cstddef>

using u16 = unsigned short;
using u32 = unsigned int;
typedef __attribute__((ext_vector_type(8))) short bf16x8;
typedef __attribute__((ext_vector_type(4))) float f32x4;

static constexpr int NUM_PEAK = 28000;
static constexpr int NUM_GENE = 12000;
static constexpr int N_NODES  = NUM_PEAK + NUM_GENE;   // 40000
static constexpr int N_EDGES  = 640000;
static constexpr int E_TOTAL  = N_EDGES + N_NODES;     // 680000
static constexpr int NT       = 100;
static constexpr int NT2      = 200;                   // mu+ls combined
static constexpr int NTP      = 128;                   // padded topic stride
static constexpr int TH       = 512;
static constexpr int EMB      = 64;
static constexpr int HID      = 128;
static constexpr int BATCH    = 256;
static constexpr int SCAN_CHUNK = 1024;
static constexpr int SCAN_NB  = (N_NODES + SCAN_CHUNK - 1) / SCAN_CHUNK;  // 40
#define BN_EPS 1e-5f

__device__ __forceinline__ u16 f2bf(float f) {
  u32 b = __float_as_uint(f);
  return (u16)((b + 0x7FFFu + ((b >> 16) & 1u)) >> 16);
}
__device__ __forceinline__ float bf2f(u16 u) {
  return __uint_as_float((u32)u << 16);
}
__device__ __forceinline__ u32 f2o(float f) {
  u32 u = __float_as_uint(f);
  return (u & 0x80000000u) ? ~u : (u | 0x80000000u);
}
__device__ __forceinline__ float o2f(u32 u) {
  return (u & 0x80000000u) ? __uint_as_float(u & 0x7fffffffu) : __uint_as_float(~u);
}

// ---------------------------------------------------------------------------
// Batched fp32->bf16 conversion (small tensors only now).
// ---------------------------------------------------------------------------
struct CvtJobs {
  const float* src[12];
  u16* dst[12];
  u32 n[12];
  u32 start[12];
  int count;
};

__global__ __launch_bounds__(256) void cvt_all(CvtJobs J) {
  const int bid = blockIdx.x;
  int seg = 0;
  while (seg + 1 < J.count && bid >= (int)J.start[seg + 1]) ++seg;
  const float* __restrict__ src = J.src[seg];
  u16* __restrict__ dst = J.dst[seg];
  const u32 n = J.n[seg];
  const u32 i = (u32)(bid - J.start[seg]) * 2048u + threadIdx.x * 8u;
  if (i + 8 <= n) {
    float4 a = *(const float4*)(src + i);
    float4 b = *(const float4*)(src + i + 4);
    ushort4 o0{f2bf(a.x), f2bf(a.y), f2bf(a.z), f2bf(a.w)};
    ushort4 o1{f2bf(b.x), f2bf(b.y), f2bf(b.z), f2bf(b.w)};
    *(ushort4*)(dst + i) = o0;
    *(ushort4*)(dst + i + 4) = o1;
  } else {
    for (u32 j = i; j < n; ++j) dst[j] = f2bf(src[j]);
  }
}

// ---------------------------------------------------------------------------
// bf16 MFMA GEMM: C(M,N) = A(M,K) @ B(N,K)^T. 64x64 tile, 4 waves, BK=32.
// LDS padded to [40] u16 (80 B stride) -> 2-way bank aliasing on b128 reads.
// ---------------------------------------------------------------------------
struct GP {
  const u16* A; const u16* B; float* C; u16* Cb; const float* bias;
  int M, N, K, chunk;
};

__global__ __launch_bounds__(256) void gemm_bt_bf16(GP g0, GP g1, int dual) {
  const GP& g = (dual && blockIdx.z) ? g1 : g0;
  const int M = g.M, N = g.N, K = g.K;
  __shared__ u16 As[64][40];
  __shared__ u16 Bs[64][40];
  const int tid = threadIdx.x;
  const int bm = blockIdx.y * 64, bn = blockIdx.x * 64;
  if (bm >= M || bn >= N) return;
  const int k0 = dual ? 0 : blockIdx.z * g.chunk;
  const int k1 = min(K, k0 + g.chunk);
  const int w = tid >> 6, lane = tid & 63;
  const int wm = (w >> 1) * 32, wn = (w & 1) * 32;
  const int fr = lane & 15;
  const int ks = (lane >> 4) * 8;
  const int srow = tid >> 2, sseg = (tid & 3) * 8;
  f32x4 acc[2][2] = {};
  for (int kt = k0; kt < k1; kt += 32) {
    const int gk = kt + sseg;
    {
      const int gm = bm + srow;
      bf16x8 v = {0, 0, 0, 0, 0, 0, 0, 0};
      if (gm < M) {
        if (gk + 8 <= k1) v = *(const bf16x8*)(g.A + (size_t)gm * K + gk);
        else if (gk < k1)
          for (int e = 0; e < k1 - gk; ++e) ((short*)&v)[e] = (short)g.A[(size_t)gm * K + gk + e];
      }
      *(bf16x8*)&As[srow][sseg] = v;
    }
    {
      const int gn = bn + srow;
      bf16x8 v = {0, 0, 0, 0, 0, 0, 0, 0};
      if (gn < N) {
        if (gk + 8 <= k1) v = *(const bf16x8*)(g.B + (size_t)gn * K + gk);
        else if (gk < k1)
          for (int e = 0; e < k1 - gk; ++e) ((short*)&v)[e] = (short)g.B[(size_t)gn * K + gk + e];
      }
      *(bf16x8*)&Bs[srow][sseg] = v;
    }
    __syncthreads();
    bf16x8 a0 = *(const bf16x8*)&As[wm + fr][ks];
    bf16x8 a1 = *(const bf16x8*)&As[wm + 16 + fr][ks];
    bf16x8 b0 = *(const bf16x8*)&Bs[wn + fr][ks];
    bf16x8 b1 = *(const bf16x8*)&Bs[wn + 16 + fr][ks];
    acc[0][0] = __builtin_amdgcn_mfma_f32_16x16x32_bf16(a0, b0, acc[0][0], 0, 0, 0);
    acc[0][1] = __builtin_amdgcn_mfma_f32_16x16x32_bf16(a0, b1, acc[0][1], 0, 0, 0);
    acc[1][0] = __builtin_amdgcn_mfma_f32_16x16x32_bf16(a1, b0, acc[1][0], 0, 0, 0);
    acc[1][1] = __builtin_amdgcn_mfma_f32_16x16x32_bf16(a1, b1, acc[1][1], 0, 0, 0);
    __syncthreads();
  }
  const bool split = (!dual && gridDim.z > 1);
#pragma unroll
  for (int fi = 0; fi < 2; ++fi)
#pragma unroll
    for (int fj = 0; fj < 2; ++fj)
#pragma unroll
      for (int r = 0; r < 4; ++r) {
        const int row = bm + wm + fi * 16 + (lane >> 4) * 4 + r;
        const int col = bn + wn + fj * 16 + fr;
        if (row < M && col < N) {
          const float v = acc[fi][fj][r];
          if (split) atomicAdd(&g.C[(size_t)row * N + col], v);
          else if (g.Cb) g.Cb[(size_t)row * N + col] = f2bf(v + (g.bias ? g.bias[col] : 0.f));
          else g.C[(size_t)row * N + col] = v + (g.bias ? g.bias[col] : 0.f);
        }
      }
}

// ---------------------------------------------------------------------------
// Encoder layer-1 GEMM, both problems in one launch. M=256 exact; 256-row
// M-tile so B (weights) is streamed exactly ONCE; fp32 inputs converted to
// bf16 inline during LDS staging (no cvt pre-pass). K and chunks are
// multiples of 32 -> no k bounds. k-split atomicAdd into pre-zeroed C.
// grid = (TH/64, 1, 2*ksp): z<ksp -> problem 0 (gene), else problem 1 (peak).
// ---------------------------------------------------------------------------
__global__ __launch_bounds__(256) void gemm_enc1(
    const float* __restrict__ A0, const float* __restrict__ B0, float* __restrict__ C0,
    int K0, int ch0,
    const float* __restrict__ A1, const float* __restrict__ B1, float* __restrict__ C1,
    int K1, int ch1, int ksp) {
  const int z = blockIdx.z;
  const bool second = (z >= ksp);
  const float* __restrict__ A = second ? A1 : A0;
  const float* __restrict__ B = second ? B1 : B0;
  float* __restrict__ C = second ? C1 : C0;
  const int K = second ? K1 : K0;
  const int chunk = second ? ch1 : ch0;
  const int zz = second ? z - ksp : z;
  const int k0 = zz * chunk;
  const int k1 = min(K, k0 + chunk);
  __shared__ u16 As[256][40];
  __shared__ u16 Bs[64][40];
  const int tid = threadIdx.x;
  const int bn = blockIdx.x * 64;
  const int w = tid >> 6, lane = tid & 63;
  const int fr = lane & 15, ks = (lane >> 4) * 8;
  const int srow = tid >> 2, sseg = (tid & 3) * 8;
  f32x4 acc[4][4] = {};
  for (int kt = k0; kt < k1; kt += 32) {
    // stage A: 256x32, fused fp32->bf16 (4 iterations of the 64-row pattern)
#pragma unroll
    for (int it = 0; it < 4; ++it) {
      const int r = it * 64 + srow;
      const float* src = A + (size_t)r * K + kt + sseg;
      float4 f0 = *(const float4*)src;
      float4 f1 = *(const float4*)(src + 4);
      ushort4 o0{f2bf(f0.x), f2bf(f0.y), f2bf(f0.z), f2bf(f0.w)};
      ushort4 o1{f2bf(f1.x), f2bf(f1.y), f2bf(f1.z), f2bf(f1.w)};
      *(ushort4*)&As[r][sseg] = o0;
      *(ushort4*)&As[r][sseg + 4] = o1;
    }
    // stage B: 64x32, fused fp32->bf16
    {
      const float* src = B + (size_t)(bn + srow) * K + kt + sseg;
      float4 f0 = *(const float4*)src;
      float4 f1 = *(const float4*)(src + 4);
      ushort4 o0{f2bf(f0.x), f2bf(f0.y), f2bf(f0.z), f2bf(f0.w)};
      ushort4 o1{f2bf(f1.x), f2bf(f1.y), f2bf(f1.z), f2bf(f1.w)};
      *(ushort4*)&Bs[srow][sseg] = o0;
      *(ushort4*)&Bs[srow][sseg + 4] = o1;
    }
    __syncthreads();
    bf16x8 bfr[4];
#pragma unroll
    for (int fj = 0; fj < 4; ++fj) bfr[fj] = *(const bf16x8*)&Bs[fj * 16 + fr][ks];
#pragma unroll
    for (int fi = 0; fi < 4; ++fi) {
      bf16x8 a = *(const bf16x8*)&As[w * 64 + fi * 16 + fr][ks];
#pragma unroll
      for (int fj = 0; fj < 4; ++fj)
        acc[fi][fj] = __builtin_amdgcn_mfma_f32_16x16x32_bf16(a, bfr[fj], acc[fi][fj], 0, 0, 0);
    }
    __syncthreads();
  }
#pragma unroll
  for (int fi = 0; fi < 4; ++fi)
#pragma unroll
    for (int fj = 0; fj < 4; ++fj)
#pragma unroll
      for (int r = 0; r < 4; ++r) {
        const int row = w * 64 + fi * 16 + (lane >> 4) * 4 + r;
        const int col = bn + fj * 16 + fr;
        atomicAdd(&C[(size_t)row * TH + col], acc[fi][fj][r]);
      }
}

// ---------------------------------------------------------------------------
// Fused recon for BOTH matrices; block-private partials (no contended atomic).
// ---------------------------------------------------------------------------
__global__ __launch_bounds__(256) void recon_fused(
    const u16* __restrict__ thg, const u16* __restrict__ betag,
    const float* __restrict__ Xg, int Ng, int tiles_g,
    const u16* __restrict__ thp, const u16* __restrict__ betap,
    const float* __restrict__ Xp, int Np, float* __restrict__ partials) {
  __shared__ float pred[64][65];
  __shared__ float wsum[4];
  int ct = blockIdx.x;
  const u16* A; const u16* B; const float* X; int N;
  if (ct < tiles_g) { A = thg; B = betag; X = Xg; N = Ng; }
  else { ct -= tiles_g; A = thp; B = betap; X = Xp; N = Np; }
  const int bm = blockIdx.y * 64, bn = ct * 64;
  const int tid = threadIdx.x, w = tid >> 6, lane = tid & 63;
  const int wm = (w >> 1) * 32, wn = (w & 1) * 32;
  const int fr = lane & 15, ks = (lane >> 4) * 8;
  const u16* Ar0 = A + (size_t)(bm + wm + fr) * NTP;
  const u16* Ar1 = A + (size_t)(bm + wm + 16 + fr) * NTP;
  bf16x8 a0[4], a1[4];
#pragma unroll
  for (int kt = 0; kt < 4; ++kt) {
    a0[kt] = *(const bf16x8*)(Ar0 + kt * 32 + ks);
    a1[kt] = *(const bf16x8*)(Ar1 + kt * 32 + ks);
  }
  const int gn0 = min(bn + wn + fr, N - 1);
  const int gn1 = min(bn + wn + 16 + fr, N - 1);
  const u16* Br0 = B + (size_t)gn0 * NTP;
  const u16* Br1 = B + (size_t)gn1 * NTP;
  f32x4 acc[2][2] = {};
#pragma unroll
  for (int kt = 0; kt < 4; ++kt) {
    bf16x8 b0 = *(const bf16x8*)(Br0 + kt * 32 + ks);
    bf16x8 b1 = *(const bf16x8*)(Br1 + kt * 32 + ks);
    acc[0][0] = __builtin_amdgcn_mfma_f32_16x16x32_bf16(a0[kt], b0, acc[0][0], 0, 0, 0);
    acc[0][1] = __builtin_amdgcn_mfma_f32_16x16x32_bf16(a0[kt], b1, acc[0][1], 0, 0, 0);
    acc[1][0] = __builtin_amdgcn_mfma_f32_16x16x32_bf16(a1[kt], b0, acc[1][0], 0, 0, 0);
    acc[1][1] = __builtin_amdgcn_mfma_f32_16x16x32_bf16(a1[kt], b1, acc[1][1], 0, 0, 0);
  }
#pragma unroll
  for (int fi = 0; fi < 2; ++fi)
#pragma unroll
    for (int fj = 0; fj < 2; ++fj)
#pragma unroll
      for (int r = 0; r < 4; ++r)
        pred[wm + fi * 16 + (lane >> 4) * 4 + r][wn + fj * 16 + fr] = acc[fi][fj][r];
  __syncthreads();
  float local = 0.f;
  if (bn + 64 <= N) {
#pragma unroll
    for (int k = 0; k < 4; ++k) {
      const int j = k * 1024 + tid * 4;
      const int row = j >> 6, col = j & 63;
      const float4 xv = *(const float4*)(X + (size_t)(bm + row) * N + bn + col);
      local += xv.x * __logf(pred[row][col + 0] + 1e-6f);
      local += xv.y * __logf(pred[row][col + 1] + 1e-6f);
      local += xv.z * __logf(pred[row][col + 2] + 1e-6f);
      local += xv.w * __logf(pred[row][col + 3] + 1e-6f);
    }
  } else {
#pragma unroll
    for (int k = 0; k < 16; ++k) {
      const int idx = k * 256 + tid, row = idx >> 6, col = idx & 63;
      if (bn + col < N)
        local += X[(size_t)(bm + row) * N + bn + col] * __logf(pred[row][col] + 1e-6f);
    }
  }
  for (int o = 32; o > 0; o >>= 1) local += __shfl_down(local, o);
  if (lane == 0) wsum[w] = local;
  __syncthreads();
  if (tid == 0)
    partials[(size_t)blockIdx.y * gridDim.x + blockIdx.x] =
        wsum[0] + wsum[1] + wsum[2] + wsum[3];
}

__global__ __launch_bounds__(256) void final_recon(
    const float* __restrict__ partials, int n, float* __restrict__ out) {
  float s = 0.f;
  for (int i = threadIdx.x; i < n; i += 256) s += partials[i];
  __shared__ float red[256];
  red[threadIdx.x] = s; __syncthreads();
  for (int o = 128; o > 0; o >>= 1) {
    if (threadIdx.x < o) red[threadIdx.x] += red[threadIdx.x + o];
    __syncthreads();
  }
  if (threadIdx.x == 0) out[0] = -red[0] * (1.f / BATCH);
}

// ---------------------------------------------------------------------------
// Paired bias+relu+BN.
// ---------------------------------------------------------------------------
__global__ __launch_bounds__(256) void bias_relu_bn2(
    const float* __restrict__ Hg, const float* __restrict__ bg,
    const float* __restrict__ gg, const float* __restrict__ beg,
    u16* __restrict__ og,
    const float* __restrict__ Hp, const float* __restrict__ bp,
    const float* __restrict__ gp, const float* __restrict__ bep,
    u16* __restrict__ op) {
  int c = blockIdx.x;
  const float *H, *b, *gma, *be; u16* ob;
  if (c < TH) { H = Hg; b = bg; gma = gg; be = beg; ob = og; }
  else { c -= TH; H = Hp; b = bp; gma = gp; be = bep; ob = op; }
  const int r = threadIdx.x;
  float v = fmaxf(H[(size_t)r * TH + c] + b[c], 0.f);
  __shared__ float red[BATCH];
  red[r] = v; __syncthreads();
  for (int s = BATCH / 2; s > 0; s >>= 1) { if (r < s) red[r] += red[r + s]; __syncthreads(); }
  const float mean = red[0] * (1.f / BATCH);
  __syncthreads();
  const float d = v - mean;
  red[r] = d * d; __syncthreads();
  for (int s = BATCH / 2; s > 0; s >>= 1) { if (r < s) red[r] += red[r + s]; __syncthreads(); }
  const float var = red[0] * (1.f / BATCH);
  ob[(size_t)r * TH + c] = f2bf(d * rsqrtf(var + BN_EPS) * gma[c] + be[c]);
}

// ---------------------------------------------------------------------------
// KL + theta for both encoders.
// ---------------------------------------------------------------------------
__global__ __launch_bounds__(128) void row_kl_theta(
    const float* __restrict__ mld, const float* __restrict__ mlj,
    const float* __restrict__ mu_b, const float* __restrict__ ls_b,
    u16* __restrict__ thd, u16* __restrict__ thj, float* __restrict__ kl_out) {
  const float* ml = blockIdx.y ? mlj : mld;
  u16* thb = blockIdx.y ? thj : thd;
  const int b = blockIdx.x;
  const int t = threadIdx.x;
  const bool act = (t < NT);
  float mu = 0.f, ls = 0.f, term = 0.f;
  if (act) {
    mu = ml[(size_t)b * NT2 + t] + mu_b[t];
    ls = 2.f * (ml[(size_t)b * NT2 + NT + t] + ls_b[t]);
    term = 1.f + ls - mu * mu - expf(ls);
  }
  __shared__ float red[128];
  red[t] = act ? term : 0.f; __syncthreads();
  for (int s = 64; s > 0; s >>= 1) { if (t < s) red[t] += red[t + s]; __syncthreads(); }
  if (t == 0) atomicAdd(kl_out, -0.5f * red[0] * (1.f / BATCH));
  __syncthreads();
  red[t] = act ? mu : -INFINITY; __syncthreads();
  for (int s = 64; s > 0; s >>= 1) { if (t < s) red[t] = fmaxf(red[t], red[t + s]); __syncthreads(); }
  const float mx = red[0];
  __syncthreads();
  const float e = act ? expf(mu - mx) : 0.f;
  red[t] = e; __syncthreads();
  for (int s = 64; s > 0; s >>= 1) { if (t < s) red[t] += red[t + s]; __syncthreads(); }
  thb[(size_t)b * NTP + t] = act ? f2bf(e / red[0]) : (u16)0;
}

// --------------------------- CSR build kernels -----------------------------
__global__ __launch_bounds__(256) void deg_count(
    const int* __restrict__ ei, int* __restrict__ deg) {
  int e = blockIdx.x * 256 + threadIdx.x;
  if (e >= E_TOTAL) return;
  const int d = (e < N_EDGES) ? ei[N_EDGES + e] : e - N_EDGES;
  atomicAdd(&deg[d], 1);
}

// Hierarchical scan: per-block sums -> tiny serial scan -> local scan+write.
__global__ __launch_bounds__(256) void scan_part(
    const int* __restrict__ deg, int* __restrict__ bsum) {
  const int base = blockIdx.x * SCAN_CHUNK + threadIdx.x * 4;
  int s = 0;
#pragma unroll
  for (int i = 0; i < 4; ++i) {
    const int idx = base + i;
    if (idx < N_NODES) s += deg[idx];
  }
  for (int o = 32; o > 0; o >>= 1) s += __shfl_down(s, o);
  __shared__ int ws[4];
  if ((threadIdx.x & 63) == 0) ws[threadIdx.x >> 6] = s;
  __syncthreads();
  if (threadIdx.x == 0) bsum[blockIdx.x] = ws[0] + ws[1] + ws[2] + ws[3];
}

__global__ __launch_bounds__(64) void scan_bsum(int* __restrict__ bsum) {
  if (threadIdx.x == 0) {
    int run = 0;
    for (int i = 0; i < SCAN_NB; ++i) { int v = bsum[i]; bsum[i] = run; run += v; }
  }
}

__global__ __launch_bounds__(256) void scan_final(
    const int* __restrict__ deg, const int* __restrict__ bsum,
    int* __restrict__ row_ptr) {
  const int t = threadIdx.x;
  const int base = blockIdx.x * SCAN_CHUNK + t * 4;
  int v[4], s = 0;
#pragma unroll
  for (int i = 0; i < 4; ++i) {
    const int idx = base + i;
    v[i] = (idx < N_NODES) ? deg[idx] : 0;
    s += v[i];
  }
  const int lane = t & 63, w = t >> 6;
  int x = s;
  for (int o = 1; o < 64; o <<= 1) {
    int y = __shfl_up(x, o);
    if (lane >= o) x += y;
  }
  __shared__ int wtot[4];
  if (lane == 63) wtot[w] = x;
  __syncthreads();
  int woff = 0;
  for (int i = 0; i < w; ++i) woff += wtot[i];
  int excl = bsum[blockIdx.x] + woff + x - s;
#pragma unroll
  for (int i = 0; i < 4; ++i) {
    const int idx = base + i;
    if (idx < N_NODES) { row_ptr[idx] = excl; excl += v[i]; }
  }
  if (blockIdx.x == 0 && t == 0) row_ptr[N_NODES] = E_TOTAL;
}

__global__ __launch_bounds__(256) void csr_scatter(
    const int* __restrict__ ei, const int* __restrict__ row_ptr,
    int* __restrict__ cur, int* __restrict__ csr_src) {
  int e = blockIdx.x * 256 + threadIdx.x;
  if (e >= E_TOTAL) return;
  int s, d;
  if (e < N_EDGES) { s = ei[e]; d = ei[N_EDGES + e]; }
  else { s = d = e - N_EDGES; }
  const int pos = atomicAdd(&cur[d], 1);
  csr_src[row_ptr[d] + pos] = s;
}

// ---------------------------------------------------------------------------
// Fused GATv2 layer, 4-way edge-parallel (16-lane groups), bf16 in/out.
// ---------------------------------------------------------------------------
template <int C>
__global__ __launch_bounds__(256) void gat_fused(
    const u16* __restrict__ xl, const u16* __restrict__ xr,
    const float* __restrict__ att, const float* __restrict__ bias,
    const int* __restrict__ row_ptr, const int* __restrict__ csr_src,
    u16* __restrict__ out_b) {
  constexpr int CPL = C / 16;
  const int lane = threadIdx.x & 63;
  const int g = lane >> 4, li = lane & 15;
  const int d = blockIdx.x * 4 + (threadIdx.x >> 6);
  if (d >= N_NODES) return;
  const int c0 = li * CPL;
  float xrv[CPL], attv[CPL], acc[CPL];
#pragma unroll
  for (int i = 0; i < CPL; ++i) {
    xrv[i] = bf2f(xr[(size_t)d * C + c0 + i]);
    attv[i] = att[c0 + i];
    acc[i] = 0.f;
  }
  float m = -INFINITY, den = 0.f;
  const int end = row_ptr[d + 1];
  int p = row_ptr[d] + g;
  int s = (p < end) ? csr_src[p] : 0;
  while (p < end) {
    const int sn = (p + 4 < end) ? csr_src[p + 4] : 0;
    float xlv[CPL];
    float part = 0.f;
#pragma unroll
    for (int i = 0; i < CPL; ++i) {
      xlv[i] = bf2f(xl[(size_t)s * C + c0 + i]);
      float x = xlv[i] + xrv[i];
      x = (x > 0.f) ? x : 0.2f * x;
      part += x * attv[i];
    }
    part += __shfl_xor(part, 1);
    part += __shfl_xor(part, 2);
    part += __shfl_xor(part, 4);
    part += __shfl_xor(part, 8);
    const float logit = part;
    const float nm = fmaxf(m, logit);
    const float scale = expf(m - nm);
    const float ex = expf(logit - nm);
    den = den * scale + ex;
#pragma unroll
    for (int i = 0; i < CPL; ++i) acc[i] = acc[i] * scale + ex * xlv[i];
    m = nm;
    p += 4;
    s = sn;
  }
  float M = m;
  M = fmaxf(M, __shfl_xor(M, 16));
  M = fmaxf(M, __shfl_xor(M, 32));
  const float gs = expf(m - M);
  den *= gs;
  den += __shfl_xor(den, 16);
  den += __shfl_xor(den, 32);
  const float inv = 1.f / (den + 1e-16f);
  float va[CPL];
#pragma unroll
  for (int i = 0; i < CPL; ++i) {
    float a = acc[i] * gs;
    a += __shfl_xor(a, 16);
    a += __shfl_xor(a, 32);
    va[i] = a;
  }
  if (g == 0) {
#pragma unroll
    for (int i = 0; i < CPL; ++i)
      out_b[(size_t)d * C + c0 + i] = f2bf(fmaxf(va[i] * inv + bias[c0 + i], 0.f));
  }
}

// init cmax (ordered -inf) + cden (0) in one tiny launch
__global__ __launch_bounds__(256) void init_cm(u32* __restrict__ cmax,
                                               float* __restrict__ cden) {
  const int i = threadIdx.x;
  if (i < 2 * NT) { cmax[i] = 0x007FFFFFu; cden[i] = 0.f; }
}

// ----------------------- column softmax statistics -------------------------
__global__ __launch_bounds__(256) void col_max(
    const float* __restrict__ Lg, const float* __restrict__ Lp,
    u32* __restrict__ gmx) {
  const float* L = blockIdx.y ? Lp : Lg;
  const int M = blockIdx.y ? NUM_PEAK : NUM_GENE;
  u32* mx = gmx + blockIdx.y * NT;
  const int r0 = blockIdx.x * 128;
  if (r0 >= M) return;
  __shared__ u32 s[NT];
  for (int i = threadIdx.x; i < NT; i += 256) s[i] = 0x007FFFFFu;
  __syncthreads();
  const int cnt = min(128, M - r0) * NT;
  const float* base = L + (size_t)r0 * NT;
  for (int i = threadIdx.x; i < cnt; i += 256) {
    const int c = i % NT;
    atomicMax(&s[c], f2o(base[i]));
  }
  __syncthreads();
  for (int i = threadIdx.x; i < NT; i += 256) atomicMax(&mx[i], s[i]);
}

__global__ __launch_bounds__(256) void col_sumexp(
    const float* __restrict__ Lg, const float* __restrict__ Lp,
    const u32* __restrict__ gmx, float* __restrict__ gden) {
  const float* L = blockIdx.y ? Lp : Lg;
  const int M = blockIdx.y ? NUM_PEAK : NUM_GENE;
  const u32* mxg = gmx + blockIdx.y * NT;
  float* dng = gden + blockIdx.y * NT;
  const int r0 = blockIdx.x * 128;
  if (r0 >= M) return;
  __shared__ float mx[NT];
  __shared__ float s[NT];
  for (int i = threadIdx.x; i < NT; i += 256) { mx[i] = o2f(mxg[i]); s[i] = 0.f; }
  __syncthreads();
  const int cnt = min(128, M - r0) * NT;
  const float* base = L + (size_t)r0 * NT;
  for (int i = threadIdx.x; i < cnt; i += 256) {
    const int c = i % NT;
    atomicAdd(&s[c], expf(base[i] - mx[c]));
  }
  __syncthreads();
  for (int i = threadIdx.x; i < NT; i += 256) atomicAdd(&dng[i], s[i]);
}

__global__ __launch_bounds__(256) void beta_norm(
    const float* __restrict__ Lg, const float* __restrict__ Lp,
    const u32* __restrict__ gmx, const float* __restrict__ gden,
    u16* __restrict__ og, u16* __restrict__ op) {
  const float* L = blockIdx.y ? Lp : Lg;
  const int M = blockIdx.y ? NUM_PEAK : NUM_GENE;
  const u32* mxg = gmx + blockIdx.y * NT;
  const float* dng = gden + blockIdx.y * NT;
  u16* o = blockIdx.y ? op : og;
  __shared__ float mx[NT], inv[NT];
  for (int i = threadIdx.x; i < NT; i += 256) { mx[i] = o2f(mxg[i]); inv[i] = 1.f / dng[i]; }
  __syncthreads();
  const size_t total = (size_t)M * NTP;
  size_t i = (size_t)blockIdx.x * 256 + threadIdx.x;
  const size_t stride = (size_t)gridDim.x * 256;
  for (; i < total; i += stride) {
    const int c = (int)(i & (NTP - 1));
    u16 v = 0;
    if (c < NT) {
      const size_t r = i >> 7;
      v = f2bf(expf(L[r * NT + c] - mx[c]) * inv[c]);
    }
    o[i] = v;
  }
}

// ---------------------------------------------------------------------------
extern "C" void kernel_launch(void* const* d_in, const int* in_sizes, int n_in,
                              void* d_out, int out_size, void* d_ws, size_t ws_size,
                              hipStream_t stream) {
  const float* Gene  = (const float*)d_in[0];
  const float* GeneN = (const float*)d_in[1];
  const float* Peak  = (const float*)d_in[2];
  const float* PeakN = (const float*)d_in[3];
  const float* feat  = (const float*)d_in[4];
  const float* Wl1 = (const float*)d_in[5];  const float* bl1 = (const float*)d_in[6];
  const float* Wr1 = (const float*)d_in[7];  const float* br1 = (const float*)d_in[8];
  const float* att1 = (const float*)d_in[9]; const float* bias1 = (const float*)d_in[10];
  const float* Wl2 = (const float*)d_in[11]; const float* bl2 = (const float*)d_in[12];
  const float* Wr2 = (const float*)d_in[13]; const float* br2 = (const float*)d_in[14];
  const float* att2 = (const float*)d_in[15]; const float* bias2 = (const float*)d_in[16];
  const float* gW1 = (const float*)d_in[17]; const float* gb1 = (const float*)d_in[18];
  const float* gg1 = (const float*)d_in[19]; const float* gbe1 = (const float*)d_in[20];
  const float* gW2 = (const float*)d_in[21]; const float* gb2 = (const float*)d_in[22];
  const float* gg2 = (const float*)d_in[23]; const float* gbe2 = (const float*)d_in[24];
  const float* pW1 = (const float*)d_in[25]; const float* pb1 = (const float*)d_in[26];
  const float* pg1 = (const float*)d_in[27]; const float* pbe1 = (const float*)d_in[28];
  const float* pW2 = (const float*)d_in[29]; const float* pb2 = (const float*)d_in[30];
  const float* pg2 = (const float*)d_in[31]; const float* pbe2 = (const float*)d_in[32];
  const float* mu_W = (const float*)d_in[33]; const float* mu_b = (const float*)d_in[34];
  const float* ls_W = (const float*)d_in[35]; const float* ls_b = (const float*)d_in[36];
  const float* alphas_W = (const float*)d_in[37];
  const float* alphas_star_W = (const float*)d_in[38];
  const int* ei = (const int*)d_in[39];
  float* out = (float*)d_out;
  (void)in_sizes; (void)n_in; (void)ws_size;

  // ---- workspace layout (bytes) ----
  char* base = (char*)d_ws;
  size_t off = 0;
  auto A = [&](size_t bytes) { void* p = base + off; off += (bytes + 255) & ~(size_t)255; return p; };
  int* deg     = (int*)A((size_t)N_NODES * 4);      // deg+cur adjacent (one memset)
  int* cur     = (int*)A((size_t)N_NODES * 4);
  int* row_ptr = (int*)A((size_t)(N_NODES + 1) * 4);
  int* bsum    = (int*)A((size_t)(SCAN_NB + 1) * 4);
  int* csr_src = (int*)A((size_t)E_TOTAL * 4);
  float* h1g = (float*)A((size_t)BATCH * TH * 4);   // h1g+h1p adjacent (one memset)
  float* h1p = (float*)A((size_t)BATCH * TH * 4);
  float* h2g = (float*)A((size_t)BATCH * TH * 4);
  float* h2p = (float*)A((size_t)BATCH * TH * 4);
  u16* h1gb = (u16*)A((size_t)BATCH * TH * 2);
  u16* h2gb = (u16*)A((size_t)BATCH * TH * 2);
  u16* h1pb = (u16*)A((size_t)BATCH * TH * 2);
  u16* h2pb = (u16*)A((size_t)BATCH * TH * 2);
  float* ml_d = (float*)A((size_t)BATCH * NT2 * 4);
  float* ml_j = (float*)A((size_t)BATCH * NT2 * 4);
  u16* th_db = (u16*)A((size_t)BATCH * NTP * 2);
  u16* th_jb = (u16*)A((size_t)BATCH * NTP * 2);
  float* lgg = (float*)A((size_t)NUM_GENE * NT * 4);
  float* lgp = (float*)A((size_t)NUM_PEAK * NT * 4);
  u16* betagb = (u16*)A((size_t)NUM_GENE * NTP * 2);
  u16* betapb = (u16*)A((size_t)NUM_PEAK * NTP * 2);
  u16* featb = (u16*)A((size_t)N_NODES * EMB * 2);
  u16* gW2b = (u16*)A((size_t)TH * TH * 2);
  u16* pW2b = (u16*)A((size_t)TH * TH * 2);
  u16* mlWb = (u16*)A((size_t)NT2 * TH * 2);
  u16* Wl1b = (u16*)A((size_t)HID * EMB * 2);
  u16* Wr1b = (u16*)A((size_t)HID * EMB * 2);
  u16* Wl2b = (u16*)A((size_t)EMB * HID * 2);
  u16* Wr2b = (u16*)A((size_t)EMB * HID * 2);
  u16* aWb  = (u16*)A((size_t)NT * EMB * 2);
  u16* aSWb = (u16*)A((size_t)NT * EMB * 2);
  u16* agg1b = (u16*)A((size_t)N_NODES * HID * 2);
  u16* embb  = (u16*)A((size_t)N_NODES * EMB * 2);
  u32* cmax = (u32*)A(2 * NT * 4);
  float* cden = (float*)A(2 * NT * 4);
  float* partials = (float*)A(4096 * 4);
  u16* xl1b = (u16*)A((size_t)N_NODES * HID * 2);
  u16* xr1b = (u16*)A((size_t)N_NODES * HID * 2);
  u16* xl2b = (u16*)A((size_t)N_NODES * EMB * 2);
  u16* xr2b = (u16*)A((size_t)N_NODES * EMB * 2);

  auto cdiv = [](int a, int b) { return (a + b - 1) / b; };
  auto Z = [&](void* p, size_t bytes) { hipMemsetAsync(p, 0, bytes, stream); };

  Z(d_out, (size_t)out_size * sizeof(float));
  Z(deg, 2 * (size_t)N_NODES * 4);                    // deg + cur

  // ---- CSR build (hierarchical scan, no single-block serialization) ----
  deg_count<<<cdiv(E_TOTAL, 256), 256, 0, stream>>>(ei, deg);
  scan_part<<<SCAN_NB, 256, 0, stream>>>(deg, bsum);
  scan_bsum<<<1, 64, 0, stream>>>(bsum);
  scan_final<<<SCAN_NB, 256, 0, stream>>>(deg, bsum, row_ptr);
  csr_scatter<<<cdiv(E_TOTAL, 256), 256, 0, stream>>>(ei, row_ptr, cur, csr_src);

  // ---- small fp32->bf16 conversions in one launch ----
  {
    CvtJobs J = {};
    int c = 0; u32 blocks = 0;
    auto add = [&](const float* s, u16* d, size_t n) {
      J.src[c] = s; J.dst[c] = d; J.n[c] = (u32)n; J.start[c] = blocks;
      blocks += (u32)((n + 2047) / 2048); ++c;
    };
    add(gW2, gW2b, (size_t)TH * TH);
    add(pW2, pW2b, (size_t)TH * TH);
    add(mu_W, mlWb, (size_t)NT * TH);
    add(ls_W, mlWb + (size_t)NT * TH, (size_t)NT * TH);
    add(feat, featb, (size_t)N_NODES * EMB);
    add(Wl1, Wl1b, (size_t)HID * EMB);
    add(Wr1, Wr1b, (size_t)HID * EMB);
    add(Wl2, Wl2b, (size_t)EMB * HID);
    add(Wr2, Wr2b, (size_t)EMB * HID);
    add(alphas_W, aWb, (size_t)NT * EMB);
    add(alphas_star_W, aSWb, (size_t)NT * EMB);
    J.count = c;
    cvt_all<<<blocks, 256, 0, stream>>>(J);
  }

  GP Zp = {};   // zero template

  // ================= encoders =================
  const int ksp = 16;
  const int chG = ((cdiv(NUM_GENE, ksp) + 31) / 32) * 32;   // 768
  const int chP = ((cdiv(NUM_PEAK, ksp) + 31) / 32) * 32;   // 1760
  Z(h1g, 2 * (size_t)BATCH * TH * 4);                 // h1g + h1p
  gemm_enc1<<<dim3(TH / 64, 1, 2 * ksp), 256, 0, stream>>>(
      GeneN, gW1, h1g, NUM_GENE, chG,
      PeakN, pW1, h1p, NUM_PEAK, chP, ksp);
  bias_relu_bn2<<<2 * TH, BATCH, 0, stream>>>(h1g, gb1, gg1, gbe1, h1gb,
                                              h1p, pb1, pg1, pbe1, h1pb);
  {
    GP g = {h1gb, gW2b, h2g, nullptr, nullptr, BATCH, TH, TH, TH};
    GP p = {h1pb, pW2b, h2p, nullptr, nullptr, BATCH, TH, TH, TH};
    gemm_bt_bf16<<<dim3(TH / 64, BATCH / 64, 2), 256, 0, stream>>>(g, p, 1);
  }
  bias_relu_bn2<<<2 * TH, BATCH, 0, stream>>>(h2g, gb2, gg2, gbe2, h2gb,
                                              h2p, pb2, pg2, pbe2, h2pb);
  {
    GP g = {h2gb, mlWb, ml_d, nullptr, nullptr, BATCH, NT2, TH, TH};
    GP p = {h2pb, mlWb, ml_j, nullptr, nullptr, BATCH, NT2, TH, TH};
    gemm_bt_bf16<<<dim3(cdiv(NT2, 64), BATCH / 64, 2), 256, 0, stream>>>(g, p, 1);
  }
  row_kl_theta<<<dim3(BATCH, 2), 128, 0, stream>>>(ml_d, ml_j, mu_b, ls_b, th_db, th_jb, out + 1);

  // ================= GAT layer 1 =================
  {
    GP l = {featb, Wl1b, nullptr, xl1b, bl1, N_NODES, HID, EMB, EMB};
    GP r = {featb, Wr1b, nullptr, xr1b, br1, N_NODES, HID, EMB, EMB};
    gemm_bt_bf16<<<dim3(HID / 64, N_NODES / 64, 2), 256, 0, stream>>>(l, r, 1);
  }
  gat_fused<HID><<<N_NODES / 4, 256, 0, stream>>>(xl1b, xr1b, att1, bias1, row_ptr, csr_src, agg1b);

  // ================= GAT layer 2 =================
  {
    GP l = {agg1b, Wl2b, nullptr, xl2b, bl2, N_NODES, EMB, HID, HID};
    GP r = {agg1b, Wr2b, nullptr, xr2b, br2, N_NODES, EMB, HID, HID};
    gemm_bt_bf16<<<dim3(EMB / 64, N_NODES / 64, 2), 256, 0, stream>>>(l, r, 1);
  }
  gat_fused<EMB><<<N_NODES / 4, 256, 0, stream>>>(xl2b, xr2b, att2, bias2, row_ptr, csr_src, embb);

  // ================= topic heads =================
  {
    GP g = {embb + (size_t)NUM_PEAK * EMB, aWb, lgg, nullptr, nullptr, NUM_GENE, NT, EMB, EMB};
    GP p = {embb, aSWb, lgp, nullptr, nullptr, NUM_PEAK, NT, EMB, EMB};
    gemm_bt_bf16<<<dim3(2, cdiv(NUM_PEAK, 64), 2), 256, 0, stream>>>(g, p, 1);
  }
  init_cm<<<1, 256, 0, stream>>>(cmax, cden);
  col_max<<<dim3(cdiv(NUM_PEAK, 128), 2), 256, 0, stream>>>(lgg, lgp, cmax);
  col_sumexp<<<dim3(cdiv(NUM_PEAK, 128), 2), 256, 0, stream>>>(lgg, lgp, cmax, cden);
  beta_norm<<<dim3(1024, 2), 256, 0, stream>>>(lgg, lgp, cmax, cden, betagb, betapb);

  // ================= fused preds + recon ============
  const int tiles_g = cdiv(NUM_GENE, 64);
  const int tiles_p = cdiv(NUM_PEAK, 64);
  const int tiles = tiles_g + tiles_p;
  recon_fused<<<dim3(tiles, 4), 256, 0, stream>>>(
      th_db, betagb, Gene, NUM_GENE, tiles_g,
      th_jb, betapb, Peak, NUM_PEAK, partials);
  final_recon<<<1, 256, 0, stream>>>(partials, tiles * 4, out);
}

// Round 8
// 434.542 us; speedup vs baseline: 5.1643x; 1.1421x over previous
//
#include <hip/hip_runtime.h>
#include <cstdint>
#include <cstddef>

using u16 = unsigned short;
using u32 = unsigned int;
typedef __attribute__((ext_vector_type(8))) short bf16x8;
typedef __attribute__((ext_vector_type(4))) float f32x4;

static constexpr int NUM_PEAK = 28000;
static constexpr int NUM_GENE = 12000;
static constexpr int N_NODES  = NUM_PEAK + NUM_GENE;   // 40000
static constexpr int N_EDGES  = 640000;
static constexpr int E_TOTAL  = N_EDGES + N_NODES;     // 680000
static constexpr int NT       = 100;
static constexpr int NT2      = 200;                   // mu+ls combined
static constexpr int NTP      = 128;                   // padded topic stride
static constexpr int TH       = 512;
static constexpr int EMB      = 64;
static constexpr int HID      = 128;
static constexpr int BATCH    = 256;
static constexpr int SCAN_CHUNK = 1024;
static constexpr int SCAN_NB  = (N_NODES + SCAN_CHUNK - 1) / SCAN_CHUNK;  // 40
static constexpr int ENC_CH   = 320;                   // enc1 k-chunk (mult of 32)
#define BN_EPS 1e-5f

__device__ __forceinline__ u16 f2bf(float f) {
  u32 b = __float_as_uint(f);
  return (u16)((b + 0x7FFFu + ((b >> 16) & 1u)) >> 16);
}
__device__ __forceinline__ float bf2f(u16 u) {
  return __uint_as_float((u32)u << 16);
}
__device__ __forceinline__ u32 f2o(float f) {
  u32 u = __float_as_uint(f);
  return (u & 0x80000000u) ? ~u : (u | 0x80000000u);
}
__device__ __forceinline__ float o2f(u32 u) {
  return (u & 0x80000000u) ? __uint_as_float(u & 0x7fffffffu) : __uint_as_float(~u);
}

// ---------------------------------------------------------------------------
// Batched fp32->bf16 conversion (small tensors only).
// ---------------------------------------------------------------------------
struct CvtJobs {
  const float* src[12];
  u16* dst[12];
  u32 n[12];
  u32 start[12];
  int count;
};

__global__ __launch_bounds__(256) void cvt_all(CvtJobs J) {
  const int bid = blockIdx.x;
  int seg = 0;
  while (seg + 1 < J.count && bid >= (int)J.start[seg + 1]) ++seg;
  const float* __restrict__ src = J.src[seg];
  u16* __restrict__ dst = J.dst[seg];
  const u32 n = J.n[seg];
  const u32 i = (u32)(bid - J.start[seg]) * 2048u + threadIdx.x * 8u;
  if (i + 8 <= n) {
    float4 a = *(const float4*)(src + i);
    float4 b = *(const float4*)(src + i + 4);
    ushort4 o0{f2bf(a.x), f2bf(a.y), f2bf(a.z), f2bf(a.w)};
    ushort4 o1{f2bf(b.x), f2bf(b.y), f2bf(b.z), f2bf(b.w)};
    *(ushort4*)(dst + i) = o0;
    *(ushort4*)(dst + i + 4) = o1;
  } else {
    for (u32 j = i; j < n; ++j) dst[j] = f2bf(src[j]);
  }
}

// ---------------------------------------------------------------------------
// bf16 MFMA GEMM: C(M,N) = A(M,K) @ B(N,K)^T. 64x64 tile, 4 waves, BK=32.
// ---------------------------------------------------------------------------
struct GP {
  const u16* A; const u16* B; float* C; u16* Cb; const float* bias;
  int M, N, K, chunk;
};

__global__ __launch_bounds__(256) void gemm_bt_bf16(GP g0, GP g1, int dual) {
  const GP& g = (dual && blockIdx.z) ? g1 : g0;
  const int M = g.M, N = g.N, K = g.K;
  __shared__ u16 As[64][40];
  __shared__ u16 Bs[64][40];
  const int tid = threadIdx.x;
  const int bm = blockIdx.y * 64, bn = blockIdx.x * 64;
  if (bm >= M || bn >= N) return;
  const int k0 = dual ? 0 : blockIdx.z * g.chunk;
  const int k1 = min(K, k0 + g.chunk);
  const int w = tid >> 6, lane = tid & 63;
  const int wm = (w >> 1) * 32, wn = (w & 1) * 32;
  const int fr = lane & 15;
  const int ks = (lane >> 4) * 8;
  const int srow = tid >> 2, sseg = (tid & 3) * 8;
  f32x4 acc[2][2] = {};
  for (int kt = k0; kt < k1; kt += 32) {
    const int gk = kt + sseg;
    {
      const int gm = bm + srow;
      bf16x8 v = {0, 0, 0, 0, 0, 0, 0, 0};
      if (gm < M) {
        if (gk + 8 <= k1) v = *(const bf16x8*)(g.A + (size_t)gm * K + gk);
        else if (gk < k1)
          for (int e = 0; e < k1 - gk; ++e) ((short*)&v)[e] = (short)g.A[(size_t)gm * K + gk + e];
      }
      *(bf16x8*)&As[srow][sseg] = v;
    }
    {
      const int gn = bn + srow;
      bf16x8 v = {0, 0, 0, 0, 0, 0, 0, 0};
      if (gn < N) {
        if (gk + 8 <= k1) v = *(const bf16x8*)(g.B + (size_t)gn * K + gk);
        else if (gk < k1)
          for (int e = 0; e < k1 - gk; ++e) ((short*)&v)[e] = (short)g.B[(size_t)gn * K + gk + e];
      }
      *(bf16x8*)&Bs[srow][sseg] = v;
    }
    __syncthreads();
    bf16x8 a0 = *(const bf16x8*)&As[wm + fr][ks];
    bf16x8 a1 = *(const bf16x8*)&As[wm + 16 + fr][ks];
    bf16x8 b0 = *(const bf16x8*)&Bs[wn + fr][ks];
    bf16x8 b1 = *(const bf16x8*)&Bs[wn + 16 + fr][ks];
    acc[0][0] = __builtin_amdgcn_mfma_f32_16x16x32_bf16(a0, b0, acc[0][0], 0, 0, 0);
    acc[0][1] = __builtin_amdgcn_mfma_f32_16x16x32_bf16(a0, b1, acc[0][1], 0, 0, 0);
    acc[1][0] = __builtin_amdgcn_mfma_f32_16x16x32_bf16(a1, b0, acc[1][0], 0, 0, 0);
    acc[1][1] = __builtin_amdgcn_mfma_f32_16x16x32_bf16(a1, b1, acc[1][1], 0, 0, 0);
    __syncthreads();
  }
  const bool split = (!dual && gridDim.z > 1);
#pragma unroll
  for (int fi = 0; fi < 2; ++fi)
#pragma unroll
    for (int fj = 0; fj < 2; ++fj)
#pragma unroll
      for (int r = 0; r < 4; ++r) {
        const int row = bm + wm + fi * 16 + (lane >> 4) * 4 + r;
        const int col = bn + wn + fj * 16 + fr;
        if (row < M && col < N) {
          const float v = acc[fi][fj][r];
          if (split) atomicAdd(&g.C[(size_t)row * N + col], v);
          else if (g.Cb) g.Cb[(size_t)row * N + col] = f2bf(v + (g.bias ? g.bias[col] : 0.f));
          else g.C[(size_t)row * N + col] = v + (g.bias ? g.bias[col] : 0.f);
        }
      }
}

// ---------------------------------------------------------------------------
// Encoder layer-1 GEMM v2. Both problems in one launch, fused fp32->bf16.
// 512 threads / 8 waves; M-tile 256 (full batch), N-tile 128; wave w owns a
// 64x64 sub-tile. grid = (TH/128, 1, kspG+kspP), chunk = ENC_CH (mult of 32;
// K % 32 == 0 so no k bounds needed). k-split atomicAdd into zeroed C.
// LDS XOR-swizzle: colbyte ^= ((row>>1)&3)<<4 -> ~2-way bank aliasing.
// ---------------------------------------------------------------------------
__device__ __forceinline__ int enc_swz(int row, int cb) {
  return (cb & 8) | ((cb & 48) ^ (((row >> 1) & 3) << 4));
}

__global__ __launch_bounds__(512) void gemm_enc1(
    const float* __restrict__ A0, const float* __restrict__ B0, float* __restrict__ C0,
    int K0, int ksp0,
    const float* __restrict__ A1, const float* __restrict__ B1, float* __restrict__ C1,
    int K1) {
  const int z = blockIdx.z;
  const bool second = (z >= ksp0);
  const float* __restrict__ A = second ? A1 : A0;
  const float* __restrict__ B = second ? B1 : B0;
  float* __restrict__ C = second ? C1 : C0;
  const int K = second ? K1 : K0;
  const int zz = second ? z - ksp0 : z;
  const int k0 = zz * ENC_CH;
  const int k1 = min(K, k0 + ENC_CH);
  __shared__ u16 As[256 * 32];
  __shared__ u16 Bs[128 * 32];
  const int tid = threadIdx.x;
  const int bn = blockIdx.x * 128;
  const int w = tid >> 6, lane = tid & 63;
  const int wm = (w >> 1) * 64;        // 0,64,128,192
  const int wn = (w & 1) * 64;         // 0,64
  const int fr = lane & 15, g = lane >> 4;
  // staging indices
  const int ar = tid >> 1, acol = (tid & 1) * 16;        // A: 16 cols/thread
  const int br = tid >> 2, bcol = (tid & 3) * 8;         // B: 8 cols/thread
  f32x4 acc[4][4] = {};
  for (int kt = k0; kt < k1; kt += 32) {
    {  // stage A 256x32 (fp32 -> bf16, swizzled)
      const float* src = A + (size_t)ar * K + kt + acol;
      float4 f0 = *(const float4*)src;
      float4 f1 = *(const float4*)(src + 4);
      float4 f2 = *(const float4*)(src + 8);
      float4 f3 = *(const float4*)(src + 12);
      ushort4 o0{f2bf(f0.x), f2bf(f0.y), f2bf(f0.z), f2bf(f0.w)};
      ushort4 o1{f2bf(f1.x), f2bf(f1.y), f2bf(f1.z), f2bf(f1.w)};
      ushort4 o2{f2bf(f2.x), f2bf(f2.y), f2bf(f2.z), f2bf(f2.w)};
      ushort4 o3{f2bf(f3.x), f2bf(f3.y), f2bf(f3.z), f2bf(f3.w)};
      const int cb = acol * 2;
      *(ushort4*)&As[ar * 32 + (enc_swz(ar, cb) >> 1)] = o0;
      *(ushort4*)&As[ar * 32 + (enc_swz(ar, cb + 8) >> 1)] = o1;
      *(ushort4*)&As[ar * 32 + (enc_swz(ar, cb + 16) >> 1)] = o2;
      *(ushort4*)&As[ar * 32 + (enc_swz(ar, cb + 24) >> 1)] = o3;
    }
    {  // stage B 128x32
      const float* src = B + (size_t)(bn + br) * K + kt + bcol;
      float4 f0 = *(const float4*)src;
      float4 f1 = *(const float4*)(src + 4);
      ushort4 o0{f2bf(f0.x), f2bf(f0.y), f2bf(f0.z), f2bf(f0.w)};
      ushort4 o1{f2bf(f1.x), f2bf(f1.y), f2bf(f1.z), f2bf(f1.w)};
      const int cb = bcol * 2;
      *(ushort4*)&Bs[br * 32 + (enc_swz(br, cb) >> 1)] = o0;
      *(ushort4*)&Bs[br * 32 + (enc_swz(br, cb + 8) >> 1)] = o1;
    }
    __syncthreads();
    bf16x8 bfr[4];
#pragma unroll
    for (int fj = 0; fj < 4; ++fj) {
      const int Rb = wn + fj * 16 + fr;
      bfr[fj] = *(const bf16x8*)&Bs[Rb * 32 + (enc_swz(Rb, g * 16) >> 1)];
    }
#pragma unroll
    for (int fi = 0; fi < 4; ++fi) {
      const int Ra = wm + fi * 16 + fr;
      bf16x8 a = *(const bf16x8*)&As[Ra * 32 + (enc_swz(Ra, g * 16) >> 1)];
#pragma unroll
      for (int fj = 0; fj < 4; ++fj)
        acc[fi][fj] = __builtin_amdgcn_mfma_f32_16x16x32_bf16(a, bfr[fj], acc[fi][fj], 0, 0, 0);
    }
    __syncthreads();
  }
#pragma unroll
  for (int fi = 0; fi < 4; ++fi)
#pragma unroll
    for (int fj = 0; fj < 4; ++fj)
#pragma unroll
      for (int r = 0; r < 4; ++r) {
        const int row = wm + fi * 16 + g * 4 + r;
        const int col = bn + wn + fj * 16 + fr;
        atomicAdd(&C[(size_t)row * TH + col], acc[fi][fj][r]);
      }
}

// ---------------------------------------------------------------------------
// Fused recon for BOTH matrices; block-private partials (no contended atomic).
// ---------------------------------------------------------------------------
__global__ __launch_bounds__(256) void recon_fused(
    const u16* __restrict__ thg, const u16* __restrict__ betag,
    const float* __restrict__ Xg, int Ng, int tiles_g,
    const u16* __restrict__ thp, const u16* __restrict__ betap,
    const float* __restrict__ Xp, int Np, float* __restrict__ partials) {
  __shared__ float pred[64][65];
  __shared__ float wsum[4];
  int ct = blockIdx.x;
  const u16* A; const u16* B; const float* X; int N;
  if (ct < tiles_g) { A = thg; B = betag; X = Xg; N = Ng; }
  else { ct -= tiles_g; A = thp; B = betap; X = Xp; N = Np; }
  const int bm = blockIdx.y * 64, bn = ct * 64;
  const int tid = threadIdx.x, w = tid >> 6, lane = tid & 63;
  const int wm = (w >> 1) * 32, wn = (w & 1) * 32;
  const int fr = lane & 15, ks = (lane >> 4) * 8;
  const u16* Ar0 = A + (size_t)(bm + wm + fr) * NTP;
  const u16* Ar1 = A + (size_t)(bm + wm + 16 + fr) * NTP;
  bf16x8 a0[4], a1[4];
#pragma unroll
  for (int kt = 0; kt < 4; ++kt) {
    a0[kt] = *(const bf16x8*)(Ar0 + kt * 32 + ks);
    a1[kt] = *(const bf16x8*)(Ar1 + kt * 32 + ks);
  }
  const int gn0 = min(bn + wn + fr, N - 1);
  const int gn1 = min(bn + wn + 16 + fr, N - 1);
  const u16* Br0 = B + (size_t)gn0 * NTP;
  const u16* Br1 = B + (size_t)gn1 * NTP;
  f32x4 acc[2][2] = {};
#pragma unroll
  for (int kt = 0; kt < 4; ++kt) {
    bf16x8 b0 = *(const bf16x8*)(Br0 + kt * 32 + ks);
    bf16x8 b1 = *(const bf16x8*)(Br1 + kt * 32 + ks);
    acc[0][0] = __builtin_amdgcn_mfma_f32_16x16x32_bf16(a0[kt], b0, acc[0][0], 0, 0, 0);
    acc[0][1] = __builtin_amdgcn_mfma_f32_16x16x32_bf16(a0[kt], b1, acc[0][1], 0, 0, 0);
    acc[1][0] = __builtin_amdgcn_mfma_f32_16x16x32_bf16(a1[kt], b0, acc[1][0], 0, 0, 0);
    acc[1][1] = __builtin_amdgcn_mfma_f32_16x16x32_bf16(a1[kt], b1, acc[1][1], 0, 0, 0);
  }
#pragma unroll
  for (int fi = 0; fi < 2; ++fi)
#pragma unroll
    for (int fj = 0; fj < 2; ++fj)
#pragma unroll
      for (int r = 0; r < 4; ++r)
        pred[wm + fi * 16 + (lane >> 4) * 4 + r][wn + fj * 16 + fr] = acc[fi][fj][r];
  __syncthreads();
  float local = 0.f;
  if (bn + 64 <= N) {
#pragma unroll
    for (int k = 0; k < 4; ++k) {
      const int j = k * 1024 + tid * 4;
      const int row = j >> 6, col = j & 63;
      const float4 xv = *(const float4*)(X + (size_t)(bm + row) * N + bn + col);
      local += xv.x * __logf(pred[row][col + 0] + 1e-6f);
      local += xv.y * __logf(pred[row][col + 1] + 1e-6f);
      local += xv.z * __logf(pred[row][col + 2] + 1e-6f);
      local += xv.w * __logf(pred[row][col + 3] + 1e-6f);
    }
  } else {
#pragma unroll
    for (int k = 0; k < 16; ++k) {
      const int idx = k * 256 + tid, row = idx >> 6, col = idx & 63;
      if (bn + col < N)
        local += X[(size_t)(bm + row) * N + bn + col] * __logf(pred[row][col] + 1e-6f);
    }
  }
  for (int o = 32; o > 0; o >>= 1) local += __shfl_down(local, o);
  if (lane == 0) wsum[w] = local;
  __syncthreads();
  if (tid == 0)
    partials[(size_t)blockIdx.y * gridDim.x + blockIdx.x] =
        wsum[0] + wsum[1] + wsum[2] + wsum[3];
}

__global__ __launch_bounds__(256) void final_recon(
    const float* __restrict__ partials, int n, float* __restrict__ out) {
  float s = 0.f;
  for (int i = threadIdx.x; i < n; i += 256) s += partials[i];
  __shared__ float red[256];
  red[threadIdx.x] = s; __syncthreads();
  for (int o = 128; o > 0; o >>= 1) {
    if (threadIdx.x < o) red[threadIdx.x] += red[threadIdx.x + o];
    __syncthreads();
  }
  if (threadIdx.x == 0) out[0] = -red[0] * (1.f / BATCH);
}

// ---------------------------------------------------------------------------
// Paired bias+relu+BN.
// ---------------------------------------------------------------------------
__global__ __launch_bounds__(256) void bias_relu_bn2(
    const float* __restrict__ Hg, const float* __restrict__ bg,
    const float* __restrict__ gg, const float* __restrict__ beg,
    u16* __restrict__ og,
    const float* __restrict__ Hp, const float* __restrict__ bp,
    const float* __restrict__ gp, const float* __restrict__ bep,
    u16* __restrict__ op) {
  int c = blockIdx.x;
  const float *H, *b, *gma, *be; u16* ob;
  if (c < TH) { H = Hg; b = bg; gma = gg; be = beg; ob = og; }
  else { c -= TH; H = Hp; b = bp; gma = gp; be = bep; ob = op; }
  const int r = threadIdx.x;
  float v = fmaxf(H[(size_t)r * TH + c] + b[c], 0.f);
  __shared__ float red[BATCH];
  red[r] = v; __syncthreads();
  for (int s = BATCH / 2; s > 0; s >>= 1) { if (r < s) red[r] += red[r + s]; __syncthreads(); }
  const float mean = red[0] * (1.f / BATCH);
  __syncthreads();
  const float d = v - mean;
  red[r] = d * d; __syncthreads();
  for (int s = BATCH / 2; s > 0; s >>= 1) { if (r < s) red[r] += red[r + s]; __syncthreads(); }
  const float var = red[0] * (1.f / BATCH);
  ob[(size_t)r * TH + c] = f2bf(d * rsqrtf(var + BN_EPS) * gma[c] + be[c]);
}

// ---------------------------------------------------------------------------
// KL + theta for both encoders.
// ---------------------------------------------------------------------------
__global__ __launch_bounds__(128) void row_kl_theta(
    const float* __restrict__ mld, const float* __restrict__ mlj,
    const float* __restrict__ mu_b, const float* __restrict__ ls_b,
    u16* __restrict__ thd, u16* __restrict__ thj, float* __restrict__ kl_out) {
  const float* ml = blockIdx.y ? mlj : mld;
  u16* thb = blockIdx.y ? thj : thd;
  const int b = blockIdx.x;
  const int t = threadIdx.x;
  const bool act = (t < NT);
  float mu = 0.f, ls = 0.f, term = 0.f;
  if (act) {
    mu = ml[(size_t)b * NT2 + t] + mu_b[t];
    ls = 2.f * (ml[(size_t)b * NT2 + NT + t] + ls_b[t]);
    term = 1.f + ls - mu * mu - expf(ls);
  }
  __shared__ float red[128];
  red[t] = act ? term : 0.f; __syncthreads();
  for (int s = 64; s > 0; s >>= 1) { if (t < s) red[t] += red[t + s]; __syncthreads(); }
  if (t == 0) atomicAdd(kl_out, -0.5f * red[0] * (1.f / BATCH));
  __syncthreads();
  red[t] = act ? mu : -INFINITY; __syncthreads();
  for (int s = 64; s > 0; s >>= 1) { if (t < s) red[t] = fmaxf(red[t], red[t + s]); __syncthreads(); }
  const float mx = red[0];
  __syncthreads();
  const float e = act ? expf(mu - mx) : 0.f;
  red[t] = e; __syncthreads();
  for (int s = 64; s > 0; s >>= 1) { if (t < s) red[t] += red[t + s]; __syncthreads(); }
  thb[(size_t)b * NTP + t] = act ? f2bf(e / red[0]) : (u16)0;
}

// --------------------------- CSR build kernels -----------------------------
__global__ __launch_bounds__(256) void deg_count(
    const int* __restrict__ ei, int* __restrict__ deg) {
  int e = blockIdx.x * 256 + threadIdx.x;
  if (e >= E_TOTAL) return;
  const int d = (e < N_EDGES) ? ei[N_EDGES + e] : e - N_EDGES;
  atomicAdd(&deg[d], 1);
}

__global__ __launch_bounds__(256) void scan_part(
    const int* __restrict__ deg, int* __restrict__ bsum) {
  const int base = blockIdx.x * SCAN_CHUNK + threadIdx.x * 4;
  int s = 0;
#pragma unroll
  for (int i = 0; i < 4; ++i) {
    const int idx = base + i;
    if (idx < N_NODES) s += deg[idx];
  }
  for (int o = 32; o > 0; o >>= 1) s += __shfl_down(s, o);
  __shared__ int ws[4];
  if ((threadIdx.x & 63) == 0) ws[threadIdx.x >> 6] = s;
  __syncthreads();
  if (threadIdx.x == 0) bsum[blockIdx.x] = ws[0] + ws[1] + ws[2] + ws[3];
}

__global__ __launch_bounds__(64) void scan_bsum(int* __restrict__ bsum) {
  if (threadIdx.x == 0) {
    int run = 0;
    for (int i = 0; i < SCAN_NB; ++i) { int v = bsum[i]; bsum[i] = run; run += v; }
  }
}

__global__ __launch_bounds__(256) void scan_final(
    const int* __restrict__ deg, const int* __restrict__ bsum,
    int* __restrict__ row_ptr) {
  const int t = threadIdx.x;
  const int base = blockIdx.x * SCAN_CHUNK + t * 4;
  int v[4], s = 0;
#pragma unroll
  for (int i = 0; i < 4; ++i) {
    const int idx = base + i;
    v[i] = (idx < N_NODES) ? deg[idx] : 0;
    s += v[i];
  }
  const int lane = t & 63, w = t >> 6;
  int x = s;
  for (int o = 1; o < 64; o <<= 1) {
    int y = __shfl_up(x, o);
    if (lane >= o) x += y;
  }
  __shared__ int wtot[4];
  if (lane == 63) wtot[w] = x;
  __syncthreads();
  int woff = 0;
  for (int i = 0; i < w; ++i) woff += wtot[i];
  int excl = bsum[blockIdx.x] + woff + x - s;
#pragma unroll
  for (int i = 0; i < 4; ++i) {
    const int idx = base + i;
    if (idx < N_NODES) { row_ptr[idx] = excl; excl += v[i]; }
  }
  if (blockIdx.x == 0 && t == 0) row_ptr[N_NODES] = E_TOTAL;
}

__global__ __launch_bounds__(256) void csr_scatter(
    const int* __restrict__ ei, const int* __restrict__ row_ptr,
    int* __restrict__ cur, int* __restrict__ csr_src) {
  int e = blockIdx.x * 256 + threadIdx.x;
  if (e >= E_TOTAL) return;
  int s, d;
  if (e < N_EDGES) { s = ei[e]; d = ei[N_EDGES + e]; }
  else { s = d = e - N_EDGES; }
  const int pos = atomicAdd(&cur[d], 1);
  csr_src[row_ptr[d] + pos] = s;
}

// ---------------------------------------------------------------------------
// Fused GATv2 layer, 4-way edge-parallel (16-lane groups), bf16 in/out.
// ---------------------------------------------------------------------------
template <int C>
__global__ __launch_bounds__(256) void gat_fused(
    const u16* __restrict__ xl, const u16* __restrict__ xr,
    const float* __restrict__ att, const float* __restrict__ bias,
    const int* __restrict__ row_ptr, const int* __restrict__ csr_src,
    u16* __restrict__ out_b) {
  constexpr int CPL = C / 16;
  const int lane = threadIdx.x & 63;
  const int g = lane >> 4, li = lane & 15;
  const int d = blockIdx.x * 4 + (threadIdx.x >> 6);
  if (d >= N_NODES) return;
  const int c0 = li * CPL;
  float xrv[CPL], attv[CPL], acc[CPL];
#pragma unroll
  for (int i = 0; i < CPL; ++i) {
    xrv[i] = bf2f(xr[(size_t)d * C + c0 + i]);
    attv[i] = att[c0 + i];
    acc[i] = 0.f;
  }
  float m = -INFINITY, den = 0.f;
  const int end = row_ptr[d + 1];
  int p = row_ptr[d] + g;
  int s = (p < end) ? csr_src[p] : 0;
  while (p < end) {
    const int sn = (p + 4 < end) ? csr_src[p + 4] : 0;
    float xlv[CPL];
    float part = 0.f;
#pragma unroll
    for (int i = 0; i < CPL; ++i) {
      xlv[i] = bf2f(xl[(size_t)s * C + c0 + i]);
      float x = xlv[i] + xrv[i];
      x = (x > 0.f) ? x : 0.2f * x;
      part += x * attv[i];
    }
    part += __shfl_xor(part, 1);
    part += __shfl_xor(part, 2);
    part += __shfl_xor(part, 4);
    part += __shfl_xor(part, 8);
    const float logit = part;
    const float nm = fmaxf(m, logit);
    const float scale = expf(m - nm);
    const float ex = expf(logit - nm);
    den = den * scale + ex;
#pragma unroll
    for (int i = 0; i < CPL; ++i) acc[i] = acc[i] * scale + ex * xlv[i];
    m = nm;
    p += 4;
    s = sn;
  }
  float M = m;
  M = fmaxf(M, __shfl_xor(M, 16));
  M = fmaxf(M, __shfl_xor(M, 32));
  const float gs = expf(m - M);
  den *= gs;
  den += __shfl_xor(den, 16);
  den += __shfl_xor(den, 32);
  const float inv = 1.f / (den + 1e-16f);
  float va[CPL];
#pragma unroll
  for (int i = 0; i < CPL; ++i) {
    float a = acc[i] * gs;
    a += __shfl_xor(a, 16);
    a += __shfl_xor(a, 32);
    va[i] = a;
  }
  if (g == 0) {
#pragma unroll
    for (int i = 0; i < CPL; ++i)
      out_b[(size_t)d * C + c0 + i] = f2bf(fmaxf(va[i] * inv + bias[c0 + i], 0.f));
  }
}

__global__ __launch_bounds__(256) void init_cm(u32* __restrict__ cmax,
                                               float* __restrict__ cden) {
  const int i = threadIdx.x;
  if (i < 2 * NT) { cmax[i] = 0x007FFFFFu; cden[i] = 0.f; }
}

// ----------------------- column softmax statistics -------------------------
__global__ __launch_bounds__(256) void col_max(
    const float* __restrict__ Lg, const float* __restrict__ Lp,
    u32* __restrict__ gmx) {
  const float* L = blockIdx.y ? Lp : Lg;
  const int M = blockIdx.y ? NUM_PEAK : NUM_GENE;
  u32* mx = gmx + blockIdx.y * NT;
  const int r0 = blockIdx.x * 128;
  if (r0 >= M) return;
  __shared__ u32 s[NT];
  for (int i = threadIdx.x; i < NT; i += 256) s[i] = 0x007FFFFFu;
  __syncthreads();
  const int cnt = min(128, M - r0) * NT;
  const float* base = L + (size_t)r0 * NT;
  for (int i = threadIdx.x; i < cnt; i += 256) {
    const int c = i % NT;
    atomicMax(&s[c], f2o(base[i]));
  }
  __syncthreads();
  for (int i = threadIdx.x; i < NT; i += 256) atomicMax(&mx[i], s[i]);
}

__global__ __launch_bounds__(256) void col_sumexp(
    const float* __restrict__ Lg, const float* __restrict__ Lp,
    const u32* __restrict__ gmx, float* __restrict__ gden) {
  const float* L = blockIdx.y ? Lp : Lg;
  const int M = blockIdx.y ? NUM_PEAK : NUM_GENE;
  const u32* mxg = gmx + blockIdx.y * NT;
  float* dng = gden + blockIdx.y * NT;
  const int r0 = blockIdx.x * 128;
  if (r0 >= M) return;
  __shared__ float mx[NT];
  __shared__ float s[NT];
  for (int i = threadIdx.x; i < NT; i += 256) { mx[i] = o2f(mxg[i]); s[i] = 0.f; }
  __syncthreads();
  const int cnt = min(128, M - r0) * NT;
  const float* base = L + (size_t)r0 * NT;
  for (int i = threadIdx.x; i < cnt; i += 256) {
    const int c = i % NT;
    atomicAdd(&s[c], expf(base[i] - mx[c]));
  }
  __syncthreads();
  for (int i = threadIdx.x; i < NT; i += 256) atomicAdd(&dng[i], s[i]);
}

__global__ __launch_bounds__(256) void beta_norm(
    const float* __restrict__ Lg, const float* __restrict__ Lp,
    const u32* __restrict__ gmx, const float* __restrict__ gden,
    u16* __restrict__ og, u16* __restrict__ op) {
  const float* L = blockIdx.y ? Lp : Lg;
  const int M = blockIdx.y ? NUM_PEAK : NUM_GENE;
  const u32* mxg = gmx + blockIdx.y * NT;
  const float* dng = gden + blockIdx.y * NT;
  u16* o = blockIdx.y ? op : og;
  __shared__ float mx[NT], inv[NT];
  for (int i = threadIdx.x; i < NT; i += 256) { mx[i] = o2f(mxg[i]); inv[i] = 1.f / dng[i]; }
  __syncthreads();
  const size_t total = (size_t)M * NTP;
  size_t i = (size_t)blockIdx.x * 256 + threadIdx.x;
  const size_t stride = (size_t)gridDim.x * 256;
  for (; i < total; i += stride) {
    const int c = (int)(i & (NTP - 1));
    u16 v = 0;
    if (c < NT) {
      const size_t r = i >> 7;
      v = f2bf(expf(L[r * NT + c] - mx[c]) * inv[c]);
    }
    o[i] = v;
  }
}

// ---------------------------------------------------------------------------
extern "C" void kernel_launch(void* const* d_in, const int* in_sizes, int n_in,
                              void* d_out, int out_size, void* d_ws, size_t ws_size,
                              hipStream_t stream) {
  const float* Gene  = (const float*)d_in[0];
  const float* GeneN = (const float*)d_in[1];
  const float* Peak  = (const float*)d_in[2];
  const float* PeakN = (const float*)d_in[3];
  const float* feat  = (const float*)d_in[4];
  const float* Wl1 = (const float*)d_in[5];  const float* bl1 = (const float*)d_in[6];
  const float* Wr1 = (const float*)d_in[7];  const float* br1 = (const float*)d_in[8];
  const float* att1 = (const float*)d_in[9]; const float* bias1 = (const float*)d_in[10];
  const float* Wl2 = (const float*)d_in[11]; const float* bl2 = (const float*)d_in[12];
  const float* Wr2 = (const float*)d_in[13]; const float* br2 = (const float*)d_in[14];
  const float* att2 = (const float*)d_in[15]; const float* bias2 = (const float*)d_in[16];
  const float* gW1 = (const float*)d_in[17]; const float* gb1 = (const float*)d_in[18];
  const float* gg1 = (const float*)d_in[19]; const float* gbe1 = (const float*)d_in[20];
  const float* gW2 = (const float*)d_in[21]; const float* gb2 = (const float*)d_in[22];
  const float* gg2 = (const float*)d_in[23]; const float* gbe2 = (const float*)d_in[24];
  const float* pW1 = (const float*)d_in[25]; const float* pb1 = (const float*)d_in[26];
  const float* pg1 = (const float*)d_in[27]; const float* pbe1 = (const float*)d_in[28];
  const float* pW2 = (const float*)d_in[29]; const float* pb2 = (const float*)d_in[30];
  const float* pg2 = (const float*)d_in[31]; const float* pbe2 = (const float*)d_in[32];
  const float* mu_W = (const float*)d_in[33]; const float* mu_b = (const float*)d_in[34];
  const float* ls_W = (const float*)d_in[35]; const float* ls_b = (const float*)d_in[36];
  const float* alphas_W = (const float*)d_in[37];
  const float* alphas_star_W = (const float*)d_in[38];
  const int* ei = (const int*)d_in[39];
  float* out = (float*)d_out;
  (void)in_sizes; (void)n_in; (void)ws_size;

  // ---- workspace layout (bytes) ----
  char* base = (char*)d_ws;
  size_t off = 0;
  auto A = [&](size_t bytes) { void* p = base + off; off += (bytes + 255) & ~(size_t)255; return p; };
  int* deg     = (int*)A((size_t)N_NODES * 4);      // deg+cur adjacent (one memset)
  int* cur     = (int*)A((size_t)N_NODES * 4);
  int* row_ptr = (int*)A((size_t)(N_NODES + 1) * 4);
  int* bsum    = (int*)A((size_t)(SCAN_NB + 1) * 4);
  int* csr_src = (int*)A((size_t)E_TOTAL * 4);
  float* h1g = (float*)A((size_t)BATCH * TH * 4);   // h1g+h1p adjacent (one memset)
  float* h1p = (float*)A((size_t)BATCH * TH * 4);
  float* h2g = (float*)A((size_t)BATCH * TH * 4);
  float* h2p = (float*)A((size_t)BATCH * TH * 4);
  u16* h1gb = (u16*)A((size_t)BATCH * TH * 2);
  u16* h2gb = (u16*)A((size_t)BATCH * TH * 2);
  u16* h1pb = (u16*)A((size_t)BATCH * TH * 2);
  u16* h2pb = (u16*)A((size_t)BATCH * TH * 2);
  float* ml_d = (float*)A((size_t)BATCH * NT2 * 4);
  float* ml_j = (float*)A((size_t)BATCH * NT2 * 4);
  u16* th_db = (u16*)A((size_t)BATCH * NTP * 2);
  u16* th_jb = (u16*)A((size_t)BATCH * NTP * 2);
  float* lgg = (float*)A((size_t)NUM_GENE * NT * 4);
  float* lgp = (float*)A((size_t)NUM_PEAK * NT * 4);
  u16* betagb = (u16*)A((size_t)NUM_GENE * NTP * 2);
  u16* betapb = (u16*)A((size_t)NUM_PEAK * NTP * 2);
  u16* featb = (u16*)A((size_t)N_NODES * EMB * 2);
  u16* gW2b = (u16*)A((size_t)TH * TH * 2);
  u16* pW2b = (u16*)A((size_t)TH * TH * 2);
  u16* mlWb = (u16*)A((size_t)NT2 * TH * 2);
  u16* Wl1b = (u16*)A((size_t)HID * EMB * 2);
  u16* Wr1b = (u16*)A((size_t)HID * EMB * 2);
  u16* Wl2b = (u16*)A((size_t)EMB * HID * 2);
  u16* Wr2b = (u16*)A((size_t)EMB * HID * 2);
  u16* aWb  = (u16*)A((size_t)NT * EMB * 2);
  u16* aSWb = (u16*)A((size_t)NT * EMB * 2);
  u16* agg1b = (u16*)A((size_t)N_NODES * HID * 2);
  u16* embb  = (u16*)A((size_t)N_NODES * EMB * 2);
  u32* cmax = (u32*)A(2 * NT * 4);
  float* cden = (float*)A(2 * NT * 4);
  float* partials = (float*)A(4096 * 4);
  u16* xl1b = (u16*)A((size_t)N_NODES * HID * 2);
  u16* xr1b = (u16*)A((size_t)N_NODES * HID * 2);
  u16* xl2b = (u16*)A((size_t)N_NODES * EMB * 2);
  u16* xr2b = (u16*)A((size_t)N_NODES * EMB * 2);

  auto cdiv = [](int a, int b) { return (a + b - 1) / b; };
  auto Z = [&](void* p, size_t bytes) { hipMemsetAsync(p, 0, bytes, stream); };

  Z(d_out, (size_t)out_size * sizeof(float));
  Z(deg, 2 * (size_t)N_NODES * 4);                    // deg + cur

  // ---- CSR build (hierarchical scan) ----
  deg_count<<<cdiv(E_TOTAL, 256), 256, 0, stream>>>(ei, deg);
  scan_part<<<SCAN_NB, 256, 0, stream>>>(deg, bsum);
  scan_bsum<<<1, 64, 0, stream>>>(bsum);
  scan_final<<<SCAN_NB, 256, 0, stream>>>(deg, bsum, row_ptr);
  csr_scatter<<<cdiv(E_TOTAL, 256), 256, 0, stream>>>(ei, row_ptr, cur, csr_src);

  // ---- small fp32->bf16 conversions in one launch ----
  {
    CvtJobs J = {};
    int c = 0; u32 blocks = 0;
    auto add = [&](const float* s, u16* d, size_t n) {
      J.src[c] = s; J.dst[c] = d; J.n[c] = (u32)n; J.start[c] = blocks;
      blocks += (u32)((n + 2047) / 2048); ++c;
    };
    add(gW2, gW2b, (size_t)TH * TH);
    add(pW2, pW2b, (size_t)TH * TH);
    add(mu_W, mlWb, (size_t)NT * TH);
    add(ls_W, mlWb + (size_t)NT * TH, (size_t)NT * TH);
    add(feat, featb, (size_t)N_NODES * EMB);
    add(Wl1, Wl1b, (size_t)HID * EMB);
    add(Wr1, Wr1b, (size_t)HID * EMB);
    add(Wl2, Wl2b, (size_t)EMB * HID);
    add(Wr2, Wr2b, (size_t)EMB * HID);
    add(alphas_W, aWb, (size_t)NT * EMB);
    add(alphas_star_W, aSWb, (size_t)NT * EMB);
    J.count = c;
    cvt_all<<<blocks, 256, 0, stream>>>(J);
  }

  // ================= encoders =================
  const int kspG = cdiv(NUM_GENE, ENC_CH);   // 38
  const int kspP = cdiv(NUM_PEAK, ENC_CH);   // 88
  Z(h1g, 2 * (size_t)BATCH * TH * 4);                 // h1g + h1p
  gemm_enc1<<<dim3(TH / 128, 1, kspG + kspP), 512, 0, stream>>>(
      GeneN, gW1, h1g, NUM_GENE, kspG,
      PeakN, pW1, h1p, NUM_PEAK);
  bias_relu_bn2<<<2 * TH, BATCH, 0, stream>>>(h1g, gb1, gg1, gbe1, h1gb,
                                              h1p, pb1, pg1, pbe1, h1pb);
  {
    GP g = {h1gb, gW2b, h2g, nullptr, nullptr, BATCH, TH, TH, TH};
    GP p = {h1pb, pW2b, h2p, nullptr, nullptr, BATCH, TH, TH, TH};
    gemm_bt_bf16<<<dim3(TH / 64, BATCH / 64, 2), 256, 0, stream>>>(g, p, 1);
  }
  bias_relu_bn2<<<2 * TH, BATCH, 0, stream>>>(h2g, gb2, gg2, gbe2, h2gb,
                                              h2p, pb2, pg2, pbe2, h2pb);
  {
    GP g = {h2gb, mlWb, ml_d, nullptr, nullptr, BATCH, NT2, TH, TH};
    GP p = {h2pb, mlWb, ml_j, nullptr, nullptr, BATCH, NT2, TH, TH};
    gemm_bt_bf16<<<dim3(cdiv(NT2, 64), BATCH / 64, 2), 256, 0, stream>>>(g, p, 1);
  }
  row_kl_theta<<<dim3(BATCH, 2), 128, 0, stream>>>(ml_d, ml_j, mu_b, ls_b, th_db, th_jb, out + 1);

  // ================= GAT layer 1 =================
  {
    GP l = {featb, Wl1b, nullptr, xl1b, bl1, N_NODES, HID, EMB, EMB};
    GP r = {featb, Wr1b, nullptr, xr1b, br1, N_NODES, HID, EMB, EMB};
    gemm_bt_bf16<<<dim3(HID / 64, N_NODES / 64, 2), 256, 0, stream>>>(l, r, 1);
  }
  gat_fused<HID><<<N_NODES / 4, 256, 0, stream>>>(xl1b, xr1b, att1, bias1, row_ptr, csr_src, agg1b);

  // ================= GAT layer 2 =================
  {
    GP l = {agg1b, Wl2b, nullptr, xl2b, bl2, N_NODES, EMB, HID, HID};
    GP r = {agg1b, Wr2b, nullptr, xr2b, br2, N_NODES, EMB, HID, HID};
    gemm_bt_bf16<<<dim3(EMB / 64, N_NODES / 64, 2), 256, 0, stream>>>(l, r, 1);
  }
  gat_fused<EMB><<<N_NODES / 4, 256, 0, stream>>>(xl2b, xr2b, att2, bias2, row_ptr, csr_src, embb);

  // ================= topic heads =================
  {
    GP g = {embb + (size_t)NUM_PEAK * EMB, aWb, lgg, nullptr, nullptr, NUM_GENE, NT, EMB, EMB};
    GP p = {embb, aSWb, lgp, nullptr, nullptr, NUM_PEAK, NT, EMB, EMB};
    gemm_bt_bf16<<<dim3(2, cdiv(NUM_PEAK, 64), 2), 256, 0, stream>>>(g, p, 1);
  }
  init_cm<<<1, 256, 0, stream>>>(cmax, cden);
  col_max<<<dim3(cdiv(NUM_PEAK, 128), 2), 256, 0, stream>>>(lgg, lgp, cmax);
  col_sumexp<<<dim3(cdiv(NUM_PEAK, 128), 2), 256, 0, stream>>>(lgg, lgp, cmax, cden);
  beta_norm<<<dim3(1024, 2), 256, 0, stream>>>(lgg, lgp, cmax, cden, betagb, betapb);

  // ================= fused preds + recon ============
  const int tiles_g = cdiv(NUM_GENE, 64);
  const int tiles_p = cdiv(NUM_PEAK, 64);
  const int tiles = tiles_g + tiles_p;
  recon_fused<<<dim3(tiles, 4), 256, 0, stream>>>(
      th_db, betagb, Gene, NUM_GENE, tiles_g,
      th_jb, betapb, Peak, NUM_PEAK, partials);
  final_recon<<<1, 256, 0, stream>>>(partials, tiles * 4, out);
}

// Round 9
// 430.849 us; speedup vs baseline: 5.2086x; 1.0086x over previous
//
#include <hip/hip_runtime.h>
#include <cstdint>
#include <cstddef>

using u16 = unsigned short;
using u32 = unsigned int;
typedef __attribute__((ext_vector_type(8))) short bf16x8;
typedef __attribute__((ext_vector_type(4))) float f32x4;

static constexpr int NUM_PEAK = 28000;
static constexpr int NUM_GENE = 12000;
static constexpr int N_NODES  = NUM_PEAK + NUM_GENE;   // 40000
static constexpr int N_EDGES  = 640000;
static constexpr int E_TOTAL  = N_EDGES + N_NODES;     // 680000
static constexpr int NT       = 100;
static constexpr int NT2      = 200;                   // mu+ls combined
static constexpr int NTP      = 128;                   // padded topic stride
static constexpr int TH       = 512;
static constexpr int EMB      = 64;
static constexpr int HID      = 128;
static constexpr int BATCH    = 256;
static constexpr int SCAN_CHUNK = 1024;
static constexpr int SCAN_NB  = (N_NODES + SCAN_CHUNK - 1) / SCAN_CHUNK;  // 40
static constexpr int ENC_CH   = 320;                   // enc1 k-chunk (mult of 32)
#define BN_EPS 1e-5f

__device__ __forceinline__ u16 f2bf(float f) {
  u32 b = __float_as_uint(f);
  return (u16)((b + 0x7FFFu + ((b >> 16) & 1u)) >> 16);
}
__device__ __forceinline__ float bf2f(u16 u) {
  return __uint_as_float((u32)u << 16);
}
__device__ __forceinline__ u32 f2o(float f) {
  u32 u = __float_as_uint(f);
  return (u & 0x80000000u) ? ~u : (u | 0x80000000u);
}
__device__ __forceinline__ float o2f(u32 u) {
  return (u & 0x80000000u) ? __uint_as_float(u & 0x7fffffffu) : __uint_as_float(~u);
}

// ---------------------------------------------------------------------------
// Batched fp32->bf16 conversion (small tensors only).
// ---------------------------------------------------------------------------
struct CvtJobs {
  const float* src[12];
  u16* dst[12];
  u32 n[12];
  u32 start[12];
  int count;
};

__global__ __launch_bounds__(256) void cvt_all(CvtJobs J) {
  const int bid = blockIdx.x;
  int seg = 0;
  while (seg + 1 < J.count && bid >= (int)J.start[seg + 1]) ++seg;
  const float* __restrict__ src = J.src[seg];
  u16* __restrict__ dst = J.dst[seg];
  const u32 n = J.n[seg];
  const u32 i = (u32)(bid - J.start[seg]) * 2048u + threadIdx.x * 8u;
  if (i + 8 <= n) {
    float4 a = *(const float4*)(src + i);
    float4 b = *(const float4*)(src + i + 4);
    ushort4 o0{f2bf(a.x), f2bf(a.y), f2bf(a.z), f2bf(a.w)};
    ushort4 o1{f2bf(b.x), f2bf(b.y), f2bf(b.z), f2bf(b.w)};
    *(ushort4*)(dst + i) = o0;
    *(ushort4*)(dst + i + 4) = o1;
  } else {
    for (u32 j = i; j < n; ++j) dst[j] = f2bf(src[j]);
  }
}

// ---------------------------------------------------------------------------
// bf16 MFMA GEMM: C(M,N) = A(M,K) @ B(N,K)^T. 64x64 tile, 4 waves, BK=32.
// ---------------------------------------------------------------------------
struct GP {
  const u16* A; const u16* B; float* C; u16* Cb; const float* bias;
  int M, N, K, chunk;
};

__global__ __launch_bounds__(256) void gemm_bt_bf16(GP g0, GP g1, int dual) {
  const GP& g = (dual && blockIdx.z) ? g1 : g0;
  const int M = g.M, N = g.N, K = g.K;
  __shared__ u16 As[64][40];
  __shared__ u16 Bs[64][40];
  const int tid = threadIdx.x;
  const int bm = blockIdx.y * 64, bn = blockIdx.x * 64;
  if (bm >= M || bn >= N) return;
  const int k0 = dual ? 0 : blockIdx.z * g.chunk;
  const int k1 = min(K, k0 + g.chunk);
  const int w = tid >> 6, lane = tid & 63;
  const int wm = (w >> 1) * 32, wn = (w & 1) * 32;
  const int fr = lane & 15;
  const int ks = (lane >> 4) * 8;
  const int srow = tid >> 2, sseg = (tid & 3) * 8;
  f32x4 acc[2][2] = {};
  for (int kt = k0; kt < k1; kt += 32) {
    const int gk = kt + sseg;
    {
      const int gm = bm + srow;
      bf16x8 v = {0, 0, 0, 0, 0, 0, 0, 0};
      if (gm < M) {
        if (gk + 8 <= k1) v = *(const bf16x8*)(g.A + (size_t)gm * K + gk);
        else if (gk < k1)
          for (int e = 0; e < k1 - gk; ++e) ((short*)&v)[e] = (short)g.A[(size_t)gm * K + gk + e];
      }
      *(bf16x8*)&As[srow][sseg] = v;
    }
    {
      const int gn = bn + srow;
      bf16x8 v = {0, 0, 0, 0, 0, 0, 0, 0};
      if (gn < N) {
        if (gk + 8 <= k1) v = *(const bf16x8*)(g.B + (size_t)gn * K + gk);
        else if (gk < k1)
          for (int e = 0; e < k1 - gk; ++e) ((short*)&v)[e] = (short)g.B[(size_t)gn * K + gk + e];
      }
      *(bf16x8*)&Bs[srow][sseg] = v;
    }
    __syncthreads();
    bf16x8 a0 = *(const bf16x8*)&As[wm + fr][ks];
    bf16x8 a1 = *(const bf16x8*)&As[wm + 16 + fr][ks];
    bf16x8 b0 = *(const bf16x8*)&Bs[wn + fr][ks];
    bf16x8 b1 = *(const bf16x8*)&Bs[wn + 16 + fr][ks];
    acc[0][0] = __builtin_amdgcn_mfma_f32_16x16x32_bf16(a0, b0, acc[0][0], 0, 0, 0);
    acc[0][1] = __builtin_amdgcn_mfma_f32_16x16x32_bf16(a0, b1, acc[0][1], 0, 0, 0);
    acc[1][0] = __builtin_amdgcn_mfma_f32_16x16x32_bf16(a1, b0, acc[1][0], 0, 0, 0);
    acc[1][1] = __builtin_amdgcn_mfma_f32_16x16x32_bf16(a1, b1, acc[1][1], 0, 0, 0);
    __syncthreads();
  }
  const bool split = (!dual && gridDim.z > 1);
#pragma unroll
  for (int fi = 0; fi < 2; ++fi)
#pragma unroll
    for (int fj = 0; fj < 2; ++fj)
#pragma unroll
      for (int r = 0; r < 4; ++r) {
        const int row = bm + wm + fi * 16 + (lane >> 4) * 4 + r;
        const int col = bn + wn + fj * 16 + fr;
        if (row < M && col < N) {
          const float v = acc[fi][fj][r];
          if (split) atomicAdd(&g.C[(size_t)row * N + col], v);
          else if (g.Cb) g.Cb[(size_t)row * N + col] = f2bf(v + (g.bias ? g.bias[col] : 0.f));
          else g.C[(size_t)row * N + col] = v + (g.bias ? g.bias[col] : 0.f);
        }
      }
}

// ---------------------------------------------------------------------------
// Encoder layer-1 GEMM v3: register prefetch + LDS double-buffer, one barrier
// per K-iter. 512 thr / 8 waves; M-tile 256, N-tile 128; wave = 64x64.
// grid = (TH/128, 1, kspG+kspP). Fused fp32->bf16 staging, XOR-swizzled LDS.
// ---------------------------------------------------------------------------
__device__ __forceinline__ int enc_swz(int row, int cb) {
  return (cb & 8) | ((cb & 48) ^ (((row >> 1) & 3) << 4));
}

__global__ __launch_bounds__(512) void gemm_enc1(
    const float* __restrict__ A0, const float* __restrict__ B0, float* __restrict__ C0,
    int K0, int ksp0,
    const float* __restrict__ A1, const float* __restrict__ B1, float* __restrict__ C1,
    int K1) {
  const int z = blockIdx.z;
  const bool second = (z >= ksp0);
  const float* __restrict__ A = second ? A1 : A0;
  const float* __restrict__ B = second ? B1 : B0;
  float* __restrict__ C = second ? C1 : C0;
  const int K = second ? K1 : K0;
  const int zz = second ? z - ksp0 : z;
  const int k0 = zz * ENC_CH;
  const int k1 = min(K, k0 + ENC_CH);
  __shared__ u16 As[2][256 * 32];
  __shared__ u16 Bs[2][128 * 32];
  const int tid = threadIdx.x;
  const int bn = blockIdx.x * 128;
  const int w = tid >> 6, lane = tid & 63;
  const int wm = (w >> 1) * 64;        // 0,64,128,192
  const int wn = (w & 1) * 64;         // 0,64
  const int fr = lane & 15, g = lane >> 4;
  const int ar = tid >> 1, acol = (tid & 1) * 16;        // A: 16 cols/thread
  const int br = tid >> 2, bcol = (tid & 3) * 8;         // B: 8 cols/thread
  const float* Abase = A + (size_t)ar * K + acol;
  const float* Bbase = B + (size_t)(bn + br) * K + bcol;

  float4 rA0, rA1, rA2, rA3, rB0, rB1;
  auto LD = [&](int kt) {
    const float* sa = Abase + kt;
    rA0 = *(const float4*)sa;
    rA1 = *(const float4*)(sa + 4);
    rA2 = *(const float4*)(sa + 8);
    rA3 = *(const float4*)(sa + 12);
    const float* sb = Bbase + kt;
    rB0 = *(const float4*)sb;
    rB1 = *(const float4*)(sb + 4);
  };
  auto ST = [&](int buf) {
    ushort4 o0{f2bf(rA0.x), f2bf(rA0.y), f2bf(rA0.z), f2bf(rA0.w)};
    ushort4 o1{f2bf(rA1.x), f2bf(rA1.y), f2bf(rA1.z), f2bf(rA1.w)};
    ushort4 o2{f2bf(rA2.x), f2bf(rA2.y), f2bf(rA2.z), f2bf(rA2.w)};
    ushort4 o3{f2bf(rA3.x), f2bf(rA3.y), f2bf(rA3.z), f2bf(rA3.w)};
    const int cbA = acol * 2;
    *(ushort4*)&As[buf][ar * 32 + (enc_swz(ar, cbA) >> 1)] = o0;
    *(ushort4*)&As[buf][ar * 32 + (enc_swz(ar, cbA + 8) >> 1)] = o1;
    *(ushort4*)&As[buf][ar * 32 + (enc_swz(ar, cbA + 16) >> 1)] = o2;
    *(ushort4*)&As[buf][ar * 32 + (enc_swz(ar, cbA + 24) >> 1)] = o3;
    ushort4 p0{f2bf(rB0.x), f2bf(rB0.y), f2bf(rB0.z), f2bf(rB0.w)};
    ushort4 p1{f2bf(rB1.x), f2bf(rB1.y), f2bf(rB1.z), f2bf(rB1.w)};
    const int cbB = bcol * 2;
    *(ushort4*)&Bs[buf][br * 32 + (enc_swz(br, cbB) >> 1)] = p0;
    *(ushort4*)&Bs[buf][br * 32 + (enc_swz(br, cbB + 8) >> 1)] = p1;
  };

  f32x4 acc[4][4] = {};
  LD(k0);
  ST(0);
  int cur = 0;
  for (int kt = k0; kt < k1; kt += 32) {
    __syncthreads();                     // buf[cur] visible to all waves
    const bool more = (kt + 32 < k1);
    if (more) LD(kt + 32);               // next tile's loads in flight
    bf16x8 bfr[4];
#pragma unroll
    for (int fj = 0; fj < 4; ++fj) {
      const int Rb = wn + fj * 16 + fr;
      bfr[fj] = *(const bf16x8*)&Bs[cur][Rb * 32 + (enc_swz(Rb, g * 16) >> 1)];
    }
#pragma unroll
    for (int fi = 0; fi < 4; ++fi) {
      const int Ra = wm + fi * 16 + fr;
      bf16x8 a = *(const bf16x8*)&As[cur][Ra * 32 + (enc_swz(Ra, g * 16) >> 1)];
#pragma unroll
      for (int fj = 0; fj < 4; ++fj)
        acc[fi][fj] = __builtin_amdgcn_mfma_f32_16x16x32_bf16(a, bfr[fj], acc[fi][fj], 0, 0, 0);
    }
    if (more) ST(cur ^ 1);               // waits vmcnt, writes OTHER buffer
    cur ^= 1;
  }
#pragma unroll
  for (int fi = 0; fi < 4; ++fi)
#pragma unroll
    for (int fj = 0; fj < 4; ++fj)
#pragma unroll
      for (int r = 0; r < 4; ++r) {
        const int row = wm + fi * 16 + g * 4 + r;
        const int col = bn + wn + fj * 16 + fr;
        atomicAdd(&C[(size_t)row * TH + col], acc[fi][fj][r]);
      }
}

// ---------------------------------------------------------------------------
// Fused recon for BOTH matrices; block-private partials (no contended atomic).
// ---------------------------------------------------------------------------
__global__ __launch_bounds__(256) void recon_fused(
    const u16* __restrict__ thg, const u16* __restrict__ betag,
    const float* __restrict__ Xg, int Ng, int tiles_g,
    const u16* __restrict__ thp, const u16* __restrict__ betap,
    const float* __restrict__ Xp, int Np, float* __restrict__ partials) {
  __shared__ float pred[64][65];
  __shared__ float wsum[4];
  int ct = blockIdx.x;
  const u16* A; const u16* B; const float* X; int N;
  if (ct < tiles_g) { A = thg; B = betag; X = Xg; N = Ng; }
  else { ct -= tiles_g; A = thp; B = betap; X = Xp; N = Np; }
  const int bm = blockIdx.y * 64, bn = ct * 64;
  const int tid = threadIdx.x, w = tid >> 6, lane = tid & 63;
  const int wm = (w >> 1) * 32, wn = (w & 1) * 32;
  const int fr = lane & 15, ks = (lane >> 4) * 8;
  const u16* Ar0 = A + (size_t)(bm + wm + fr) * NTP;
  const u16* Ar1 = A + (size_t)(bm + wm + 16 + fr) * NTP;
  bf16x8 a0[4], a1[4];
#pragma unroll
  for (int kt = 0; kt < 4; ++kt) {
    a0[kt] = *(const bf16x8*)(Ar0 + kt * 32 + ks);
    a1[kt] = *(const bf16x8*)(Ar1 + kt * 32 + ks);
  }
  const int gn0 = min(bn + wn + fr, N - 1);
  const int gn1 = min(bn + wn + 16 + fr, N - 1);
  const u16* Br0 = B + (size_t)gn0 * NTP;
  const u16* Br1 = B + (size_t)gn1 * NTP;
  f32x4 acc[2][2] = {};
#pragma unroll
  for (int kt = 0; kt < 4; ++kt) {
    bf16x8 b0 = *(const bf16x8*)(Br0 + kt * 32 + ks);
    bf16x8 b1 = *(const bf16x8*)(Br1 + kt * 32 + ks);
    acc[0][0] = __builtin_amdgcn_mfma_f32_16x16x32_bf16(a0[kt], b0, acc[0][0], 0, 0, 0);
    acc[0][1] = __builtin_amdgcn_mfma_f32_16x16x32_bf16(a0[kt], b1, acc[0][1], 0, 0, 0);
    acc[1][0] = __builtin_amdgcn_mfma_f32_16x16x32_bf16(a1[kt], b0, acc[1][0], 0, 0, 0);
    acc[1][1] = __builtin_amdgcn_mfma_f32_16x16x32_bf16(a1[kt], b1, acc[1][1], 0, 0, 0);
  }
#pragma unroll
  for (int fi = 0; fi < 2; ++fi)
#pragma unroll
    for (int fj = 0; fj < 2; ++fj)
#pragma unroll
      for (int r = 0; r < 4; ++r)
        pred[wm + fi * 16 + (lane >> 4) * 4 + r][wn + fj * 16 + fr] = acc[fi][fj][r];
  __syncthreads();
  float local = 0.f;
  if (bn + 64 <= N) {
#pragma unroll
    for (int k = 0; k < 4; ++k) {
      const int j = k * 1024 + tid * 4;
      const int row = j >> 6, col = j & 63;
      const float4 xv = *(const float4*)(X + (size_t)(bm + row) * N + bn + col);
      local += xv.x * __logf(pred[row][col + 0] + 1e-6f);
      local += xv.y * __logf(pred[row][col + 1] + 1e-6f);
      local += xv.z * __logf(pred[row][col + 2] + 1e-6f);
      local += xv.w * __logf(pred[row][col + 3] + 1e-6f);
    }
  } else {
#pragma unroll
    for (int k = 0; k < 16; ++k) {
      const int idx = k * 256 + tid, row = idx >> 6, col = idx & 63;
      if (bn + col < N)
        local += X[(size_t)(bm + row) * N + bn + col] * __logf(pred[row][col] + 1e-6f);
    }
  }
  for (int o = 32; o > 0; o >>= 1) local += __shfl_down(local, o);
  if (lane == 0) wsum[w] = local;
  __syncthreads();
  if (tid == 0)
    partials[(size_t)blockIdx.y * gridDim.x + blockIdx.x] =
        wsum[0] + wsum[1] + wsum[2] + wsum[3];
}

__global__ __launch_bounds__(256) void final_recon(
    const float* __restrict__ partials, int n, float* __restrict__ out) {
  float s = 0.f;
  for (int i = threadIdx.x; i < n; i += 256) s += partials[i];
  __shared__ float red[256];
  red[threadIdx.x] = s; __syncthreads();
  for (int o = 128; o > 0; o >>= 1) {
    if (threadIdx.x < o) red[threadIdx.x] += red[threadIdx.x + o];
    __syncthreads();
  }
  if (threadIdx.x == 0) out[0] = -red[0] * (1.f / BATCH);
}

// ---------------------------------------------------------------------------
// Paired bias+relu+BN.
// ---------------------------------------------------------------------------
__global__ __launch_bounds__(256) void bias_relu_bn2(
    const float* __restrict__ Hg, const float* __restrict__ bg,
    const float* __restrict__ gg, const float* __restrict__ beg,
    u16* __restrict__ og,
    const float* __restrict__ Hp, const float* __restrict__ bp,
    const float* __restrict__ gp, const float* __restrict__ bep,
    u16* __restrict__ op) {
  int c = blockIdx.x;
  const float *H, *b, *gma, *be; u16* ob;
  if (c < TH) { H = Hg; b = bg; gma = gg; be = beg; ob = og; }
  else { c -= TH; H = Hp; b = bp; gma = gp; be = bep; ob = op; }
  const int r = threadIdx.x;
  float v = fmaxf(H[(size_t)r * TH + c] + b[c], 0.f);
  __shared__ float red[BATCH];
  red[r] = v; __syncthreads();
  for (int s = BATCH / 2; s > 0; s >>= 1) { if (r < s) red[r] += red[r + s]; __syncthreads(); }
  const float mean = red[0] * (1.f / BATCH);
  __syncthreads();
  const float d = v - mean;
  red[r] = d * d; __syncthreads();
  for (int s = BATCH / 2; s > 0; s >>= 1) { if (r < s) red[r] += red[r + s]; __syncthreads(); }
  const float var = red[0] * (1.f / BATCH);
  ob[(size_t)r * TH + c] = f2bf(d * rsqrtf(var + BN_EPS) * gma[c] + be[c]);
}

// ---------------------------------------------------------------------------
// KL + theta for both encoders.
// ---------------------------------------------------------------------------
__global__ __launch_bounds__(128) void row_kl_theta(
    const float* __restrict__ mld, const float* __restrict__ mlj,
    const float* __restrict__ mu_b, const float* __restrict__ ls_b,
    u16* __restrict__ thd, u16* __restrict__ thj, float* __restrict__ kl_out) {
  const float* ml = blockIdx.y ? mlj : mld;
  u16* thb = blockIdx.y ? thj : thd;
  const int b = blockIdx.x;
  const int t = threadIdx.x;
  const bool act = (t < NT);
  float mu = 0.f, ls = 0.f, term = 0.f;
  if (act) {
    mu = ml[(size_t)b * NT2 + t] + mu_b[t];
    ls = 2.f * (ml[(size_t)b * NT2 + NT + t] + ls_b[t]);
    term = 1.f + ls - mu * mu - expf(ls);
  }
  __shared__ float red[128];
  red[t] = act ? term : 0.f; __syncthreads();
  for (int s = 64; s > 0; s >>= 1) { if (t < s) red[t] += red[t + s]; __syncthreads(); }
  if (t == 0) atomicAdd(kl_out, -0.5f * red[0] * (1.f / BATCH));
  __syncthreads();
  red[t] = act ? mu : -INFINITY; __syncthreads();
  for (int s = 64; s > 0; s >>= 1) { if (t < s) red[t] = fmaxf(red[t], red[t + s]); __syncthreads(); }
  const float mx = red[0];
  __syncthreads();
  const float e = act ? expf(mu - mx) : 0.f;
  red[t] = e; __syncthreads();
  for (int s = 64; s > 0; s >>= 1) { if (t < s) red[t] += red[t + s]; __syncthreads(); }
  thb[(size_t)b * NTP + t] = act ? f2bf(e / red[0]) : (u16)0;
}

// --------------------------- CSR build kernels -----------------------------
__global__ __launch_bounds__(256) void deg_count(
    const int* __restrict__ ei, int* __restrict__ deg) {
  int e = blockIdx.x * 256 + threadIdx.x;
  if (e >= E_TOTAL) return;
  const int d = (e < N_EDGES) ? ei[N_EDGES + e] : e - N_EDGES;
  atomicAdd(&deg[d], 1);
}

__global__ __launch_bounds__(256) void scan_part(
    const int* __restrict__ deg, int* __restrict__ bsum) {
  const int base = blockIdx.x * SCAN_CHUNK + threadIdx.x * 4;
  int s = 0;
#pragma unroll
  for (int i = 0; i < 4; ++i) {
    const int idx = base + i;
    if (idx < N_NODES) s += deg[idx];
  }
  for (int o = 32; o > 0; o >>= 1) s += __shfl_down(s, o);
  __shared__ int ws[4];
  if ((threadIdx.x & 63) == 0) ws[threadIdx.x >> 6] = s;
  __syncthreads();
  if (threadIdx.x == 0) bsum[blockIdx.x] = ws[0] + ws[1] + ws[2] + ws[3];
}

__global__ __launch_bounds__(64) void scan_bsum(int* __restrict__ bsum) {
  if (threadIdx.x == 0) {
    int run = 0;
    for (int i = 0; i < SCAN_NB; ++i) { int v = bsum[i]; bsum[i] = run; run += v; }
  }
}

__global__ __launch_bounds__(256) void scan_final(
    const int* __restrict__ deg, const int* __restrict__ bsum,
    int* __restrict__ row_ptr) {
  const int t = threadIdx.x;
  const int base = blockIdx.x * SCAN_CHUNK + t * 4;
  int v[4], s = 0;
#pragma unroll
  for (int i = 0; i < 4; ++i) {
    const int idx = base + i;
    v[i] = (idx < N_NODES) ? deg[idx] : 0;
    s += v[i];
  }
  const int lane = t & 63, w = t >> 6;
  int x = s;
  for (int o = 1; o < 64; o <<= 1) {
    int y = __shfl_up(x, o);
    if (lane >= o) x += y;
  }
  __shared__ int wtot[4];
  if (lane == 63) wtot[w] = x;
  __syncthreads();
  int woff = 0;
  for (int i = 0; i < w; ++i) woff += wtot[i];
  int excl = bsum[blockIdx.x] + woff + x - s;
#pragma unroll
  for (int i = 0; i < 4; ++i) {
    const int idx = base + i;
    if (idx < N_NODES) { row_ptr[idx] = excl; excl += v[i]; }
  }
  if (blockIdx.x == 0 && t == 0) row_ptr[N_NODES] = E_TOTAL;
}

__global__ __launch_bounds__(256) void csr_scatter(
    const int* __restrict__ ei, const int* __restrict__ row_ptr,
    int* __restrict__ cur, int* __restrict__ csr_src) {
  int e = blockIdx.x * 256 + threadIdx.x;
  if (e >= E_TOTAL) return;
  int s, d;
  if (e < N_EDGES) { s = ei[e]; d = ei[N_EDGES + e]; }
  else { s = d = e - N_EDGES; }
  const int pos = atomicAdd(&cur[d], 1);
  csr_src[row_ptr[d] + pos] = s;
}

// ---------------------------------------------------------------------------
// Fused GATv2 layer, 4-way edge-parallel (16-lane groups), bf16 in/out.
// ---------------------------------------------------------------------------
template <int C>
__global__ __launch_bounds__(256) void gat_fused(
    const u16* __restrict__ xl, const u16* __restrict__ xr,
    const float* __restrict__ att, const float* __restrict__ bias,
    const int* __restrict__ row_ptr, const int* __restrict__ csr_src,
    u16* __restrict__ out_b) {
  constexpr int CPL = C / 16;
  const int lane = threadIdx.x & 63;
  const int g = lane >> 4, li = lane & 15;
  const int d = blockIdx.x * 4 + (threadIdx.x >> 6);
  if (d >= N_NODES) return;
  const int c0 = li * CPL;
  float xrv[CPL], attv[CPL], acc[CPL];
#pragma unroll
  for (int i = 0; i < CPL; ++i) {
    xrv[i] = bf2f(xr[(size_t)d * C + c0 + i]);
    attv[i] = att[c0 + i];
    acc[i] = 0.f;
  }
  float m = -INFINITY, den = 0.f;
  const int end = row_ptr[d + 1];
  int p = row_ptr[d] + g;
  int s = (p < end) ? csr_src[p] : 0;
  while (p < end) {
    const int sn = (p + 4 < end) ? csr_src[p + 4] : 0;
    float xlv[CPL];
    float part = 0.f;
#pragma unroll
    for (int i = 0; i < CPL; ++i) {
      xlv[i] = bf2f(xl[(size_t)s * C + c0 + i]);
      float x = xlv[i] + xrv[i];
      x = (x > 0.f) ? x : 0.2f * x;
      part += x * attv[i];
    }
    part += __shfl_xor(part, 1);
    part += __shfl_xor(part, 2);
    part += __shfl_xor(part, 4);
    part += __shfl_xor(part, 8);
    const float logit = part;
    const float nm = fmaxf(m, logit);
    const float scale = expf(m - nm);
    const float ex = expf(logit - nm);
    den = den * scale + ex;
#pragma unroll
    for (int i = 0; i < CPL; ++i) acc[i] = acc[i] * scale + ex * xlv[i];
    m = nm;
    p += 4;
    s = sn;
  }
  float M = m;
  M = fmaxf(M, __shfl_xor(M, 16));
  M = fmaxf(M, __shfl_xor(M, 32));
  const float gs = expf(m - M);
  den *= gs;
  den += __shfl_xor(den, 16);
  den += __shfl_xor(den, 32);
  const float inv = 1.f / (den + 1e-16f);
  float va[CPL];
#pragma unroll
  for (int i = 0; i < CPL; ++i) {
    float a = acc[i] * gs;
    a += __shfl_xor(a, 16);
    a += __shfl_xor(a, 32);
    va[i] = a;
  }
  if (g == 0) {
#pragma unroll
    for (int i = 0; i < CPL; ++i)
      out_b[(size_t)d * C + c0 + i] = f2bf(fmaxf(va[i] * inv + bias[c0 + i], 0.f));
  }
}

__global__ __launch_bounds__(256) void init_cm(u32* __restrict__ cmax,
                                               float* __restrict__ cden) {
  const int i = threadIdx.x;
  if (i < 2 * NT) { cmax[i] = 0x007FFFFFu; cden[i] = 0.f; }
}

// ----------------------- column softmax statistics -------------------------
__global__ __launch_bounds__(256) void col_max(
    const float* __restrict__ Lg, const float* __restrict__ Lp,
    u32* __restrict__ gmx) {
  const float* L = blockIdx.y ? Lp : Lg;
  const int M = blockIdx.y ? NUM_PEAK : NUM_GENE;
  u32* mx = gmx + blockIdx.y * NT;
  const int r0 = blockIdx.x * 128;
  if (r0 >= M) return;
  __shared__ u32 s[NT];
  for (int i = threadIdx.x; i < NT; i += 256) s[i] = 0x007FFFFFu;
  __syncthreads();
  const int cnt = min(128, M - r0) * NT;
  const float* base = L + (size_t)r0 * NT;
  for (int i = threadIdx.x; i < cnt; i += 256) {
    const int c = i % NT;
    atomicMax(&s[c], f2o(base[i]));
  }
  __syncthreads();
  for (int i = threadIdx.x; i < NT; i += 256) atomicMax(&mx[i], s[i]);
}

__global__ __launch_bounds__(256) void col_sumexp(
    const float* __restrict__ Lg, const float* __restrict__ Lp,
    const u32* __restrict__ gmx, float* __restrict__ gden) {
  const float* L = blockIdx.y ? Lp : Lg;
  const int M = blockIdx.y ? NUM_PEAK : NUM_GENE;
  const u32* mxg = gmx + blockIdx.y * NT;
  float* dng = gden + blockIdx.y * NT;
  const int r0 = blockIdx.x * 128;
  if (r0 >= M) return;
  __shared__ float mx[NT];
  __shared__ float s[NT];
  for (int i = threadIdx.x; i < NT; i += 256) { mx[i] = o2f(mxg[i]); s[i] = 0.f; }
  __syncthreads();
  const int cnt = min(128, M - r0) * NT;
  const float* base = L + (size_t)r0 * NT;
  for (int i = threadIdx.x; i < cnt; i += 256) {
    const int c = i % NT;
    atomicAdd(&s[c], expf(base[i] - mx[c]));
  }
  __syncthreads();
  for (int i = threadIdx.x; i < NT; i += 256) atomicAdd(&dng[i], s[i]);
}

__global__ __launch_bounds__(256) void beta_norm(
    const float* __restrict__ Lg, const float* __restrict__ Lp,
    const u32* __restrict__ gmx, const float* __restrict__ gden,
    u16* __restrict__ og, u16* __restrict__ op) {
  const float* L = blockIdx.y ? Lp : Lg;
  const int M = blockIdx.y ? NUM_PEAK : NUM_GENE;
  const u32* mxg = gmx + blockIdx.y * NT;
  const float* dng = gden + blockIdx.y * NT;
  u16* o = blockIdx.y ? op : og;
  __shared__ float mx[NT], inv[NT];
  for (int i = threadIdx.x; i < NT; i += 256) { mx[i] = o2f(mxg[i]); inv[i] = 1.f / dng[i]; }
  __syncthreads();
  const size_t total = (size_t)M * NTP;
  size_t i = (size_t)blockIdx.x * 256 + threadIdx.x;
  const size_t stride = (size_t)gridDim.x * 256;
  for (; i < total; i += stride) {
    const int c = (int)(i & (NTP - 1));
    u16 v = 0;
    if (c < NT) {
      const size_t r = i >> 7;
      v = f2bf(expf(L[r * NT + c] - mx[c]) * inv[c]);
    }
    o[i] = v;
  }
}

// ---------------------------------------------------------------------------
extern "C" void kernel_launch(void* const* d_in, const int* in_sizes, int n_in,
                              void* d_out, int out_size, void* d_ws, size_t ws_size,
                              hipStream_t stream) {
  const float* Gene  = (const float*)d_in[0];
  const float* GeneN = (const float*)d_in[1];
  const float* Peak  = (const float*)d_in[2];
  const float* PeakN = (const float*)d_in[3];
  const float* feat  = (const float*)d_in[4];
  const float* Wl1 = (const float*)d_in[5];  const float* bl1 = (const float*)d_in[6];
  const float* Wr1 = (const float*)d_in[7];  const float* br1 = (const float*)d_in[8];
  const float* att1 = (const float*)d_in[9]; const float* bias1 = (const float*)d_in[10];
  const float* Wl2 = (const float*)d_in[11]; const float* bl2 = (const float*)d_in[12];
  const float* Wr2 = (const float*)d_in[13]; const float* br2 = (const float*)d_in[14];
  const float* att2 = (const float*)d_in[15]; const float* bias2 = (const float*)d_in[16];
  const float* gW1 = (const float*)d_in[17]; const float* gb1 = (const float*)d_in[18];
  const float* gg1 = (const float*)d_in[19]; const float* gbe1 = (const float*)d_in[20];
  const float* gW2 = (const float*)d_in[21]; const float* gb2 = (const float*)d_in[22];
  const float* gg2 = (const float*)d_in[23]; const float* gbe2 = (const float*)d_in[24];
  const float* pW1 = (const float*)d_in[25]; const float* pb1 = (const float*)d_in[26];
  const float* pg1 = (const float*)d_in[27]; const float* pbe1 = (const float*)d_in[28];
  const float* pW2 = (const float*)d_in[29]; const float* pb2 = (const float*)d_in[30];
  const float* pg2 = (const float*)d_in[31]; const float* pbe2 = (const float*)d_in[32];
  const float* mu_W = (const float*)d_in[33]; const float* mu_b = (const float*)d_in[34];
  const float* ls_W = (const float*)d_in[35]; const float* ls_b = (const float*)d_in[36];
  const float* alphas_W = (const float*)d_in[37];
  const float* alphas_star_W = (const float*)d_in[38];
  const int* ei = (const int*)d_in[39];
  float* out = (float*)d_out;
  (void)in_sizes; (void)n_in; (void)ws_size;

  // ---- workspace layout (bytes) ----
  char* base = (char*)d_ws;
  size_t off = 0;
  auto A = [&](size_t bytes) { void* p = base + off; off += (bytes + 255) & ~(size_t)255; return p; };
  int* deg     = (int*)A((size_t)N_NODES * 4);      // deg+cur adjacent (one memset)
  int* cur     = (int*)A((size_t)N_NODES * 4);
  int* row_ptr = (int*)A((size_t)(N_NODES + 1) * 4);
  int* bsum    = (int*)A((size_t)(SCAN_NB + 1) * 4);
  int* csr_src = (int*)A((size_t)E_TOTAL * 4);
  float* h1g = (float*)A((size_t)BATCH * TH * 4);   // h1g+h1p adjacent (one memset)
  float* h1p = (float*)A((size_t)BATCH * TH * 4);
  float* h2g = (float*)A((size_t)BATCH * TH * 4);
  float* h2p = (float*)A((size_t)BATCH * TH * 4);
  u16* h1gb = (u16*)A((size_t)BATCH * TH * 2);
  u16* h2gb = (u16*)A((size_t)BATCH * TH * 2);
  u16* h1pb = (u16*)A((size_t)BATCH * TH * 2);
  u16* h2pb = (u16*)A((size_t)BATCH * TH * 2);
  float* ml_d = (float*)A((size_t)BATCH * NT2 * 4);
  float* ml_j = (float*)A((size_t)BATCH * NT2 * 4);
  u16* th_db = (u16*)A((size_t)BATCH * NTP * 2);
  u16* th_jb = (u16*)A((size_t)BATCH * NTP * 2);
  float* lgg = (float*)A((size_t)NUM_GENE * NT * 4);
  float* lgp = (float*)A((size_t)NUM_PEAK * NT * 4);
  u16* betagb = (u16*)A((size_t)NUM_GENE * NTP * 2);
  u16* betapb = (u16*)A((size_t)NUM_PEAK * NTP * 2);
  u16* featb = (u16*)A((size_t)N_NODES * EMB * 2);
  u16* gW2b = (u16*)A((size_t)TH * TH * 2);
  u16* pW2b = (u16*)A((size_t)TH * TH * 2);
  u16* mlWb = (u16*)A((size_t)NT2 * TH * 2);
  u16* Wl1b = (u16*)A((size_t)HID * EMB * 2);
  u16* Wr1b = (u16*)A((size_t)HID * EMB * 2);
  u16* Wl2b = (u16*)A((size_t)EMB * HID * 2);
  u16* Wr2b = (u16*)A((size_t)EMB * HID * 2);
  u16* aWb  = (u16*)A((size_t)NT * EMB * 2);
  u16* aSWb = (u16*)A((size_t)NT * EMB * 2);
  u16* agg1b = (u16*)A((size_t)N_NODES * HID * 2);
  u16* embb  = (u16*)A((size_t)N_NODES * EMB * 2);
  u32* cmax = (u32*)A(2 * NT * 4);
  float* cden = (float*)A(2 * NT * 4);
  float* partials = (float*)A(4096 * 4);
  u16* xl1b = (u16*)A((size_t)N_NODES * HID * 2);
  u16* xr1b = (u16*)A((size_t)N_NODES * HID * 2);
  u16* xl2b = (u16*)A((size_t)N_NODES * EMB * 2);
  u16* xr2b = (u16*)A((size_t)N_NODES * EMB * 2);

  auto cdiv = [](int a, int b) { return (a + b - 1) / b; };
  auto Z = [&](void* p, size_t bytes) { hipMemsetAsync(p, 0, bytes, stream); };

  Z(d_out, (size_t)out_size * sizeof(float));
  Z(deg, 2 * (size_t)N_NODES * 4);                    // deg + cur

  // ---- CSR build (hierarchical scan) ----
  deg_count<<<cdiv(E_TOTAL, 256), 256, 0, stream>>>(ei, deg);
  scan_part<<<SCAN_NB, 256, 0, stream>>>(deg, bsum);
  scan_bsum<<<1, 64, 0, stream>>>(bsum);
  scan_final<<<SCAN_NB, 256, 0, stream>>>(deg, bsum, row_ptr);
  csr_scatter<<<cdiv(E_TOTAL, 256), 256, 0, stream>>>(ei, row_ptr, cur, csr_src);

  // ---- small fp32->bf16 conversions in one launch ----
  {
    CvtJobs J = {};
    int c = 0; u32 blocks = 0;
    auto add = [&](const float* s, u16* d, size_t n) {
      J.src[c] = s; J.dst[c] = d; J.n[c] = (u32)n; J.start[c] = blocks;
      blocks += (u32)((n + 2047) / 2048); ++c;
    };
    add(gW2, gW2b, (size_t)TH * TH);
    add(pW2, pW2b, (size_t)TH * TH);
    add(mu_W, mlWb, (size_t)NT * TH);
    add(ls_W, mlWb + (size_t)NT * TH, (size_t)NT * TH);
    add(feat, featb, (size_t)N_NODES * EMB);
    add(Wl1, Wl1b, (size_t)HID * EMB);
    add(Wr1, Wr1b, (size_t)HID * EMB);
    add(Wl2, Wl2b, (size_t)EMB * HID);
    add(Wr2, Wr2b, (size_t)EMB * HID);
    add(alphas_W, aWb, (size_t)NT * EMB);
    add(alphas_star_W, aSWb, (size_t)NT * EMB);
    J.count = c;
    cvt_all<<<blocks, 256, 0, stream>>>(J);
  }

  // ================= encoders =================
  const int kspG = cdiv(NUM_GENE, ENC_CH);   // 38
  const int kspP = cdiv(NUM_PEAK, ENC_CH);   // 88
  Z(h1g, 2 * (size_t)BATCH * TH * 4);                 // h1g + h1p
  gemm_enc1<<<dim3(TH / 128, 1, kspG + kspP), 512, 0, stream>>>(
      GeneN, gW1, h1g, NUM_GENE, kspG,
      PeakN, pW1, h1p, NUM_PEAK);
  bias_relu_bn2<<<2 * TH, BATCH, 0, stream>>>(h1g, gb1, gg1, gbe1, h1gb,
                                              h1p, pb1, pg1, pbe1, h1pb);
  {
    GP g = {h1gb, gW2b, h2g, nullptr, nullptr, BATCH, TH, TH, TH};
    GP p = {h1pb, pW2b, h2p, nullptr, nullptr, BATCH, TH, TH, TH};
    gemm_bt_bf16<<<dim3(TH / 64, BATCH / 64, 2), 256, 0, stream>>>(g, p, 1);
  }
  bias_relu_bn2<<<2 * TH, BATCH, 0, stream>>>(h2g, gb2, gg2, gbe2, h2gb,
                                              h2p, pb2, pg2, pbe2, h2pb);
  {
    GP g = {h2gb, mlWb, ml_d, nullptr, nullptr, BATCH, NT2, TH, TH};
    GP p = {h2pb, mlWb, ml_j, nullptr, nullptr, BATCH, NT2, TH, TH};
    gemm_bt_bf16<<<dim3(cdiv(NT2, 64), BATCH / 64, 2), 256, 0, stream>>>(g, p, 1);
  }
  row_kl_theta<<<dim3(BATCH, 2), 128, 0, stream>>>(ml_d, ml_j, mu_b, ls_b, th_db, th_jb, out + 1);

  // ================= GAT layer 1 =================
  {
    GP l = {featb, Wl1b, nullptr, xl1b, bl1, N_NODES, HID, EMB, EMB};
    GP r = {featb, Wr1b, nullptr, xr1b, br1, N_NODES, HID, EMB, EMB};
    gemm_bt_bf16<<<dim3(HID / 64, N_NODES / 64, 2), 256, 0, stream>>>(l, r, 1);
  }
  gat_fused<HID><<<N_NODES / 4, 256, 0, stream>>>(xl1b, xr1b, att1, bias1, row_ptr, csr_src, agg1b);

  // ================= GAT layer 2 =================
  {
    GP l = {agg1b, Wl2b, nullptr, xl2b, bl2, N_NODES, EMB, HID, HID};
    GP r = {agg1b, Wr2b, nullptr, xr2b, br2, N_NODES, EMB, HID, HID};
    gemm_bt_bf16<<<dim3(EMB / 64, N_NODES / 64, 2), 256, 0, stream>>>(l, r, 1);
  }
  gat_fused<EMB><<<N_NODES / 4, 256, 0, stream>>>(xl2b, xr2b, att2, bias2, row_ptr, csr_src, embb);

  // ================= topic heads =================
  {
    GP g = {embb + (size_t)NUM_PEAK * EMB, aWb, lgg, nullptr, nullptr, NUM_GENE, NT, EMB, EMB};
    GP p = {embb, aSWb, lgp, nullptr, nullptr, NUM_PEAK, NT, EMB, EMB};
    gemm_bt_bf16<<<dim3(2, cdiv(NUM_PEAK, 64), 2), 256, 0, stream>>>(g, p, 1);
  }
  init_cm<<<1, 256, 0, stream>>>(cmax, cden);
  col_max<<<dim3(cdiv(NUM_PEAK, 128), 2), 256, 0, stream>>>(lgg, lgp, cmax);
  col_sumexp<<<dim3(cdiv(NUM_PEAK, 128), 2), 256, 0, stream>>>(lgg, lgp, cmax, cden);
  beta_norm<<<dim3(1024, 2), 256, 0, stream>>>(lgg, lgp, cmax, cden, betagb, betapb);

  // ================= fused preds + recon ============
  const int tiles_g = cdiv(NUM_GENE, 64);
  const int tiles_p = cdiv(NUM_PEAK, 64);
  const int tiles = tiles_g + tiles_p;
  recon_fused<<<dim3(tiles, 4), 256, 0, stream>>>(
      th_db, betagb, Gene, NUM_GENE, tiles_g,
      th_jb, betapb, Peak, NUM_PEAK, partials);
  final_recon<<<1, 256, 0, stream>>>(partials, tiles * 4, out);
}